// Round 2
// baseline (5176.329 us; speedup 1.0000x reference)
//
#include <hip/hip_runtime.h>

#define L 128
#define NSTEPS 2

typedef __attribute__((ext_vector_type(8))) short short8;
typedef __attribute__((ext_vector_type(4))) float f32x4;

static __device__ __forceinline__ unsigned short f2bf(float f) {
  unsigned int u = __float_as_uint(f);
  u += 0x7FFFu + ((u >> 16) & 1u);   // round-to-nearest-even
  return (unsigned short)(u >> 16);
}
static __device__ __forceinline__ float bf2f(unsigned short h) {
  return __uint_as_float(((unsigned int)h) << 16);
}

// hi[s][n][k] = bf16(in[s][k][n]); lo = bf16(residual)  (transpose + split)
__global__ void conv_split_kernel(const float* __restrict__ in,
                                  unsigned short* __restrict__ hi,
                                  unsigned short* __restrict__ lo,
                                  int K, int N, int S) {
  int id = blockIdx.x * 256 + threadIdx.x;
  int kn = K * N;
  int total = S * kn;
  if (id >= total) return;
  int s = id / kn;
  int rem = id - s * kn;
  int n = rem / K;
  int k = rem - n * K;
  float x = in[(size_t)s * kn + (size_t)k * N + n];
  unsigned short h = f2bf(x);
  hi[id] = h;
  lo[id] = f2bf(x - bf2f(h));
}

// out[m][j] = b[j] + sum_k feats[m][k] * W[k][j]   (exact fp32)
__global__ void embed_kernel(const float* __restrict__ feats, const float* __restrict__ W,
                             const float* __restrict__ bias, float* __restrict__ out,
                             int M, int K) {
  int j = threadIdx.x;  // 128
  for (int row = blockIdx.x; row < M; row += gridDim.x) {
    const float* f = feats + (size_t)row * K;
    float acc = bias[j];
    for (int k = 0; k < K; ++k) acc += f[k] * W[k * L + j];
    out[(size_t)row * L + j] = acc;
  }
}

__global__ void glob_embed_kernel(const float* __restrict__ gin, const float* __restrict__ W,
                                  const float* __restrict__ bias, float* __restrict__ glob) {
  int j = threadIdx.x;  // 128
  float acc = bias[j];
  for (int k = 0; k < 16; ++k) acc += gin[k] * W[k * L + j];
  glob[j] = acc;
}

// Fused per-step update for edges (EDGE_MODE) or nodes, split-precision bf16 MFMA.
// Tile: 64 rows x 512-concat input. 256 threads = 4 waves (2x2), each wave owns a
// 32-row x 64-col output sub-tile (2x4 frags of 16x16x32 bf16 MFMA, 3 products each).
// LDS 128KB: As_hi[64][512] + As_lo[64][512], XOR-swizzled in 16B units; aliased later
// as H_hi/H_lo [64][136] bf16 and Ef[64][132] f32.
template<bool EDGE_MODE>
__global__ __launch_bounds__(256, 1)
void block_step_kernel(float* __restrict__ x_io,                       // [M][128] in/out
                       const float* __restrict__ gsrc1,                // nodes | sent
                       const float* __restrict__ gsrc2,                // nodes | recv
                       const int* __restrict__ idx1, const int* __restrict__ idx2,
                       const float* __restrict__ glob,                 // [128]
                       const unsigned short* __restrict__ W0h,         // [128][512] bf16 T
                       const unsigned short* __restrict__ W0l,
                       const float* __restrict__ b0,
                       const unsigned short* __restrict__ W1h,         // [128][128] bf16 T
                       const unsigned short* __restrict__ W1l,
                       const float* __restrict__ b1,
                       const float* __restrict__ ln_s, const float* __restrict__ ln_b,
                       float* __restrict__ scat1, float* __restrict__ scat2,
                       float* __restrict__ agg,                        // [128]
                       int M) {
  __shared__ __align__(16) unsigned short As_hi[64][512];   // 64 KB
  __shared__ __align__(16) unsigned short As_lo[64][512];   // 64 KB

  const int t = threadIdx.x;
  const int m0 = blockIdx.x * 64;
  const int valid = (M - m0 < 64) ? (M - m0) : 64;

  // ---- stage A tile [64][512] -> bf16 hi/lo, swizzled: 16B-unit c8 ^= (row&7) ----
  for (int g = t; g < 64 * 64; g += 256) {
    int row = g >> 6;
    int c8 = g & 63;
    int col = c8 << 3;
    short8 hv = {0, 0, 0, 0, 0, 0, 0, 0};
    short8 lv = {0, 0, 0, 0, 0, 0, 0, 0};
    if (row < valid) {
      int seg = col >> 7;     // 0: self, 1: gather1, 2: gather2, 3: glob
      int cin = col & 127;
      const float* p;
      if (seg == 0) {
        p = x_io + (size_t)(m0 + row) * L + cin;
      } else if (seg == 1) {
        p = (EDGE_MODE ? gsrc1 + (size_t)idx1[m0 + row] * L
                       : gsrc1 + (size_t)(m0 + row) * L) + cin;
      } else if (seg == 2) {
        p = (EDGE_MODE ? gsrc2 + (size_t)idx2[m0 + row] * L
                       : gsrc2 + (size_t)(m0 + row) * L) + cin;
      } else {
        p = glob + cin;
      }
      float4 v0 = *(const float4*)(p);
      float4 v1 = *(const float4*)(p + 4);
      float xs[8] = {v0.x, v0.y, v0.z, v0.w, v1.x, v1.y, v1.z, v1.w};
#pragma unroll
      for (int j = 0; j < 8; ++j) {
        unsigned short h = f2bf(xs[j]);
        hv[j] = (short)h;
        lv[j] = (short)f2bf(xs[j] - bf2f(h));
      }
    }
    int sw = (c8 ^ (row & 7)) << 3;
    *(short8*)&As_hi[row][sw] = hv;
    *(short8*)&As_lo[row][sw] = lv;
  }
  __syncthreads();

  const int lane = t & 63;
  const int wid = t >> 6;
  const int wm = wid >> 1;            // 0..1: row half
  const int wn = wid & 1;             // 0..1: col half
  const int lr = lane & 15;
  const int lk = (lane >> 4) << 3;    // k offset in chunk: 0,8,16,24
  const int rr = (lane >> 4) << 2;    // C/D row group: 0,4,8,12

  const f32x4 z4 = {0.f, 0.f, 0.f, 0.f};
  f32x4 acc[2][4];
#pragma unroll
  for (int i = 0; i < 2; ++i)
#pragma unroll
    for (int j = 0; j < 4; ++j) acc[i][j] = z4;

  // ---- layer 0: [64x512] @ [512x128], 3-product split ----
  const int row0 = wm * 32 + lr;
  const int row1 = wm * 32 + 16 + lr;
#pragma unroll 2
  for (int k0 = 0; k0 < 512; k0 += 32) {
    int c8 = (k0 + lk) >> 3;
    int sw0 = (c8 ^ (row0 & 7)) << 3;
    int sw1 = (c8 ^ (row1 & 7)) << 3;
    short8 a0h = *(const short8*)&As_hi[row0][sw0];
    short8 a0l = *(const short8*)&As_lo[row0][sw0];
    short8 a1h = *(const short8*)&As_hi[row1][sw1];
    short8 a1l = *(const short8*)&As_lo[row1][sw1];
#pragma unroll
    for (int fn = 0; fn < 4; ++fn) {
      size_t wb = (size_t)(wn * 64 + fn * 16 + lr) * 512 + k0 + lk;
      short8 bh = *(const short8*)(W0h + wb);
      short8 bl = *(const short8*)(W0l + wb);
      acc[0][fn] = __builtin_amdgcn_mfma_f32_16x16x32_bf16(a0h, bh, acc[0][fn], 0, 0, 0);
      acc[0][fn] = __builtin_amdgcn_mfma_f32_16x16x32_bf16(a0l, bh, acc[0][fn], 0, 0, 0);
      acc[0][fn] = __builtin_amdgcn_mfma_f32_16x16x32_bf16(a0h, bl, acc[0][fn], 0, 0, 0);
      acc[1][fn] = __builtin_amdgcn_mfma_f32_16x16x32_bf16(a1h, bh, acc[1][fn], 0, 0, 0);
      acc[1][fn] = __builtin_amdgcn_mfma_f32_16x16x32_bf16(a1l, bh, acc[1][fn], 0, 0, 0);
      acc[1][fn] = __builtin_amdgcn_mfma_f32_16x16x32_bf16(a1h, bl, acc[1][fn], 0, 0, 0);
    }
  }
  __syncthreads();   // all As reads done; safe to overwrite via alias

  // ---- h = relu(acc + b0) -> H_hi/H_lo [64][136] bf16 (alias As_hi / As_lo) ----
  unsigned short* Hh = &As_hi[0][0];
  unsigned short* Hl = &As_lo[0][0];
#pragma unroll
  for (int fm = 0; fm < 2; ++fm)
#pragma unroll
    for (int fn = 0; fn < 4; ++fn) {
      int col = wn * 64 + fn * 16 + lr;
      float bb = b0[col];
#pragma unroll
      for (int r = 0; r < 4; ++r) {
        int row = wm * 32 + fm * 16 + rr + r;
        float x = fmaxf(acc[fm][fn][r] + bb, 0.f);
        unsigned short h = f2bf(x);
        Hh[row * 136 + col] = h;
        Hl[row * 136 + col] = f2bf(x - bf2f(h));
      }
    }
  __syncthreads();

  // ---- layer 1: [64x128] @ [128x128], 3-product split ----
  f32x4 acc2[2][4];
#pragma unroll
  for (int i = 0; i < 2; ++i)
#pragma unroll
    for (int j = 0; j < 4; ++j) acc2[i][j] = z4;
#pragma unroll
  for (int k0 = 0; k0 < 128; k0 += 32) {
    short8 a0h = *(const short8*)&Hh[row0 * 136 + k0 + lk];
    short8 a0l = *(const short8*)&Hl[row0 * 136 + k0 + lk];
    short8 a1h = *(const short8*)&Hh[row1 * 136 + k0 + lk];
    short8 a1l = *(const short8*)&Hl[row1 * 136 + k0 + lk];
#pragma unroll
    for (int fn = 0; fn < 4; ++fn) {
      size_t wb = (size_t)(wn * 64 + fn * 16 + lr) * 128 + k0 + lk;
      short8 bh = *(const short8*)(W1h + wb);
      short8 bl = *(const short8*)(W1l + wb);
      acc2[0][fn] = __builtin_amdgcn_mfma_f32_16x16x32_bf16(a0h, bh, acc2[0][fn], 0, 0, 0);
      acc2[0][fn] = __builtin_amdgcn_mfma_f32_16x16x32_bf16(a0l, bh, acc2[0][fn], 0, 0, 0);
      acc2[0][fn] = __builtin_amdgcn_mfma_f32_16x16x32_bf16(a0h, bl, acc2[0][fn], 0, 0, 0);
      acc2[1][fn] = __builtin_amdgcn_mfma_f32_16x16x32_bf16(a1h, bh, acc2[1][fn], 0, 0, 0);
      acc2[1][fn] = __builtin_amdgcn_mfma_f32_16x16x32_bf16(a1l, bh, acc2[1][fn], 0, 0, 0);
      acc2[1][fn] = __builtin_amdgcn_mfma_f32_16x16x32_bf16(a1h, bl, acc2[1][fn], 0, 0, 0);
    }
  }
  __syncthreads();   // all H reads done; safe to overwrite via alias

  // ---- out = relu(acc2 + b1) -> Ef[64][132] f32 (aliases As_hi) ----
  float* Ef = (float*)&As_hi[0][0];
#pragma unroll
  for (int fm = 0; fm < 2; ++fm)
#pragma unroll
    for (int fn = 0; fn < 4; ++fn) {
      int col = wn * 64 + fn * 16 + lr;
      float bb = b1[col];
#pragma unroll
      for (int r = 0; r < 4; ++r) {
        int row = wm * 32 + fm * 16 + rr + r;
        Ef[row * 132 + col] = fmaxf(acc2[fm][fn][r] + bb, 0.f);
      }
    }
  __syncthreads();

  // ---- scatter-add segment sums (edge mode) ----
  if (EDGE_MODE) {
    for (int g = t; g < 64 * 128; g += 256) {
      int row = g >> 7, col = g & 127;
      if (row < valid) {
        float v = Ef[row * 132 + col];
        atomicAdd(&scat1[(size_t)idx1[m0 + row] * L + col], v);
        atomicAdd(&scat2[(size_t)idx2[m0 + row] * L + col], v);
      }
    }
  }
  // ---- column aggregate (partial sum -> global atomics) ----
  if (t < 128) {
    float s = 0.f;
    for (int row = 0; row < valid; ++row) s += Ef[row * 132 + t];
    atomicAdd(&agg[t], s);
  }

  // ---- residual + LayerNorm, in place (4 lanes per row) ----
  {
    int r = t >> 2, q = t & 3;
    if (r < valid) {
      size_t base = (size_t)(m0 + r) * L;
      float xv[32];
      float sum = 0.f, sq = 0.f;
#pragma unroll
      for (int i = 0; i < 32; ++i) {
        int c = q * 32 + i;
        float x = Ef[r * 132 + c] + x_io[base + c];
        xv[i] = x;
        sum += x; sq += x * x;
      }
      sum += __shfl_xor(sum, 1); sq += __shfl_xor(sq, 1);
      sum += __shfl_xor(sum, 2); sq += __shfl_xor(sq, 2);
      float mu = sum * (1.f / 128.f);
      float var = sq * (1.f / 128.f) - mu * mu;
      float rs = rsqrtf(var + 1e-6f);
#pragma unroll
      for (int i = 0; i < 32; ++i) {
        int c = q * 32 + i;
        x_io[base + c] = (xv[i] - mu) * rs * ln_s[c] + ln_b[c];
      }
    }
  }
}

// single-block global update: MLP(concat(node_agg, edge_agg, glob)) + residual + LN
__global__ void glob_step_kernel(float* __restrict__ glob,
                                 const float* __restrict__ node_agg,
                                 const float* __restrict__ edge_agg,
                                 const float* __restrict__ W0, const float* __restrict__ b0,
                                 const float* __restrict__ W1, const float* __restrict__ b1,
                                 const float* __restrict__ ln_s, const float* __restrict__ ln_b) {
  __shared__ float gin[384];
  __shared__ float h[128];
  __shared__ float red4[4];
  int j = threadIdx.x;  // 128
  gin[j] = node_agg[j];
  gin[128 + j] = edge_agg[j];
  gin[256 + j] = glob[j];
  __syncthreads();
  float a = b0[j];
  for (int k = 0; k < 384; ++k) a += gin[k] * W0[k * L + j];
  h[j] = fmaxf(a, 0.f);
  __syncthreads();
  float o = b1[j];
  for (int k = 0; k < 128; ++k) o += h[k] * W1[k * L + j];
  o = fmaxf(o, 0.f);
  float x = o + glob[j];
  float sum = x, sq = x * x;
  for (int m = 1; m < 64; m <<= 1) { sum += __shfl_xor(sum, m); sq += __shfl_xor(sq, m); }
  if ((j & 63) == 0) { red4[(j >> 6) * 2] = sum; red4[(j >> 6) * 2 + 1] = sq; }
  __syncthreads();
  sum = red4[0] + red4[2]; sq = red4[1] + red4[3];
  float mu = sum * (1.f / 128.f);
  float var = sq * (1.f / 128.f) - mu * mu;
  float rs = rsqrtf(var + 1e-6f);
  glob[j] = (x - mu) * rs * ln_s[j] + ln_b[j];
}

__global__ void decode_kernel(const float* __restrict__ glob, const float* __restrict__ W,
                              const float* __restrict__ bias, float* __restrict__ out) {
  int j = threadIdx.x;  // 128
  float a = bias[j];
  for (int k = 0; k < 128; ++k) a += glob[k] * W[k * L + j];
  out[j] = a;
}

extern "C" void kernel_launch(void* const* d_in, const int* in_sizes, int n_in,
                              void* d_out, int out_size, void* d_ws, size_t ws_size,
                              hipStream_t stream) {
  const float* node_feats = (const float*)d_in[0];
  const float* edge_feats = (const float*)d_in[1];
  const float* globals_   = (const float*)d_in[2];
  const int*   senders    = (const int*)d_in[3];
  const int*   receivers  = (const int*)d_in[4];
  const float* emb_node_W = (const float*)d_in[5];
  const float* emb_node_b = (const float*)d_in[6];
  const float* emb_edge_W = (const float*)d_in[7];
  const float* emb_edge_b = (const float*)d_in[8];
  const float* emb_glob_W = (const float*)d_in[9];
  const float* emb_glob_b = (const float*)d_in[10];
  const float* edge_W0 = (const float*)d_in[11];
  const float* edge_b0 = (const float*)d_in[12];
  const float* edge_W1 = (const float*)d_in[13];
  const float* edge_b1 = (const float*)d_in[14];
  const float* node_W0 = (const float*)d_in[15];
  const float* node_b0 = (const float*)d_in[16];
  const float* node_W1 = (const float*)d_in[17];
  const float* node_b1 = (const float*)d_in[18];
  const float* glob_W0 = (const float*)d_in[19];
  const float* glob_b0 = (const float*)d_in[20];
  const float* glob_W1 = (const float*)d_in[21];
  const float* glob_b1 = (const float*)d_in[22];
  const float* ln_node_s = (const float*)d_in[23];
  const float* ln_node_b = (const float*)d_in[24];
  const float* ln_edge_s = (const float*)d_in[25];
  const float* ln_edge_b = (const float*)d_in[26];
  const float* ln_glob_s = (const float*)d_in[27];
  const float* ln_glob_b = (const float*)d_in[28];
  const float* dec_W = (const float*)d_in[29];
  const float* dec_b = (const float*)d_in[30];

  const int N = in_sizes[0] / 64;
  const int E = in_sizes[1] / 32;

  float* nodes = (float*)d_out;                   // [N][128]
  float* edges = nodes + (size_t)N * L;           // [E][128]
  float* gout  = edges + (size_t)E * L;           // [128]

  char* ws = (char*)d_ws;
  float* sent = (float*)ws;      ws += (size_t)N * L * 4;
  float* recv = (float*)ws;      ws += (size_t)N * L * 4;
  float* glob = (float*)ws;      ws += 512;
  float* node_agg = (float*)ws;  ws += 512;
  float* edge_agg = (float*)ws;  ws += 512;
  unsigned short* eW0h = (unsigned short*)ws; ws += (size_t)NSTEPS * 128 * 512 * 2;
  unsigned short* eW0l = (unsigned short*)ws; ws += (size_t)NSTEPS * 128 * 512 * 2;
  unsigned short* eW1h = (unsigned short*)ws; ws += (size_t)NSTEPS * 128 * 128 * 2;
  unsigned short* eW1l = (unsigned short*)ws; ws += (size_t)NSTEPS * 128 * 128 * 2;
  unsigned short* nW0h = (unsigned short*)ws; ws += (size_t)NSTEPS * 128 * 512 * 2;
  unsigned short* nW0l = (unsigned short*)ws; ws += (size_t)NSTEPS * 128 * 512 * 2;
  unsigned short* nW1h = (unsigned short*)ws; ws += (size_t)NSTEPS * 128 * 128 * 2;
  unsigned short* nW1l = (unsigned short*)ws; ws += (size_t)NSTEPS * 128 * 128 * 2;

  // weight prep (bf16 hi/lo, transposed)
  conv_split_kernel<<<(NSTEPS * 512 * 128 + 255) / 256, 256, 0, stream>>>(edge_W0, eW0h, eW0l, 512, 128, NSTEPS);
  conv_split_kernel<<<(NSTEPS * 128 * 128 + 255) / 256, 256, 0, stream>>>(edge_W1, eW1h, eW1l, 128, 128, NSTEPS);
  conv_split_kernel<<<(NSTEPS * 512 * 128 + 255) / 256, 256, 0, stream>>>(node_W0, nW0h, nW0l, 512, 128, NSTEPS);
  conv_split_kernel<<<(NSTEPS * 128 * 128 + 255) / 256, 256, 0, stream>>>(node_W1, nW1h, nW1l, 128, 128, NSTEPS);

  // embeddings (exact fp32)
  embed_kernel<<<2048, 128, 0, stream>>>(node_feats, emb_node_W, emb_node_b, nodes, N, 64);
  embed_kernel<<<4096, 128, 0, stream>>>(edge_feats, emb_edge_W, emb_edge_b, edges, E, 32);
  glob_embed_kernel<<<1, 128, 0, stream>>>(globals_, emb_glob_W, emb_glob_b, glob);

  const int egrid = (E + 63) / 64;
  const int ngrid = (N + 63) / 64;
  for (int s = 0; s < NSTEPS; ++s) {
    hipMemsetAsync(sent, 0, (size_t)N * L * 4, stream);
    hipMemsetAsync(recv, 0, (size_t)N * L * 4, stream);
    hipMemsetAsync(node_agg, 0, 512, stream);
    hipMemsetAsync(edge_agg, 0, 512, stream);

    block_step_kernel<true><<<egrid, 256, 0, stream>>>(
        edges, nodes, nodes, senders, receivers, glob,
        eW0h + (size_t)s * 128 * 512, eW0l + (size_t)s * 128 * 512, edge_b0 + s * L,
        eW1h + (size_t)s * 128 * 128, eW1l + (size_t)s * 128 * 128, edge_b1 + s * L,
        ln_edge_s + s * L, ln_edge_b + s * L,
        sent, recv, edge_agg, E);

    block_step_kernel<false><<<ngrid, 256, 0, stream>>>(
        nodes, sent, recv, nullptr, nullptr, glob,
        nW0h + (size_t)s * 128 * 512, nW0l + (size_t)s * 128 * 512, node_b0 + s * L,
        nW1h + (size_t)s * 128 * 128, nW1l + (size_t)s * 128 * 128, node_b1 + s * L,
        ln_node_s + s * L, ln_node_b + s * L,
        nullptr, nullptr, node_agg, N);

    glob_step_kernel<<<1, 128, 0, stream>>>(
        glob, node_agg, edge_agg,
        glob_W0 + (size_t)s * 384 * L, glob_b0 + s * L,
        glob_W1 + (size_t)s * 128 * L, glob_b1 + s * L,
        ln_glob_s + s * L, ln_glob_b + s * L);
  }

  decode_kernel<<<1, 128, 0, stream>>>(glob, dec_W, dec_b, gout);
}

// Round 3
// 4005.203 us; speedup vs baseline: 1.2924x; 1.2924x over previous
//
#include <hip/hip_runtime.h>

#define L 128
#define NSTEPS 2

typedef __attribute__((ext_vector_type(8))) short short8;
typedef __attribute__((ext_vector_type(4))) float f32x4;

static __device__ __forceinline__ unsigned short f2bf(float f) {
  unsigned int u = __float_as_uint(f);
  u += 0x7FFFu + ((u >> 16) & 1u);   // round-to-nearest-even
  return (unsigned short)(u >> 16);
}
static __device__ __forceinline__ unsigned short f2bf_trunc(float f) {
  return (unsigned short)(__float_as_uint(f) >> 16);  // lo-part: truncation is enough
}
static __device__ __forceinline__ float bf2f(unsigned short h) {
  return __uint_as_float(((unsigned int)h) << 16);
}

// hi[s][n][k] = bf16(in[s][k][n]) for k < Kkeep; lo = bf16(residual)
__global__ void conv_split_kernel(const float* __restrict__ in,
                                  unsigned short* __restrict__ hi,
                                  unsigned short* __restrict__ lo,
                                  int Ksrc, int Kkeep, int S) {
  int id = blockIdx.x * 256 + threadIdx.x;
  int nk = 128 * Kkeep;
  int total = S * nk;
  if (id >= total) return;
  int s = id / nk;
  int rem = id - s * nk;
  int n = rem / Kkeep;
  int k = rem - n * Kkeep;
  float x = in[(size_t)s * Ksrc * 128 + (size_t)k * 128 + n];
  unsigned short h = f2bf(x);
  hi[id] = h;
  lo[id] = f2bf(x - bf2f(h));
}

// out[m][j] = b[j] + sum_k feats[m][k] * W[k][j]   (exact fp32)
__global__ void embed_kernel(const float* __restrict__ feats, const float* __restrict__ W,
                             const float* __restrict__ bias, float* __restrict__ out,
                             int M, int K) {
  int j = threadIdx.x;  // 128
  for (int row = blockIdx.x; row < M; row += gridDim.x) {
    const float* f = feats + (size_t)row * K;
    float acc = bias[j];
    for (int k = 0; k < K; ++k) acc += f[k] * W[k * L + j];
    out[(size_t)row * L + j] = acc;
  }
}

__global__ void glob_embed_kernel(const float* __restrict__ gin, const float* __restrict__ W,
                                  const float* __restrict__ bias, float* __restrict__ glob) {
  int j = threadIdx.x;  // 128
  float acc = bias[j];
  for (int k = 0; k < 16; ++k) acc += gin[k] * W[k * L + j];
  glob[j] = acc;
}

// b0eff[j] = b0[j] + sum_k glob[k] * Wg[k][j]   (Wg = last 128 rows of W0, fp32 exact)
__global__ void fold_glob_kernel(const float* __restrict__ Wg, const float* __restrict__ b0,
                                 const float* __restrict__ glob, float* __restrict__ b0eff) {
  int j = threadIdx.x;  // 128
  float a = b0[j];
  for (int k = 0; k < 128; ++k) a += glob[k] * Wg[k * L + j];
  b0eff[j] = a;
}

// Fused per-step update. 256 threads = 4 waves; each wave owns 16 rows x 128 cols.
// A-fragments loaded straight from global (no LDS staging); split-precision bf16
// (3 MFMA products, hi*hi + lo*hi + hi*lo). Global segment folded into b0eff.
// LDS: only the hidden tile H32[64][128] as (hi<<16)|lo u32, XOR-swizzled (16B units).
template<bool EDGE_MODE>
__global__ __launch_bounds__(256, 3)
void block_step_kernel(float* __restrict__ x_io,                       // [M][128] in/out
                       const float* __restrict__ gsrc1,                // nodes | sent
                       const float* __restrict__ gsrc2,                // nodes | recv
                       const int* __restrict__ idx1, const int* __restrict__ idx2,
                       const unsigned short* __restrict__ W0h,         // [128][384] bf16 T
                       const unsigned short* __restrict__ W0l,
                       const float* __restrict__ b0eff,
                       const unsigned short* __restrict__ W1h,         // [128][128] bf16 T
                       const unsigned short* __restrict__ W1l,
                       const float* __restrict__ b1,
                       const float* __restrict__ ln_s, const float* __restrict__ ln_b,
                       float* __restrict__ scat1, float* __restrict__ scat2,
                       float* __restrict__ agg,                        // [128]
                       int M) {
  __shared__ unsigned int H32[64 * 128];   // 32 KB

  const int t = threadIdx.x;
  const int lane = t & 63;
  const int wg = t >> 6;          // wave id 0..3 -> rows wg*16..+16
  const int c = lane & 15;
  const int g = lane >> 4;        // 0..3
  const int m0 = blockIdx.x * 64;
  const int valid = min(M - m0, 64);

  // ---- per-lane A-row bases (row = wg*16 + c in the tile) ----
  const int arow = wg * 16 + c;
  const int arow_c = min(arow, valid - 1);
  const size_t grow = (size_t)(m0 + arow_c);
  const float* base0 = x_io + grow * L;
  const float* base1 = EDGE_MODE ? gsrc1 + (size_t)idx1[grow] * L : gsrc1 + grow * L;
  const float* base2 = EDGE_MODE ? gsrc2 + (size_t)idx2[grow] * L : gsrc2 + grow * L;

  const f32x4 z4 = {0.f, 0.f, 0.f, 0.f};
  f32x4 acc[8];
#pragma unroll
  for (int f = 0; f < 8; ++f) acc[f] = z4;

  // ---- layer 0: [64x384] @ [384x128], A direct from global ----
#pragma unroll
  for (int seg = 0; seg < 3; ++seg) {
    const float* bp = (seg == 0 ? base0 : (seg == 1 ? base1 : base2)) + g * 8;
#pragma unroll
    for (int kk = 0; kk < 4; ++kk) {
      const int ks = seg * 4 + kk;
      float4 v0 = *(const float4*)(bp + kk * 32);
      float4 v1 = *(const float4*)(bp + kk * 32 + 4);
      float xs[8] = {v0.x, v0.y, v0.z, v0.w, v1.x, v1.y, v1.z, v1.w};
      short8 ah, al;
#pragma unroll
      for (int j = 0; j < 8; ++j) {
        unsigned short h = f2bf(xs[j]);
        ah[j] = (short)h;
        al[j] = (short)f2bf_trunc(xs[j] - bf2f(h));
      }
#pragma unroll
      for (int fn = 0; fn < 8; ++fn) {
        size_t wb = (size_t)(fn * 16 + c) * 384 + ks * 32 + g * 8;
        short8 bh = *(const short8*)(W0h + wb);
        short8 bl = *(const short8*)(W0l + wb);
        acc[fn] = __builtin_amdgcn_mfma_f32_16x16x32_bf16(ah, bh, acc[fn], 0, 0, 0);
        acc[fn] = __builtin_amdgcn_mfma_f32_16x16x32_bf16(al, bh, acc[fn], 0, 0, 0);
        acc[fn] = __builtin_amdgcn_mfma_f32_16x16x32_bf16(ah, bl, acc[fn], 0, 0, 0);
      }
    }
  }

  // ---- hidden: relu(acc + b0eff) -> H32 (packed hi|lo, swizzled) ----
#pragma unroll
  for (int fn = 0; fn < 8; ++fn) {
    int col = fn * 16 + c;
    float bb = b0eff[col];
#pragma unroll
    for (int ri = 0; ri < 4; ++ri) {
      int row = wg * 16 + g * 4 + ri;
      float x = fmaxf(acc[fn][ri] + bb, 0.f);
      unsigned short h = f2bf(x);
      unsigned short lo = f2bf_trunc(x - bf2f(h));
      int u = (col >> 2) ^ (row & 7);
      H32[row * 128 + u * 4 + (col & 3)] = ((unsigned int)h << 16) | lo;
    }
  }
  __syncthreads();

  // ---- layer 1: [64x128] @ [128x128] ----
  f32x4 acc2[8];
#pragma unroll
  for (int f = 0; f < 8; ++f) acc2[f] = z4;
  const int hrow = arow;
#pragma unroll
  for (int ks = 0; ks < 4; ++ks) {
    int k32 = ks * 32 + g * 8;
    int u0 = ((k32 >> 2)) ^ (hrow & 7);
    int u1 = ((k32 >> 2) + 1) ^ (hrow & 7);
    uint4 q0 = *(const uint4*)&H32[hrow * 128 + u0 * 4];
    uint4 q1 = *(const uint4*)&H32[hrow * 128 + u1 * 4];
    unsigned int qs[8] = {q0.x, q0.y, q0.z, q0.w, q1.x, q1.y, q1.z, q1.w};
    short8 ah, al;
#pragma unroll
    for (int j = 0; j < 8; ++j) {
      ah[j] = (short)(qs[j] >> 16);
      al[j] = (short)(qs[j] & 0xFFFFu);
    }
#pragma unroll
    for (int fn = 0; fn < 8; ++fn) {
      size_t wb = (size_t)(fn * 16 + c) * 128 + ks * 32 + g * 8;
      short8 bh = *(const short8*)(W1h + wb);
      short8 bl = *(const short8*)(W1l + wb);
      acc2[fn] = __builtin_amdgcn_mfma_f32_16x16x32_bf16(ah, bh, acc2[fn], 0, 0, 0);
      acc2[fn] = __builtin_amdgcn_mfma_f32_16x16x32_bf16(al, bh, acc2[fn], 0, 0, 0);
      acc2[fn] = __builtin_amdgcn_mfma_f32_16x16x32_bf16(ah, bl, acc2[fn], 0, 0, 0);
    }
  }

  // ---- epilogue from registers: scatter, column-agg, residual + LN ----
  const int rbase = wg * 16 + g * 4;
  int sidx[4], ridx[4];
  if (EDGE_MODE) {
#pragma unroll
    for (int ri = 0; ri < 4; ++ri) {
      int rr = min(rbase + ri, valid - 1);
      sidx[ri] = idx1[m0 + rr];
      ridx[ri] = idx2[m0 + rr];
    }
  }
  float colagg[8];
  float sum[4] = {0.f, 0.f, 0.f, 0.f}, sq[4] = {0.f, 0.f, 0.f, 0.f};
  float xv[8][4];
#pragma unroll
  for (int fn = 0; fn < 8; ++fn) {
    colagg[fn] = 0.f;
    int col = fn * 16 + c;
    float bb = b1[col];
#pragma unroll
    for (int ri = 0; ri < 4; ++ri) {
      int row = rbase + ri;
      float e = fmaxf(acc2[fn][ri] + bb, 0.f);
      if (row < valid) {
        if (EDGE_MODE) {
          atomicAdd(scat1 + (size_t)sidx[ri] * L + col, e);
          atomicAdd(scat2 + (size_t)ridx[ri] * L + col, e);
        }
        colagg[fn] += e;
        float x = e + x_io[(size_t)(m0 + row) * L + col];
        xv[fn][ri] = x;
        sum[ri] += x;
        sq[ri] += x * x;
      } else {
        xv[fn][ri] = 0.f;
      }
    }
  }
  // row stats: reduce over the 16 lanes sharing g (masks 1,2,4,8 permute c)
#pragma unroll
  for (int mask = 1; mask <= 8; mask <<= 1) {
#pragma unroll
    for (int ri = 0; ri < 4; ++ri) {
      sum[ri] += __shfl_xor(sum[ri], mask);
      sq[ri] += __shfl_xor(sq[ri], mask);
    }
  }
  float mu[4], rs[4];
#pragma unroll
  for (int ri = 0; ri < 4; ++ri) {
    mu[ri] = sum[ri] * (1.f / 128.f);
    float var = sq[ri] * (1.f / 128.f) - mu[ri] * mu[ri];
    rs[ri] = rsqrtf(var + 1e-6f);
  }
#pragma unroll
  for (int fn = 0; fn < 8; ++fn) {
    int col = fn * 16 + c;
    float lns = ln_s[col], lnb = ln_b[col];
#pragma unroll
    for (int ri = 0; ri < 4; ++ri) {
      int row = rbase + ri;
      if (row < valid)
        x_io[(size_t)(m0 + row) * L + col] = (xv[fn][ri] - mu[ri]) * rs[ri] * lns + lnb;
    }
  }
  // column aggregate: reduce over g (masks 16,32), then one atomic per col
#pragma unroll
  for (int mask = 16; mask <= 32; mask <<= 1)
#pragma unroll
    for (int fn = 0; fn < 8; ++fn) colagg[fn] += __shfl_xor(colagg[fn], mask);
  if (lane < 16) {
#pragma unroll
    for (int fn = 0; fn < 8; ++fn) atomicAdd(agg + fn * 16 + lane, colagg[fn]);
  }
}

// single-block global update: MLP(concat(node_agg, edge_agg, glob)) + residual + LN
__global__ void glob_step_kernel(float* __restrict__ glob,
                                 const float* __restrict__ node_agg,
                                 const float* __restrict__ edge_agg,
                                 const float* __restrict__ W0, const float* __restrict__ b0,
                                 const float* __restrict__ W1, const float* __restrict__ b1,
                                 const float* __restrict__ ln_s, const float* __restrict__ ln_b) {
  __shared__ float gin[384];
  __shared__ float h[128];
  __shared__ float red4[4];
  int j = threadIdx.x;  // 128
  gin[j] = node_agg[j];
  gin[128 + j] = edge_agg[j];
  gin[256 + j] = glob[j];
  __syncthreads();
  float a = b0[j];
  for (int k = 0; k < 384; ++k) a += gin[k] * W0[k * L + j];
  h[j] = fmaxf(a, 0.f);
  __syncthreads();
  float o = b1[j];
  for (int k = 0; k < 128; ++k) o += h[k] * W1[k * L + j];
  o = fmaxf(o, 0.f);
  float x = o + glob[j];
  float sum = x, sq = x * x;
  for (int m = 1; m < 64; m <<= 1) { sum += __shfl_xor(sum, m); sq += __shfl_xor(sq, m); }
  if ((j & 63) == 0) { red4[(j >> 6) * 2] = sum; red4[(j >> 6) * 2 + 1] = sq; }
  __syncthreads();
  sum = red4[0] + red4[2]; sq = red4[1] + red4[3];
  float mu = sum * (1.f / 128.f);
  float var = sq * (1.f / 128.f) - mu * mu;
  float rsd = rsqrtf(var + 1e-6f);
  glob[j] = (x - mu) * rsd * ln_s[j] + ln_b[j];
}

__global__ void decode_kernel(const float* __restrict__ glob, const float* __restrict__ W,
                              const float* __restrict__ bias, float* __restrict__ out) {
  int j = threadIdx.x;  // 128
  float a = bias[j];
  for (int k = 0; k < 128; ++k) a += glob[k] * W[k * L + j];
  out[j] = a;
}

extern "C" void kernel_launch(void* const* d_in, const int* in_sizes, int n_in,
                              void* d_out, int out_size, void* d_ws, size_t ws_size,
                              hipStream_t stream) {
  const float* node_feats = (const float*)d_in[0];
  const float* edge_feats = (const float*)d_in[1];
  const float* globals_   = (const float*)d_in[2];
  const int*   senders    = (const int*)d_in[3];
  const int*   receivers  = (const int*)d_in[4];
  const float* emb_node_W = (const float*)d_in[5];
  const float* emb_node_b = (const float*)d_in[6];
  const float* emb_edge_W = (const float*)d_in[7];
  const float* emb_edge_b = (const float*)d_in[8];
  const float* emb_glob_W = (const float*)d_in[9];
  const float* emb_glob_b = (const float*)d_in[10];
  const float* edge_W0 = (const float*)d_in[11];
  const float* edge_b0 = (const float*)d_in[12];
  const float* edge_W1 = (const float*)d_in[13];
  const float* edge_b1 = (const float*)d_in[14];
  const float* node_W0 = (const float*)d_in[15];
  const float* node_b0 = (const float*)d_in[16];
  const float* node_W1 = (const float*)d_in[17];
  const float* node_b1 = (const float*)d_in[18];
  const float* glob_W0 = (const float*)d_in[19];
  const float* glob_b0 = (const float*)d_in[20];
  const float* glob_W1 = (const float*)d_in[21];
  const float* glob_b1 = (const float*)d_in[22];
  const float* ln_node_s = (const float*)d_in[23];
  const float* ln_node_b = (const float*)d_in[24];
  const float* ln_edge_s = (const float*)d_in[25];
  const float* ln_edge_b = (const float*)d_in[26];
  const float* ln_glob_s = (const float*)d_in[27];
  const float* ln_glob_b = (const float*)d_in[28];
  const float* dec_W = (const float*)d_in[29];
  const float* dec_b = (const float*)d_in[30];

  const int N = in_sizes[0] / 64;
  const int E = in_sizes[1] / 32;

  float* nodes = (float*)d_out;                   // [N][128]
  float* edges = nodes + (size_t)N * L;           // [E][128]
  float* gout  = edges + (size_t)E * L;           // [128]

  char* ws = (char*)d_ws;
  float* sent = (float*)ws;      ws += (size_t)N * L * 4;
  float* recv = (float*)ws;      ws += (size_t)N * L * 4;
  float* glob = (float*)ws;      ws += 512;
  float* node_agg = (float*)ws;  ws += 512;
  float* edge_agg = (float*)ws;  ws += 512;
  float* b0e_eff = (float*)ws;   ws += 512;
  float* b0n_eff = (float*)ws;   ws += 512;
  unsigned short* eW0h = (unsigned short*)ws; ws += (size_t)NSTEPS * 128 * 384 * 2;
  unsigned short* eW0l = (unsigned short*)ws; ws += (size_t)NSTEPS * 128 * 384 * 2;
  unsigned short* eW1h = (unsigned short*)ws; ws += (size_t)NSTEPS * 128 * 128 * 2;
  unsigned short* eW1l = (unsigned short*)ws; ws += (size_t)NSTEPS * 128 * 128 * 2;
  unsigned short* nW0h = (unsigned short*)ws; ws += (size_t)NSTEPS * 128 * 384 * 2;
  unsigned short* nW0l = (unsigned short*)ws; ws += (size_t)NSTEPS * 128 * 384 * 2;
  unsigned short* nW1h = (unsigned short*)ws; ws += (size_t)NSTEPS * 128 * 128 * 2;
  unsigned short* nW1l = (unsigned short*)ws; ws += (size_t)NSTEPS * 128 * 128 * 2;

  // weight prep (bf16 hi/lo, transposed, first 384 rows of W0 only)
  conv_split_kernel<<<(NSTEPS * 128 * 384 + 255) / 256, 256, 0, stream>>>(edge_W0, eW0h, eW0l, 512, 384, NSTEPS);
  conv_split_kernel<<<(NSTEPS * 128 * 128 + 255) / 256, 256, 0, stream>>>(edge_W1, eW1h, eW1l, 128, 128, NSTEPS);
  conv_split_kernel<<<(NSTEPS * 128 * 384 + 255) / 256, 256, 0, stream>>>(node_W0, nW0h, nW0l, 512, 384, NSTEPS);
  conv_split_kernel<<<(NSTEPS * 128 * 128 + 255) / 256, 256, 0, stream>>>(node_W1, nW1h, nW1l, 128, 128, NSTEPS);

  // embeddings (exact fp32)
  embed_kernel<<<2048, 128, 0, stream>>>(node_feats, emb_node_W, emb_node_b, nodes, N, 64);
  embed_kernel<<<4096, 128, 0, stream>>>(edge_feats, emb_edge_W, emb_edge_b, edges, E, 32);
  glob_embed_kernel<<<1, 128, 0, stream>>>(globals_, emb_glob_W, emb_glob_b, glob);

  const int egrid = (E + 63) / 64;
  const int ngrid = (N + 63) / 64;
  for (int s = 0; s < NSTEPS; ++s) {
    hipMemsetAsync(sent, 0, (size_t)N * L * 4, stream);
    hipMemsetAsync(recv, 0, (size_t)N * L * 4, stream);
    hipMemsetAsync(node_agg, 0, 512, stream);
    hipMemsetAsync(edge_agg, 0, 512, stream);

    fold_glob_kernel<<<1, 128, 0, stream>>>(edge_W0 + (size_t)s * 512 * L + 384 * L,
                                            edge_b0 + s * L, glob, b0e_eff);
    fold_glob_kernel<<<1, 128, 0, stream>>>(node_W0 + (size_t)s * 512 * L + 384 * L,
                                            node_b0 + s * L, glob, b0n_eff);

    block_step_kernel<true><<<egrid, 256, 0, stream>>>(
        edges, nodes, nodes, senders, receivers,
        eW0h + (size_t)s * 128 * 384, eW0l + (size_t)s * 128 * 384, b0e_eff,
        eW1h + (size_t)s * 128 * 128, eW1l + (size_t)s * 128 * 128, edge_b1 + s * L,
        ln_edge_s + s * L, ln_edge_b + s * L,
        sent, recv, edge_agg, E);

    block_step_kernel<false><<<ngrid, 256, 0, stream>>>(
        nodes, sent, recv, nullptr, nullptr,
        nW0h + (size_t)s * 128 * 384, nW0l + (size_t)s * 128 * 384, b0n_eff,
        nW1h + (size_t)s * 128 * 128, nW1l + (size_t)s * 128 * 128, node_b1 + s * L,
        ln_node_s + s * L, ln_node_b + s * L,
        nullptr, nullptr, node_agg, N);

    glob_step_kernel<<<1, 128, 0, stream>>>(
        glob, node_agg, edge_agg,
        glob_W0 + (size_t)s * 384 * L, glob_b0 + s * L,
        glob_W1 + (size_t)s * 128 * L, glob_b1 + s * L,
        ln_glob_s + s * L, ln_glob_b + s * L);
  }

  decode_kernel<<<1, 128, 0, stream>>>(glob, dec_W, dec_b, gout);
}

// Round 4
// 3895.169 us; speedup vs baseline: 1.3289x; 1.0282x over previous
//
#include <hip/hip_runtime.h>

#define L 128
#define NSTEPS 2
#define SCAN_B 250

typedef __attribute__((ext_vector_type(8))) short short8;
typedef __attribute__((ext_vector_type(4))) float f32x4;

static __device__ __forceinline__ unsigned short f2bf(float f) {
  unsigned int u = __float_as_uint(f);
  u += 0x7FFFu + ((u >> 16) & 1u);   // round-to-nearest-even
  return (unsigned short)(u >> 16);
}
static __device__ __forceinline__ unsigned short f2bf_trunc(float f) {
  return (unsigned short)(__float_as_uint(f) >> 16);  // lo-part: truncation is enough
}
static __device__ __forceinline__ float bf2f(unsigned short h) {
  return __uint_as_float(((unsigned int)h) << 16);
}

// hi[s][n][k] = bf16(in[s][k][n]) for k < Kkeep; lo = bf16(residual)
__global__ void conv_split_kernel(const float* __restrict__ in,
                                  unsigned short* __restrict__ hi,
                                  unsigned short* __restrict__ lo,
                                  int Ksrc, int Kkeep, int S) {
  int id = blockIdx.x * 256 + threadIdx.x;
  int nk = 128 * Kkeep;
  int total = S * nk;
  if (id >= total) return;
  int s = id / nk;
  int rem = id - s * nk;
  int n = rem / Kkeep;
  int k = rem - n * Kkeep;
  float x = in[(size_t)s * Ksrc * 128 + (size_t)k * 128 + n];
  unsigned short h = f2bf(x);
  hi[id] = h;
  lo[id] = f2bf(x - bf2f(h));
}

__global__ void embed_kernel(const float* __restrict__ feats, const float* __restrict__ W,
                             const float* __restrict__ bias, float* __restrict__ out,
                             int M, int K) {
  int j = threadIdx.x;  // 128
  for (int row = blockIdx.x; row < M; row += gridDim.x) {
    const float* f = feats + (size_t)row * K;
    float acc = bias[j];
    for (int k = 0; k < K; ++k) acc += f[k] * W[k * L + j];
    out[(size_t)row * L + j] = acc;
  }
}

__global__ void glob_embed_kernel(const float* __restrict__ gin, const float* __restrict__ W,
                                  const float* __restrict__ bias, float* __restrict__ glob) {
  int j = threadIdx.x;  // 128
  float acc = bias[j];
  for (int k = 0; k < 16; ++k) acc += gin[k] * W[k * L + j];
  glob[j] = acc;
}

__global__ void fold_glob_kernel(const float* __restrict__ Wg, const float* __restrict__ b0,
                                 const float* __restrict__ glob, float* __restrict__ b0eff) {
  int j = threadIdx.x;  // 128
  float a = b0[j];
  for (int k = 0; k < 128; ++k) a += glob[k] * Wg[k * L + j];
  b0eff[j] = a;
}

// ---------------- CSR build ----------------
__global__ void hist_kernel(const int* __restrict__ senders, const int* __restrict__ receivers,
                            int* __restrict__ cnt1, int* __restrict__ cnt2, int E) {
  int e = blockIdx.x * 256 + threadIdx.x;
  if (e >= E) return;
  atomicAdd(&cnt1[senders[e]], 1);
  atomicAdd(&cnt2[receivers[e]], 1);
}

__global__ void scan_sum_kernel(const int* __restrict__ cnt, int* __restrict__ part,
                                int n, int chunk) {
  __shared__ int red[256];
  int b = blockIdx.x, t = threadIdx.x;
  int lo = b * chunk, hi = min(lo + chunk, n);
  red[t] = (lo + t < hi) ? cnt[lo + t] : 0;
  __syncthreads();
  for (int o = 128; o > 0; o >>= 1) { if (t < o) red[t] += red[t + o]; __syncthreads(); }
  if (t == 0) part[b] = red[0];
}

__global__ void scan_part_kernel(int* __restrict__ part, int nb) {
  if (threadIdx.x == 0) {
    int run = 0;
    for (int i = 0; i < nb; ++i) { int v = part[i]; part[i] = run; run += v; }
  }
}

__global__ void scan_write_kernel(const int* __restrict__ cnt, const int* __restrict__ part,
                                  int* __restrict__ rp, int n, int chunk, int E) {
  __shared__ int buf[256];
  int b = blockIdx.x, t = threadIdx.x;
  int lo = b * chunk, hi = min(lo + chunk, n);
  buf[t] = (lo + t < hi) ? cnt[lo + t] : 0;
  __syncthreads();
  if (t == 0) {
    int run = part[b];
    for (int i = 0; i < hi - lo; ++i) { rp[lo + i] = run; run += buf[i]; }
  }
  if (b == gridDim.x - 1 && t == 0) rp[n] = E;
}

__global__ void fill_kernel(const int* __restrict__ senders, const int* __restrict__ receivers,
                            const int* __restrict__ rp1, const int* __restrict__ rp2,
                            int* __restrict__ cnt1, int* __restrict__ cnt2,
                            int* __restrict__ el1, int* __restrict__ el2, int E) {
  int e = blockIdx.x * 256 + threadIdx.x;
  if (e >= E) return;
  int s = senders[e];
  int p = atomicAdd(&cnt1[s], 1);
  el1[rp1[s] + p] = e;
  int r = receivers[e];
  int q = atomicAdd(&cnt2[r], 1);
  el2[rp2[r] + q] = e;
}

// sent[v][col] = sum over CSR sender-edges of e_buf; recv likewise. No atomics.
__global__ __launch_bounds__(256) void gather_kernel(
    const float* __restrict__ e_buf,
    const int* __restrict__ rp1, const int* __restrict__ el1,
    const int* __restrict__ rp2, const int* __restrict__ el2,
    float* __restrict__ sent, float* __restrict__ recv, int N) {
  int t = threadIdx.x;
  int v = blockIdx.x * 2 + (t >> 7);
  if (v >= N) return;
  int col = t & 127;
  float s1 = 0.f;
  int a1 = rp1[v], b1 = rp1[v + 1];
  for (int j = a1; j < b1; ++j) s1 += e_buf[(size_t)el1[j] * L + col];
  float s2 = 0.f;
  int a2 = rp2[v], b2 = rp2[v + 1];
  for (int j = a2; j < b2; ++j) s2 += e_buf[(size_t)el2[j] * L + col];
  sent[(size_t)v * L + col] = s1;
  recv[(size_t)v * L + col] = s2;
}

// Fused per-step update. ROWS*4 threads = ROWS/16 waves; each wave owns 16 rows x 128 cols.
// A-fragments from global; split-precision bf16 (hi*hi + lo*hi + hi*lo). Glob folded in b0eff.
// LDS: hidden tile H32[ROWS][128] as (hi<<16)|lo u32, XOR-swizzled in 16B units.
// CSR: edge mode writes raw e_new to e_buf (no scatter atomics); else atomic scatter.
template<int ROWS, bool EDGE_MODE, bool CSR>
__global__ __launch_bounds__(ROWS * 4, 4)
void block_step_kernel(float* __restrict__ x_io,
                       const float* __restrict__ gsrc1,
                       const float* __restrict__ gsrc2,
                       const int* __restrict__ idx1, const int* __restrict__ idx2,
                       const unsigned short* __restrict__ W0h,
                       const unsigned short* __restrict__ W0l,
                       const float* __restrict__ b0eff,
                       const unsigned short* __restrict__ W1h,
                       const unsigned short* __restrict__ W1l,
                       const float* __restrict__ b1,
                       const float* __restrict__ ln_s, const float* __restrict__ ln_b,
                       float* __restrict__ scat1, float* __restrict__ scat2,
                       float* __restrict__ agg, float* __restrict__ e_buf,
                       int M) {
  constexpr int W = ROWS / 16;
  __shared__ unsigned int H32[ROWS * 128];

  const int t = threadIdx.x;
  const int lane = t & 63;
  const int wg = t >> 6;          // wave id -> rows wg*16..+16
  const int c = lane & 15;
  const int g = lane >> 4;        // 0..3
  const int m0 = blockIdx.x * ROWS;
  const int valid = min(M - m0, ROWS);

  const int arow = wg * 16 + c;
  const int arow_c = min(arow, valid - 1);
  const size_t grow = (size_t)(m0 + arow_c);
  const float* base0 = x_io + grow * L;
  const float* base1 = EDGE_MODE ? gsrc1 + (size_t)idx1[grow] * L : gsrc1 + grow * L;
  const float* base2 = EDGE_MODE ? gsrc2 + (size_t)idx2[grow] * L : gsrc2 + grow * L;

  const f32x4 z4 = {0.f, 0.f, 0.f, 0.f};
  f32x4 acc[8];
#pragma unroll
  for (int f = 0; f < 8; ++f) acc[f] = z4;

  // ---- layer 0: [ROWS x 384] @ [384 x 128], A direct from global ----
#pragma unroll
  for (int seg = 0; seg < 3; ++seg) {
    const float* bp = (seg == 0 ? base0 : (seg == 1 ? base1 : base2)) + g * 8;
#pragma unroll
    for (int kk = 0; kk < 4; ++kk) {
      const int ks = seg * 4 + kk;
      float4 v0 = *(const float4*)(bp + kk * 32);
      float4 v1 = *(const float4*)(bp + kk * 32 + 4);
      float xs[8] = {v0.x, v0.y, v0.z, v0.w, v1.x, v1.y, v1.z, v1.w};
      short8 ah, al;
#pragma unroll
      for (int j = 0; j < 8; ++j) {
        unsigned short h = f2bf(xs[j]);
        ah[j] = (short)h;
        al[j] = (short)f2bf_trunc(xs[j] - bf2f(h));
      }
#pragma unroll
      for (int fn = 0; fn < 8; ++fn) {
        size_t wb = (size_t)(fn * 16 + c) * 384 + ks * 32 + g * 8;
        short8 bh = *(const short8*)(W0h + wb);
        short8 bl = *(const short8*)(W0l + wb);
        acc[fn] = __builtin_amdgcn_mfma_f32_16x16x32_bf16(ah, bh, acc[fn], 0, 0, 0);
        acc[fn] = __builtin_amdgcn_mfma_f32_16x16x32_bf16(al, bh, acc[fn], 0, 0, 0);
        acc[fn] = __builtin_amdgcn_mfma_f32_16x16x32_bf16(ah, bl, acc[fn], 0, 0, 0);
      }
    }
  }

  // ---- hidden: relu(acc + b0eff) -> H32 (packed hi|lo, swizzled; wave-private stripe) ----
#pragma unroll
  for (int fn = 0; fn < 8; ++fn) {
    int col = fn * 16 + c;
    float bb = b0eff[col];
#pragma unroll
    for (int ri = 0; ri < 4; ++ri) {
      int row = wg * 16 + g * 4 + ri;
      float x = fmaxf(acc[fn][ri] + bb, 0.f);
      unsigned short h = f2bf(x);
      unsigned short lo = f2bf_trunc(x - bf2f(h));
      int u = (col >> 2) ^ (row & 7);
      H32[row * 128 + u * 4 + (col & 3)] = ((unsigned int)h << 16) | lo;
    }
  }
  // no barrier: each wave reads only its own 16-row stripe

  // ---- layer 1: [ROWS x 128] @ [128 x 128] ----
  f32x4 acc2[8];
#pragma unroll
  for (int f = 0; f < 8; ++f) acc2[f] = z4;
  const int hrow = arow;
#pragma unroll
  for (int ks = 0; ks < 4; ++ks) {
    int k32 = ks * 32 + g * 8;
    int u0 = ((k32 >> 2)) ^ (hrow & 7);
    int u1 = ((k32 >> 2) + 1) ^ (hrow & 7);
    uint4 q0 = *(const uint4*)&H32[hrow * 128 + u0 * 4];
    uint4 q1 = *(const uint4*)&H32[hrow * 128 + u1 * 4];
    unsigned int qs[8] = {q0.x, q0.y, q0.z, q0.w, q1.x, q1.y, q1.z, q1.w};
    short8 ah, al;
#pragma unroll
    for (int j = 0; j < 8; ++j) {
      ah[j] = (short)(qs[j] >> 16);
      al[j] = (short)(qs[j] & 0xFFFFu);
    }
#pragma unroll
    for (int fn = 0; fn < 8; ++fn) {
      size_t wb = (size_t)(fn * 16 + c) * 128 + ks * 32 + g * 8;
      short8 bh = *(const short8*)(W1h + wb);
      short8 bl = *(const short8*)(W1l + wb);
      acc2[fn] = __builtin_amdgcn_mfma_f32_16x16x32_bf16(ah, bh, acc2[fn], 0, 0, 0);
      acc2[fn] = __builtin_amdgcn_mfma_f32_16x16x32_bf16(al, bh, acc2[fn], 0, 0, 0);
      acc2[fn] = __builtin_amdgcn_mfma_f32_16x16x32_bf16(ah, bl, acc2[fn], 0, 0, 0);
    }
  }

  // ---- epilogue from registers ----
  const int rbase = wg * 16 + g * 4;
  int sidx[4], ridx[4];
  if (EDGE_MODE && !CSR) {
#pragma unroll
    for (int ri = 0; ri < 4; ++ri) {
      int rr = min(rbase + ri, valid - 1);
      sidx[ri] = idx1[m0 + rr];
      ridx[ri] = idx2[m0 + rr];
    }
  }
  float colagg[8];
  float sum[4] = {0.f, 0.f, 0.f, 0.f}, sq[4] = {0.f, 0.f, 0.f, 0.f};
  float xv[8][4];
#pragma unroll
  for (int fn = 0; fn < 8; ++fn) {
    colagg[fn] = 0.f;
    int col = fn * 16 + c;
    float bb = b1[col];
#pragma unroll
    for (int ri = 0; ri < 4; ++ri) {
      int row = rbase + ri;
      float e = fmaxf(acc2[fn][ri] + bb, 0.f);
      if (row < valid) {
        if (EDGE_MODE) {
          if (CSR) {
            e_buf[(size_t)(m0 + row) * L + col] = e;
          } else {
            atomicAdd(scat1 + (size_t)sidx[ri] * L + col, e);
            atomicAdd(scat2 + (size_t)ridx[ri] * L + col, e);
          }
        }
        colagg[fn] += e;
        float x = e + x_io[(size_t)(m0 + row) * L + col];
        xv[fn][ri] = x;
        sum[ri] += x;
        sq[ri] += x * x;
      } else {
        xv[fn][ri] = 0.f;
      }
    }
  }
  // row stats: reduce over the 16 lanes sharing g
#pragma unroll
  for (int mask = 1; mask <= 8; mask <<= 1) {
#pragma unroll
    for (int ri = 0; ri < 4; ++ri) {
      sum[ri] += __shfl_xor(sum[ri], mask);
      sq[ri] += __shfl_xor(sq[ri], mask);
    }
  }
  float mu[4], rs[4];
#pragma unroll
  for (int ri = 0; ri < 4; ++ri) {
    mu[ri] = sum[ri] * (1.f / 128.f);
    float var = sq[ri] * (1.f / 128.f) - mu[ri] * mu[ri];
    rs[ri] = rsqrtf(var + 1e-6f);
  }
#pragma unroll
  for (int fn = 0; fn < 8; ++fn) {
    int col = fn * 16 + c;
    float lns = ln_s[col], lnb = ln_b[col];
#pragma unroll
    for (int ri = 0; ri < 4; ++ri) {
      int row = rbase + ri;
      if (row < valid)
        x_io[(size_t)(m0 + row) * L + col] = (xv[fn][ri] - mu[ri]) * rs[ri] * lns + lnb;
    }
  }
  // column aggregate: reduce over g, then LDS-reduce across waves, 128 atomics/block
#pragma unroll
  for (int mask = 16; mask <= 32; mask <<= 1)
#pragma unroll
    for (int fn = 0; fn < 8; ++fn) colagg[fn] += __shfl_xor(colagg[fn], mask);
  __syncthreads();                 // all H32 reads complete; reuse as float scratch
  float* F = (float*)H32;
  if (lane < 16) {
#pragma unroll
    for (int fn = 0; fn < 8; ++fn) F[wg * 128 + fn * 16 + lane] = colagg[fn];
  }
  __syncthreads();
  if (t < 128) {
    float s = 0.f;
#pragma unroll
    for (int w = 0; w < W; ++w) s += F[w * 128 + t];
    atomicAdd(agg + t, s);
  }
}

__global__ void glob_step_kernel(float* __restrict__ glob,
                                 const float* __restrict__ node_agg,
                                 const float* __restrict__ edge_agg,
                                 const float* __restrict__ W0, const float* __restrict__ b0,
                                 const float* __restrict__ W1, const float* __restrict__ b1,
                                 const float* __restrict__ ln_s, const float* __restrict__ ln_b) {
  __shared__ float gin[384];
  __shared__ float h[128];
  __shared__ float red4[4];
  int j = threadIdx.x;  // 128
  gin[j] = node_agg[j];
  gin[128 + j] = edge_agg[j];
  gin[256 + j] = glob[j];
  __syncthreads();
  float a = b0[j];
  for (int k = 0; k < 384; ++k) a += gin[k] * W0[k * L + j];
  h[j] = fmaxf(a, 0.f);
  __syncthreads();
  float o = b1[j];
  for (int k = 0; k < 128; ++k) o += h[k] * W1[k * L + j];
  o = fmaxf(o, 0.f);
  float x = o + glob[j];
  float sum = x, sq = x * x;
  for (int m = 1; m < 64; m <<= 1) { sum += __shfl_xor(sum, m); sq += __shfl_xor(sq, m); }
  if ((j & 63) == 0) { red4[(j >> 6) * 2] = sum; red4[(j >> 6) * 2 + 1] = sq; }
  __syncthreads();
  sum = red4[0] + red4[2]; sq = red4[1] + red4[3];
  float mu = sum * (1.f / 128.f);
  float var = sq * (1.f / 128.f) - mu * mu;
  float rsd = rsqrtf(var + 1e-6f);
  glob[j] = (x - mu) * rsd * ln_s[j] + ln_b[j];
}

__global__ void decode_kernel(const float* __restrict__ glob, const float* __restrict__ W,
                              const float* __restrict__ bias, float* __restrict__ out) {
  int j = threadIdx.x;  // 128
  float a = bias[j];
  for (int k = 0; k < 128; ++k) a += glob[k] * W[k * L + j];
  out[j] = a;
}

extern "C" void kernel_launch(void* const* d_in, const int* in_sizes, int n_in,
                              void* d_out, int out_size, void* d_ws, size_t ws_size,
                              hipStream_t stream) {
  const float* node_feats = (const float*)d_in[0];
  const float* edge_feats = (const float*)d_in[1];
  const float* globals_   = (const float*)d_in[2];
  const int*   senders    = (const int*)d_in[3];
  const int*   receivers  = (const int*)d_in[4];
  const float* emb_node_W = (const float*)d_in[5];
  const float* emb_node_b = (const float*)d_in[6];
  const float* emb_edge_W = (const float*)d_in[7];
  const float* emb_edge_b = (const float*)d_in[8];
  const float* emb_glob_W = (const float*)d_in[9];
  const float* emb_glob_b = (const float*)d_in[10];
  const float* edge_W0 = (const float*)d_in[11];
  const float* edge_b0 = (const float*)d_in[12];
  const float* edge_W1 = (const float*)d_in[13];
  const float* edge_b1 = (const float*)d_in[14];
  const float* node_W0 = (const float*)d_in[15];
  const float* node_b0 = (const float*)d_in[16];
  const float* node_W1 = (const float*)d_in[17];
  const float* node_b1 = (const float*)d_in[18];
  const float* glob_W0 = (const float*)d_in[19];
  const float* glob_b0 = (const float*)d_in[20];
  const float* glob_W1 = (const float*)d_in[21];
  const float* glob_b1 = (const float*)d_in[22];
  const float* ln_node_s = (const float*)d_in[23];
  const float* ln_node_b = (const float*)d_in[24];
  const float* ln_edge_s = (const float*)d_in[25];
  const float* ln_edge_b = (const float*)d_in[26];
  const float* ln_glob_s = (const float*)d_in[27];
  const float* ln_glob_b = (const float*)d_in[28];
  const float* dec_W = (const float*)d_in[29];
  const float* dec_b = (const float*)d_in[30];

  const int N = in_sizes[0] / 64;
  const int E = in_sizes[1] / 32;

  float* nodes = (float*)d_out;                   // [N][128]
  float* edges = nodes + (size_t)N * L;           // [E][128]
  float* gout  = edges + (size_t)E * L;           // [128]

  char* wp = (char*)d_ws;
  auto alloc = [&](size_t bytes) -> char* {
    char* p = wp;
    wp += (bytes + 255) & ~(size_t)255;
    return p;
  };
  float* sent = (float*)alloc((size_t)N * L * 4);
  float* recv = (float*)alloc((size_t)N * L * 4);
  float* glob = (float*)alloc(512);
  float* node_agg = (float*)alloc(512);
  float* edge_agg = (float*)alloc(512);
  float* b0e_eff = (float*)alloc(512);
  float* b0n_eff = (float*)alloc(512);
  unsigned short* eW0h = (unsigned short*)alloc((size_t)NSTEPS * 128 * 384 * 2);
  unsigned short* eW0l = (unsigned short*)alloc((size_t)NSTEPS * 128 * 384 * 2);
  unsigned short* eW1h = (unsigned short*)alloc((size_t)NSTEPS * 128 * 128 * 2);
  unsigned short* eW1l = (unsigned short*)alloc((size_t)NSTEPS * 128 * 128 * 2);
  unsigned short* nW0h = (unsigned short*)alloc((size_t)NSTEPS * 128 * 384 * 2);
  unsigned short* nW0l = (unsigned short*)alloc((size_t)NSTEPS * 128 * 384 * 2);
  unsigned short* nW1h = (unsigned short*)alloc((size_t)NSTEPS * 128 * 128 * 2);
  unsigned short* nW1l = (unsigned short*)alloc((size_t)NSTEPS * 128 * 128 * 2);
  int* rp1 = (int*)alloc((size_t)(N + 1) * 4);
  int* rp2 = (int*)alloc((size_t)(N + 1) * 4);
  int* cnt1 = (int*)alloc((size_t)N * 4);
  int* cnt2 = (int*)alloc((size_t)N * 4);
  int* el1 = (int*)alloc((size_t)E * 4);
  int* el2 = (int*)alloc((size_t)E * 4);
  int* part = (int*)alloc(SCAN_B * 4);
  size_t before_ebuf = (size_t)(wp - (char*)d_ws);
  float* e_buf = (float*)alloc((size_t)E * L * 4);
  size_t need = (size_t)(wp - (char*)d_ws);
  const bool csr = ws_size >= need;

  // weight prep (bf16 hi/lo, transposed, first 384 rows of W0 only)
  conv_split_kernel<<<(NSTEPS * 128 * 384 + 255) / 256, 256, 0, stream>>>(edge_W0, eW0h, eW0l, 512, 384, NSTEPS);
  conv_split_kernel<<<(NSTEPS * 128 * 128 + 255) / 256, 256, 0, stream>>>(edge_W1, eW1h, eW1l, 128, 128, NSTEPS);
  conv_split_kernel<<<(NSTEPS * 128 * 384 + 255) / 256, 256, 0, stream>>>(node_W0, nW0h, nW0l, 512, 384, NSTEPS);
  conv_split_kernel<<<(NSTEPS * 128 * 128 + 255) / 256, 256, 0, stream>>>(node_W1, nW1h, nW1l, 128, 128, NSTEPS);

  // embeddings (exact fp32)
  embed_kernel<<<2048, 128, 0, stream>>>(node_feats, emb_node_W, emb_node_b, nodes, N, 64);
  embed_kernel<<<4096, 128, 0, stream>>>(edge_feats, emb_edge_W, emb_edge_b, edges, E, 32);
  glob_embed_kernel<<<1, 128, 0, stream>>>(globals_, emb_glob_W, emb_glob_b, glob);

  const int egrid = (E + 63) / 64;
  const int ngrid = (N + 31) / 32;
  const int chunk = (N + SCAN_B - 1) / SCAN_B;

  if (csr) {
    // build CSR by sender and receiver (once per launch)
    hipMemsetAsync(cnt1, 0, (size_t)N * 4, stream);
    hipMemsetAsync(cnt2, 0, (size_t)N * 4, stream);
    hist_kernel<<<(E + 255) / 256, 256, 0, stream>>>(senders, receivers, cnt1, cnt2, E);
    scan_sum_kernel<<<SCAN_B, 256, 0, stream>>>(cnt1, part, N, chunk);
    scan_part_kernel<<<1, 64, 0, stream>>>(part, SCAN_B);
    scan_write_kernel<<<SCAN_B, 256, 0, stream>>>(cnt1, part, rp1, N, chunk, E);
    scan_sum_kernel<<<SCAN_B, 256, 0, stream>>>(cnt2, part, N, chunk);
    scan_part_kernel<<<1, 64, 0, stream>>>(part, SCAN_B);
    scan_write_kernel<<<SCAN_B, 256, 0, stream>>>(cnt2, part, rp2, N, chunk, E);
    hipMemsetAsync(cnt1, 0, (size_t)N * 4, stream);
    hipMemsetAsync(cnt2, 0, (size_t)N * 4, stream);
    fill_kernel<<<(E + 255) / 256, 256, 0, stream>>>(senders, receivers, rp1, rp2, cnt1, cnt2, el1, el2, E);
  }

  for (int s = 0; s < NSTEPS; ++s) {
    hipMemsetAsync(node_agg, 0, 512, stream);
    hipMemsetAsync(edge_agg, 0, 512, stream);
    if (!csr) {
      hipMemsetAsync(sent, 0, (size_t)N * L * 4, stream);
      hipMemsetAsync(recv, 0, (size_t)N * L * 4, stream);
    }

    fold_glob_kernel<<<1, 128, 0, stream>>>(edge_W0 + (size_t)s * 512 * L + 384 * L,
                                            edge_b0 + s * L, glob, b0e_eff);
    fold_glob_kernel<<<1, 128, 0, stream>>>(node_W0 + (size_t)s * 512 * L + 384 * L,
                                            node_b0 + s * L, glob, b0n_eff);

    if (csr) {
      block_step_kernel<64, true, true><<<egrid, 256, 0, stream>>>(
          edges, nodes, nodes, senders, receivers,
          eW0h + (size_t)s * 128 * 384, eW0l + (size_t)s * 128 * 384, b0e_eff,
          eW1h + (size_t)s * 128 * 128, eW1l + (size_t)s * 128 * 128, edge_b1 + s * L,
          ln_edge_s + s * L, ln_edge_b + s * L,
          nullptr, nullptr, edge_agg, e_buf, E);
      gather_kernel<<<(N + 1) / 2, 256, 0, stream>>>(e_buf, rp1, el1, rp2, el2, sent, recv, N);
    } else {
      block_step_kernel<64, true, false><<<egrid, 256, 0, stream>>>(
          edges, nodes, nodes, senders, receivers,
          eW0h + (size_t)s * 128 * 384, eW0l + (size_t)s * 128 * 384, b0e_eff,
          eW1h + (size_t)s * 128 * 128, eW1l + (size_t)s * 128 * 128, edge_b1 + s * L,
          ln_edge_s + s * L, ln_edge_b + s * L,
          sent, recv, edge_agg, nullptr, E);
    }

    block_step_kernel<32, false, false><<<ngrid, 128, 0, stream>>>(
        nodes, sent, recv, nullptr, nullptr,
        nW0h + (size_t)s * 128 * 384, nW0l + (size_t)s * 128 * 384, b0n_eff,
        nW1h + (size_t)s * 128 * 128, nW1l + (size_t)s * 128 * 128, node_b1 + s * L,
        ln_node_s + s * L, ln_node_b + s * L,
        nullptr, nullptr, node_agg, nullptr, N);

    glob_step_kernel<<<1, 128, 0, stream>>>(
        glob, node_agg, edge_agg,
        glob_W0 + (size_t)s * 384 * L, glob_b0 + s * L,
        glob_W1 + (size_t)s * 128 * L, glob_b1 + s * L,
        ln_glob_s + s * L, ln_glob_b + s * L);
  }

  decode_kernel<<<1, 128, 0, stream>>>(glob, dec_W, dec_b, gout);
  (void)before_ebuf;
}

// Round 5
// 2961.681 us; speedup vs baseline: 1.7478x; 1.3152x over previous
//
#include <hip/hip_runtime.h>

#define L 128
#define NSTEPS 2
#define SCAN_B 250

typedef __attribute__((ext_vector_type(8))) short short8;
typedef __attribute__((ext_vector_type(4))) float f32x4;

static __device__ __forceinline__ unsigned short f2bf(float f) {
  unsigned int u = __float_as_uint(f);
  u += 0x7FFFu + ((u >> 16) & 1u);   // round-to-nearest-even
  return (unsigned short)(u >> 16);
}
static __device__ __forceinline__ unsigned short f2bf_trunc(float f) {
  return (unsigned short)(__float_as_uint(f) >> 16);  // lo-part: truncation is enough
}
static __device__ __forceinline__ float bf2f(unsigned short h) {
  return __uint_as_float(((unsigned int)h) << 16);
}

// hi[s][n][k] = bf16(in[s][k][n]) for k < Kkeep; lo = bf16(residual)
__global__ void conv_split_kernel(const float* __restrict__ in,
                                  unsigned short* __restrict__ hi,
                                  unsigned short* __restrict__ lo,
                                  int Ksrc, int Kkeep, int S) {
  int id = blockIdx.x * 256 + threadIdx.x;
  int nk = 128 * Kkeep;
  int total = S * nk;
  if (id >= total) return;
  int s = id / nk;
  int rem = id - s * nk;
  int n = rem / Kkeep;
  int k = rem - n * Kkeep;
  float x = in[(size_t)s * Ksrc * 128 + (size_t)k * 128 + n];
  unsigned short h = f2bf(x);
  hi[id] = h;
  lo[id] = f2bf(x - bf2f(h));
}

__global__ void embed_kernel(const float* __restrict__ feats, const float* __restrict__ W,
                             const float* __restrict__ bias, float* __restrict__ out,
                             int M, int K) {
  int j = threadIdx.x;  // 128
  for (int row = blockIdx.x; row < M; row += gridDim.x) {
    const float* f = feats + (size_t)row * K;
    float acc = bias[j];
    for (int k = 0; k < K; ++k) acc += f[k] * W[k * L + j];
    out[(size_t)row * L + j] = acc;
  }
}

__global__ void glob_embed_kernel(const float* __restrict__ gin, const float* __restrict__ W,
                                  const float* __restrict__ bias, float* __restrict__ glob) {
  int j = threadIdx.x;  // 128
  float acc = bias[j];
  for (int k = 0; k < 16; ++k) acc += gin[k] * W[k * L + j];
  glob[j] = acc;
}

__global__ void fold_glob_kernel(const float* __restrict__ Wg, const float* __restrict__ b0,
                                 const float* __restrict__ glob, float* __restrict__ b0eff) {
  int j = threadIdx.x;  // 128
  float a = b0[j];
  for (int k = 0; k < 128; ++k) a += glob[k] * Wg[k * L + j];
  b0eff[j] = a;
}

// ---------------- CSR build ----------------
__global__ void hist_kernel(const int* __restrict__ senders, const int* __restrict__ receivers,
                            int* __restrict__ cnt1, int* __restrict__ cnt2, int E) {
  int e = blockIdx.x * 256 + threadIdx.x;
  if (e >= E) return;
  atomicAdd(&cnt1[senders[e]], 1);
  atomicAdd(&cnt2[receivers[e]], 1);
}

__global__ void scan_sum_kernel(const int* __restrict__ cnt, int* __restrict__ part,
                                int n, int chunk) {
  __shared__ int red[256];
  int b = blockIdx.x, t = threadIdx.x;
  int lo = b * chunk, hi = min(lo + chunk, n);
  red[t] = (lo + t < hi) ? cnt[lo + t] : 0;
  __syncthreads();
  for (int o = 128; o > 0; o >>= 1) { if (t < o) red[t] += red[t + o]; __syncthreads(); }
  if (t == 0) part[b] = red[0];
}

__global__ void scan_part_kernel(int* __restrict__ part, int nb) {
  if (threadIdx.x == 0) {
    int run = 0;
    for (int i = 0; i < nb; ++i) { int v = part[i]; part[i] = run; run += v; }
  }
}

__global__ void scan_write_kernel(const int* __restrict__ cnt, const int* __restrict__ part,
                                  int* __restrict__ rp, int n, int chunk, int E) {
  __shared__ int buf[256];
  int b = blockIdx.x, t = threadIdx.x;
  int lo = b * chunk, hi = min(lo + chunk, n);
  buf[t] = (lo + t < hi) ? cnt[lo + t] : 0;
  __syncthreads();
  if (t == 0) {
    int run = part[b];
    for (int i = 0; i < hi - lo; ++i) { rp[lo + i] = run; run += buf[i]; }
  }
  if (b == gridDim.x - 1 && t == 0) rp[n] = E;
}

__global__ void fill_kernel(const int* __restrict__ senders, const int* __restrict__ receivers,
                            const int* __restrict__ rp1, const int* __restrict__ rp2,
                            int* __restrict__ cnt1, int* __restrict__ cnt2,
                            int* __restrict__ el1, int* __restrict__ el2, int E) {
  int e = blockIdx.x * 256 + threadIdx.x;
  if (e >= E) return;
  int s = senders[e];
  int p = atomicAdd(&cnt1[s], 1);
  el1[rp1[s] + p] = e;
  int r = receivers[e];
  int q = atomicAdd(&cnt2[r], 1);
  el2[rp2[r] + q] = e;
}

// sent[v][col] = sum over CSR sender-edges of e_buf; recv likewise. No atomics.
__global__ __launch_bounds__(256) void gather_kernel(
    const float* __restrict__ e_buf,
    const int* __restrict__ rp1, const int* __restrict__ el1,
    const int* __restrict__ rp2, const int* __restrict__ el2,
    float* __restrict__ sent, float* __restrict__ recv, int N) {
  int t = threadIdx.x;
  int v = blockIdx.x * 2 + (t >> 7);
  if (v >= N) return;
  int col = t & 127;
  float s1 = 0.f;
  int a1 = rp1[v], b1 = rp1[v + 1];
  for (int j = a1; j < b1; ++j) s1 += e_buf[(size_t)el1[j] * L + col];
  float s2 = 0.f;
  int a2 = rp2[v], b2 = rp2[v + 1];
  for (int j = a2; j < b2; ++j) s2 += e_buf[(size_t)el2[j] * L + col];
  sent[(size_t)v * L + col] = s1;
  recv[(size_t)v * L + col] = s2;
}

// Fused per-step update. Block = ROWS threads = ROWS/64 waves; each wave owns
// 64 rows (4 x 16-row fragments) x 128 cols, so each W-fragment load (32B from L2)
// feeds 12 MFMAs (layer0) / 8 MFMAs (layer1) — amortizes L2 weight traffic 4x.
// Layer0: split-precision (Ah*Bh + Al*Bh + Ah*Bl). Hidden stored as plain bf16 in
// LDS (XOR-swizzled 16B units); layer1 uses 2 products (Ah*Bh + Ah*Bl).
// Glob segment folded into b0eff. CSR: edge rows written raw to e_buf (no atomics).
template<int ROWS, bool EDGE_MODE, bool CSR>
__global__ __launch_bounds__(ROWS, 2)
void block_step_kernel(float* __restrict__ x_io,
                       const float* __restrict__ gsrc1,
                       const float* __restrict__ gsrc2,
                       const int* __restrict__ idx1, const int* __restrict__ idx2,
                       const unsigned short* __restrict__ W0h,
                       const unsigned short* __restrict__ W0l,
                       const float* __restrict__ b0eff,
                       const unsigned short* __restrict__ W1h,
                       const unsigned short* __restrict__ W1l,
                       const float* __restrict__ b1,
                       const float* __restrict__ ln_s, const float* __restrict__ ln_b,
                       float* __restrict__ scat1, float* __restrict__ scat2,
                       float* __restrict__ agg, float* __restrict__ e_buf,
                       int M) {
  constexpr int WAVES = ROWS / 64;
  __shared__ unsigned short Hbf[ROWS * 128];   // bf16 hidden tile, swizzled

  const int t = threadIdx.x;
  const int lane = t & 63;
  const int wg = t >> 6;
  const int c = lane & 15;
  const int g = lane >> 4;
  const int m0 = blockIdx.x * ROWS;
  const int valid = min(M - m0, ROWS);
  const int wbase = wg * 64;

  // per-fragment row indices (A rows: rf*16 + c), clamped
  int rc4[4], j1[4], j2[4];
#pragma unroll
  for (int rf = 0; rf < 4; ++rf) {
    int rl = wbase + rf * 16 + c;
    int rc = min(rl, valid - 1);
    rc4[rf] = m0 + rc;
    j1[rf] = EDGE_MODE ? idx1[m0 + rc] : (m0 + rc);
    j2[rf] = EDGE_MODE ? idx2[m0 + rc] : (m0 + rc);
  }

  const f32x4 z4 = {0.f, 0.f, 0.f, 0.f};
  f32x4 acc[4][8];
#pragma unroll
  for (int rf = 0; rf < 4; ++rf)
#pragma unroll
    for (int fn = 0; fn < 8; ++fn) acc[rf][fn] = z4;

  // ---- layer 0: [ROWS x 384] @ [384 x 128], A direct from global ----
#pragma unroll
  for (int seg = 0; seg < 3; ++seg) {
    const float* src = (seg == 0) ? x_io : (seg == 1 ? gsrc1 : gsrc2);
    const int* rsel = (seg == 0) ? rc4 : (seg == 1 ? j1 : j2);
#pragma unroll
    for (int kk = 0; kk < 4; ++kk) {
      const int ks = seg * 4 + kk;
      short8 ah[4], al[4];
#pragma unroll
      for (int rf = 0; rf < 4; ++rf) {
        const float* bp = src + (size_t)rsel[rf] * L + g * 8 + kk * 32;
        float4 v0 = *(const float4*)bp;
        float4 v1 = *(const float4*)(bp + 4);
        float xs[8] = {v0.x, v0.y, v0.z, v0.w, v1.x, v1.y, v1.z, v1.w};
#pragma unroll
        for (int j = 0; j < 8; ++j) {
          unsigned short h = f2bf(xs[j]);
          ah[rf][j] = (short)h;
          al[rf][j] = (short)f2bf_trunc(xs[j] - bf2f(h));
        }
      }
#pragma unroll
      for (int fn = 0; fn < 8; ++fn) {
        size_t wb = (size_t)(fn * 16 + c) * 384 + ks * 32 + g * 8;
        short8 bh = *(const short8*)(W0h + wb);
        short8 bl = *(const short8*)(W0l + wb);
#pragma unroll
        for (int rf = 0; rf < 4; ++rf) {
          acc[rf][fn] = __builtin_amdgcn_mfma_f32_16x16x32_bf16(ah[rf], bh, acc[rf][fn], 0, 0, 0);
          acc[rf][fn] = __builtin_amdgcn_mfma_f32_16x16x32_bf16(al[rf], bh, acc[rf][fn], 0, 0, 0);
          acc[rf][fn] = __builtin_amdgcn_mfma_f32_16x16x32_bf16(ah[rf], bl, acc[rf][fn], 0, 0, 0);
        }
      }
    }
  }

  // ---- hidden: relu(acc + b0eff) -> Hbf (bf16, swizzled; wave-private stripe) ----
#pragma unroll
  for (int fn = 0; fn < 8; ++fn) {
    int col = fn * 16 + c;
    float bb = b0eff[col];
    int unit = col >> 3;
#pragma unroll
    for (int rf = 0; rf < 4; ++rf) {
#pragma unroll
      for (int ri = 0; ri < 4; ++ri) {
        int rl = wbase + rf * 16 + g * 4 + ri;
        float x = fmaxf(acc[rf][fn][ri] + bb, 0.f);
        Hbf[rl * 128 + ((unit ^ (rl & 15)) << 3) + (col & 7)] = f2bf(x);
      }
    }
  }
  // no barrier: each wave reads only its own 64-row stripe

  // ---- layer 1: [ROWS x 128] @ [128 x 128], 2-product ----
  f32x4 acc2[4][8];
#pragma unroll
  for (int rf = 0; rf < 4; ++rf)
#pragma unroll
    for (int fn = 0; fn < 8; ++fn) acc2[rf][fn] = z4;
#pragma unroll
  for (int ks = 0; ks < 4; ++ks) {
    short8 ah[4];
#pragma unroll
    for (int rf = 0; rf < 4; ++rf) {
      int rl = wbase + rf * 16 + c;
      int unit = ks * 4 + g;
      ah[rf] = *(const short8*)&Hbf[rl * 128 + ((unit ^ (rl & 15)) << 3)];
    }
#pragma unroll
    for (int fn = 0; fn < 8; ++fn) {
      size_t wb = (size_t)(fn * 16 + c) * 128 + ks * 32 + g * 8;
      short8 bh = *(const short8*)(W1h + wb);
      short8 bl = *(const short8*)(W1l + wb);
#pragma unroll
      for (int rf = 0; rf < 4; ++rf) {
        acc2[rf][fn] = __builtin_amdgcn_mfma_f32_16x16x32_bf16(ah[rf], bh, acc2[rf][fn], 0, 0, 0);
        acc2[rf][fn] = __builtin_amdgcn_mfma_f32_16x16x32_bf16(ah[rf], bl, acc2[rf][fn], 0, 0, 0);
      }
    }
  }

  // ---- epilogue, per row-fragment (limits register pressure) ----
  float colagg[8];
#pragma unroll
  for (int fn = 0; fn < 8; ++fn) colagg[fn] = 0.f;

#pragma unroll
  for (int rf = 0; rf < 4; ++rf) {
    const int rb = wbase + rf * 16 + g * 4;
    int sidx[4], ridx[4];
    if (EDGE_MODE && !CSR) {
#pragma unroll
      for (int ri = 0; ri < 4; ++ri) {
        int rr = min(rb + ri, valid - 1);
        sidx[ri] = idx1[m0 + rr];
        ridx[ri] = idx2[m0 + rr];
      }
    }
    float sum[4] = {0.f, 0.f, 0.f, 0.f}, sq[4] = {0.f, 0.f, 0.f, 0.f};
    float xv[8][4];
#pragma unroll
    for (int fn = 0; fn < 8; ++fn) {
      int col = fn * 16 + c;
      float bb = b1[col];
#pragma unroll
      for (int ri = 0; ri < 4; ++ri) {
        int row = rb + ri;
        float e = fmaxf(acc2[rf][fn][ri] + bb, 0.f);
        if (row < valid) {
          if (EDGE_MODE) {
            if (CSR) {
              e_buf[(size_t)(m0 + row) * L + col] = e;
            } else {
              atomicAdd(scat1 + (size_t)sidx[ri] * L + col, e);
              atomicAdd(scat2 + (size_t)ridx[ri] * L + col, e);
            }
          }
          colagg[fn] += e;
          float x = e + x_io[(size_t)(m0 + row) * L + col];
          xv[fn][ri] = x;
          sum[ri] += x;
          sq[ri] += x * x;
        } else {
          xv[fn][ri] = 0.f;
        }
      }
    }
#pragma unroll
    for (int mask = 1; mask <= 8; mask <<= 1) {
#pragma unroll
      for (int ri = 0; ri < 4; ++ri) {
        sum[ri] += __shfl_xor(sum[ri], mask);
        sq[ri] += __shfl_xor(sq[ri], mask);
      }
    }
    float mu[4], rs[4];
#pragma unroll
    for (int ri = 0; ri < 4; ++ri) {
      mu[ri] = sum[ri] * (1.f / 128.f);
      float var = sq[ri] * (1.f / 128.f) - mu[ri] * mu[ri];
      rs[ri] = rsqrtf(var + 1e-6f);
    }
#pragma unroll
    for (int fn = 0; fn < 8; ++fn) {
      int col = fn * 16 + c;
      float lns = ln_s[col], lnb = ln_b[col];
#pragma unroll
      for (int ri = 0; ri < 4; ++ri) {
        int row = rb + ri;
        if (row < valid)
          x_io[(size_t)(m0 + row) * L + col] = (xv[fn][ri] - mu[ri]) * rs[ri] * lns + lnb;
      }
    }
  }

  // column aggregate: reduce over g, LDS-reduce across waves, 128 atomics/block
#pragma unroll
  for (int mask = 16; mask <= 32; mask <<= 1)
#pragma unroll
    for (int fn = 0; fn < 8; ++fn) colagg[fn] += __shfl_xor(colagg[fn], mask);
  __syncthreads();                 // all Hbf reads complete; reuse as float scratch
  float* F = (float*)Hbf;
  if (lane < 16) {
#pragma unroll
    for (int fn = 0; fn < 8; ++fn) F[wg * 128 + fn * 16 + lane] = colagg[fn];
  }
  __syncthreads();
  if (t < 128) {
    float s = 0.f;
#pragma unroll
    for (int w = 0; w < WAVES; ++w) s += F[w * 128 + t];
    atomicAdd(agg + t, s);
  }
}

__global__ void glob_step_kernel(float* __restrict__ glob,
                                 const float* __restrict__ node_agg,
                                 const float* __restrict__ edge_agg,
                                 const float* __restrict__ W0, const float* __restrict__ b0,
                                 const float* __restrict__ W1, const float* __restrict__ b1,
                                 const float* __restrict__ ln_s, const float* __restrict__ ln_b) {
  __shared__ float gin[384];
  __shared__ float h[128];
  __shared__ float red4[4];
  int j = threadIdx.x;  // 128
  gin[j] = node_agg[j];
  gin[128 + j] = edge_agg[j];
  gin[256 + j] = glob[j];
  __syncthreads();
  float a = b0[j];
  for (int k = 0; k < 384; ++k) a += gin[k] * W0[k * L + j];
  h[j] = fmaxf(a, 0.f);
  __syncthreads();
  float o = b1[j];
  for (int k = 0; k < 128; ++k) o += h[k] * W1[k * L + j];
  o = fmaxf(o, 0.f);
  float x = o + glob[j];
  float sum = x, sq = x * x;
  for (int m = 1; m < 64; m <<= 1) { sum += __shfl_xor(sum, m); sq += __shfl_xor(sq, m); }
  if ((j & 63) == 0) { red4[(j >> 6) * 2] = sum; red4[(j >> 6) * 2 + 1] = sq; }
  __syncthreads();
  sum = red4[0] + red4[2]; sq = red4[1] + red4[3];
  float mu = sum * (1.f / 128.f);
  float var = sq * (1.f / 128.f) - mu * mu;
  float rsd = rsqrtf(var + 1e-6f);
  glob[j] = (x - mu) * rsd * ln_s[j] + ln_b[j];
}

__global__ void decode_kernel(const float* __restrict__ glob, const float* __restrict__ W,
                              const float* __restrict__ bias, float* __restrict__ out) {
  int j = threadIdx.x;  // 128
  float a = bias[j];
  for (int k = 0; k < 128; ++k) a += glob[k] * W[k * L + j];
  out[j] = a;
}

extern "C" void kernel_launch(void* const* d_in, const int* in_sizes, int n_in,
                              void* d_out, int out_size, void* d_ws, size_t ws_size,
                              hipStream_t stream) {
  const float* node_feats = (const float*)d_in[0];
  const float* edge_feats = (const float*)d_in[1];
  const float* globals_   = (const float*)d_in[2];
  const int*   senders    = (const int*)d_in[3];
  const int*   receivers  = (const int*)d_in[4];
  const float* emb_node_W = (const float*)d_in[5];
  const float* emb_node_b = (const float*)d_in[6];
  const float* emb_edge_W = (const float*)d_in[7];
  const float* emb_edge_b = (const float*)d_in[8];
  const float* emb_glob_W = (const float*)d_in[9];
  const float* emb_glob_b = (const float*)d_in[10];
  const float* edge_W0 = (const float*)d_in[11];
  const float* edge_b0 = (const float*)d_in[12];
  const float* edge_W1 = (const float*)d_in[13];
  const float* edge_b1 = (const float*)d_in[14];
  const float* node_W0 = (const float*)d_in[15];
  const float* node_b0 = (const float*)d_in[16];
  const float* node_W1 = (const float*)d_in[17];
  const float* node_b1 = (const float*)d_in[18];
  const float* glob_W0 = (const float*)d_in[19];
  const float* glob_b0 = (const float*)d_in[20];
  const float* glob_W1 = (const float*)d_in[21];
  const float* glob_b1 = (const float*)d_in[22];
  const float* ln_node_s = (const float*)d_in[23];
  const float* ln_node_b = (const float*)d_in[24];
  const float* ln_edge_s = (const float*)d_in[25];
  const float* ln_edge_b = (const float*)d_in[26];
  const float* ln_glob_s = (const float*)d_in[27];
  const float* ln_glob_b = (const float*)d_in[28];
  const float* dec_W = (const float*)d_in[29];
  const float* dec_b = (const float*)d_in[30];

  const int N = in_sizes[0] / 64;
  const int E = in_sizes[1] / 32;

  float* nodes = (float*)d_out;                   // [N][128]
  float* edges = nodes + (size_t)N * L;           // [E][128]
  float* gout  = edges + (size_t)E * L;           // [128]

  char* wp = (char*)d_ws;
  auto alloc = [&](size_t bytes) -> char* {
    char* p = wp;
    wp += (bytes + 255) & ~(size_t)255;
    return p;
  };
  float* sent = (float*)alloc((size_t)N * L * 4);
  float* recv = (float*)alloc((size_t)N * L * 4);
  float* glob = (float*)alloc(512);
  float* node_agg = (float*)alloc(512);
  float* edge_agg = (float*)alloc(512);
  float* b0e_eff = (float*)alloc(512);
  float* b0n_eff = (float*)alloc(512);
  unsigned short* eW0h = (unsigned short*)alloc((size_t)NSTEPS * 128 * 384 * 2);
  unsigned short* eW0l = (unsigned short*)alloc((size_t)NSTEPS * 128 * 384 * 2);
  unsigned short* eW1h = (unsigned short*)alloc((size_t)NSTEPS * 128 * 128 * 2);
  unsigned short* eW1l = (unsigned short*)alloc((size_t)NSTEPS * 128 * 128 * 2);
  unsigned short* nW0h = (unsigned short*)alloc((size_t)NSTEPS * 128 * 384 * 2);
  unsigned short* nW0l = (unsigned short*)alloc((size_t)NSTEPS * 128 * 384 * 2);
  unsigned short* nW1h = (unsigned short*)alloc((size_t)NSTEPS * 128 * 128 * 2);
  unsigned short* nW1l = (unsigned short*)alloc((size_t)NSTEPS * 128 * 128 * 2);
  int* rp1 = (int*)alloc((size_t)(N + 1) * 4);
  int* rp2 = (int*)alloc((size_t)(N + 1) * 4);
  int* cnt1 = (int*)alloc((size_t)N * 4);
  int* cnt2 = (int*)alloc((size_t)N * 4);
  int* el1 = (int*)alloc((size_t)E * 4);
  int* el2 = (int*)alloc((size_t)E * 4);
  int* part = (int*)alloc(SCAN_B * 4);
  float* e_buf = (float*)alloc((size_t)E * L * 4);
  size_t need = (size_t)(wp - (char*)d_ws);
  const bool csr = ws_size >= need;

  // weight prep (bf16 hi/lo, transposed, first 384 rows of W0 only)
  conv_split_kernel<<<(NSTEPS * 128 * 384 + 255) / 256, 256, 0, stream>>>(edge_W0, eW0h, eW0l, 512, 384, NSTEPS);
  conv_split_kernel<<<(NSTEPS * 128 * 128 + 255) / 256, 256, 0, stream>>>(edge_W1, eW1h, eW1l, 128, 128, NSTEPS);
  conv_split_kernel<<<(NSTEPS * 128 * 384 + 255) / 256, 256, 0, stream>>>(node_W0, nW0h, nW0l, 512, 384, NSTEPS);
  conv_split_kernel<<<(NSTEPS * 128 * 128 + 255) / 256, 256, 0, stream>>>(node_W1, nW1h, nW1l, 128, 128, NSTEPS);

  // embeddings (exact fp32)
  embed_kernel<<<2048, 128, 0, stream>>>(node_feats, emb_node_W, emb_node_b, nodes, N, 64);
  embed_kernel<<<4096, 128, 0, stream>>>(edge_feats, emb_edge_W, emb_edge_b, edges, E, 32);
  glob_embed_kernel<<<1, 128, 0, stream>>>(globals_, emb_glob_W, emb_glob_b, glob);

  const int egrid = (E + 255) / 256;
  const int ngrid = (N + 127) / 128;
  const int chunk = (N + SCAN_B - 1) / SCAN_B;

  if (csr) {
    hipMemsetAsync(cnt1, 0, (size_t)N * 4, stream);
    hipMemsetAsync(cnt2, 0, (size_t)N * 4, stream);
    hist_kernel<<<(E + 255) / 256, 256, 0, stream>>>(senders, receivers, cnt1, cnt2, E);
    scan_sum_kernel<<<SCAN_B, 256, 0, stream>>>(cnt1, part, N, chunk);
    scan_part_kernel<<<1, 64, 0, stream>>>(part, SCAN_B);
    scan_write_kernel<<<SCAN_B, 256, 0, stream>>>(cnt1, part, rp1, N, chunk, E);
    scan_sum_kernel<<<SCAN_B, 256, 0, stream>>>(cnt2, part, N, chunk);
    scan_part_kernel<<<1, 64, 0, stream>>>(part, SCAN_B);
    scan_write_kernel<<<SCAN_B, 256, 0, stream>>>(cnt2, part, rp2, N, chunk, E);
    hipMemsetAsync(cnt1, 0, (size_t)N * 4, stream);
    hipMemsetAsync(cnt2, 0, (size_t)N * 4, stream);
    fill_kernel<<<(E + 255) / 256, 256, 0, stream>>>(senders, receivers, rp1, rp2, cnt1, cnt2, el1, el2, E);
  }

  for (int s = 0; s < NSTEPS; ++s) {
    hipMemsetAsync(node_agg, 0, 512, stream);
    hipMemsetAsync(edge_agg, 0, 512, stream);
    if (!csr) {
      hipMemsetAsync(sent, 0, (size_t)N * L * 4, stream);
      hipMemsetAsync(recv, 0, (size_t)N * L * 4, stream);
    }

    fold_glob_kernel<<<1, 128, 0, stream>>>(edge_W0 + (size_t)s * 512 * L + 384 * L,
                                            edge_b0 + s * L, glob, b0e_eff);
    fold_glob_kernel<<<1, 128, 0, stream>>>(node_W0 + (size_t)s * 512 * L + 384 * L,
                                            node_b0 + s * L, glob, b0n_eff);

    if (csr) {
      block_step_kernel<256, true, true><<<egrid, 256, 0, stream>>>(
          edges, nodes, nodes, senders, receivers,
          eW0h + (size_t)s * 128 * 384, eW0l + (size_t)s * 128 * 384, b0e_eff,
          eW1h + (size_t)s * 128 * 128, eW1l + (size_t)s * 128 * 128, edge_b1 + s * L,
          ln_edge_s + s * L, ln_edge_b + s * L,
          nullptr, nullptr, edge_agg, e_buf, E);
      gather_kernel<<<(N + 1) / 2, 256, 0, stream>>>(e_buf, rp1, el1, rp2, el2, sent, recv, N);
    } else {
      block_step_kernel<256, true, false><<<egrid, 256, 0, stream>>>(
          edges, nodes, nodes, senders, receivers,
          eW0h + (size_t)s * 128 * 384, eW0l + (size_t)s * 128 * 384, b0e_eff,
          eW1h + (size_t)s * 128 * 128, eW1l + (size_t)s * 128 * 128, edge_b1 + s * L,
          ln_edge_s + s * L, ln_edge_b + s * L,
          sent, recv, edge_agg, nullptr, E);
    }

    block_step_kernel<128, false, false><<<ngrid, 128, 0, stream>>>(
        nodes, sent, recv, nullptr, nullptr,
        nW0h + (size_t)s * 128 * 384, nW0l + (size_t)s * 128 * 384, b0n_eff,
        nW1h + (size_t)s * 128 * 128, nW1l + (size_t)s * 128 * 128, node_b1 + s * L,
        ln_node_s + s * L, ln_node_b + s * L,
        nullptr, nullptr, node_agg, nullptr, N);

    glob_step_kernel<<<1, 128, 0, stream>>>(
        glob, node_agg, edge_agg,
        glob_W0 + (size_t)s * 384 * L, glob_b0 + s * L,
        glob_W1 + (size_t)s * 128 * L, glob_b1 + s * L,
        ln_glob_s + s * L, ln_glob_b + s * L);
  }

  decode_kernel<<<1, 128, 0, stream>>>(glob, dec_W, dec_b, gout);
}

// Round 6
// 2566.521 us; speedup vs baseline: 2.0169x; 1.1540x over previous
//
#include <hip/hip_runtime.h>

#define L 128
#define NSTEPS 2
#define SCAN_B 250

typedef __attribute__((ext_vector_type(8))) short short8;
typedef __attribute__((ext_vector_type(4))) float f32x4;

static __device__ __forceinline__ unsigned short f2bf(float f) {
  unsigned int u = __float_as_uint(f);
  u += 0x7FFFu + ((u >> 16) & 1u);   // round-to-nearest-even
  return (unsigned short)(u >> 16);
}
static __device__ __forceinline__ unsigned short f2bf_trunc(float f) {
  return (unsigned short)(__float_as_uint(f) >> 16);
}
static __device__ __forceinline__ float bf2f(unsigned short h) {
  return __uint_as_float(((unsigned int)h) << 16);
}
static __device__ __forceinline__ float bfhi(unsigned u) {          // hi16 as float
  return __uint_as_float(u & 0xFFFF0000u);
}
static __device__ __forceinline__ float bflo(unsigned u) {          // lo16 as float
  return __uint_as_float(u << 16);
}
static __device__ __forceinline__ unsigned packf(float x) {         // (hi<<16)|lo
  unsigned short h = f2bf(x);
  unsigned short l = f2bf_trunc(x - bf2f(h));
  return ((unsigned)h << 16) | l;
}
static __device__ __forceinline__ float unpackf(unsigned p) {       // hi + lo
  return bfhi(p) + bflo(p);
}

// unpack 8 packed u32 -> hi-short8 and lo-short8 (8 v_perm)
static __device__ __forceinline__ void unpack8(const unsigned* __restrict__ p,
                                               short8& ah, short8& al) {
  uint4 q0 = *(const uint4*)p;
  uint4 q1 = *(const uint4*)(p + 4);
  union U { unsigned u[4]; short8 s; } A, B;
  A.u[0] = __builtin_amdgcn_perm(q0.y, q0.x, 0x07060302u);
  A.u[1] = __builtin_amdgcn_perm(q0.w, q0.z, 0x07060302u);
  A.u[2] = __builtin_amdgcn_perm(q1.y, q1.x, 0x07060302u);
  A.u[3] = __builtin_amdgcn_perm(q1.w, q1.z, 0x07060302u);
  B.u[0] = __builtin_amdgcn_perm(q0.y, q0.x, 0x05040100u);
  B.u[1] = __builtin_amdgcn_perm(q0.w, q0.z, 0x05040100u);
  B.u[2] = __builtin_amdgcn_perm(q1.y, q1.x, 0x05040100u);
  B.u[3] = __builtin_amdgcn_perm(q1.w, q1.z, 0x05040100u);
  ah = A.s; al = B.s;
}

// hi[s][n][k] = bf16(in[s][k][n]) for k < Kkeep; lo = bf16(residual)
__global__ void conv_split_kernel(const float* __restrict__ in,
                                  unsigned short* __restrict__ hi,
                                  unsigned short* __restrict__ lo,
                                  int Ksrc, int Kkeep, int S) {
  int id = blockIdx.x * 256 + threadIdx.x;
  int nk = 128 * Kkeep;
  int total = S * nk;
  if (id >= total) return;
  int s = id / nk;
  int rem = id - s * nk;
  int n = rem / Kkeep;
  int k = rem - n * Kkeep;
  float x = in[(size_t)s * Ksrc * 128 + (size_t)k * 128 + n];
  unsigned short h = f2bf(x);
  hi[id] = h;
  lo[id] = f2bf(x - bf2f(h));
}

// fp32 out (edges: d_out array is the live state)
__global__ void embed_kernel(const float* __restrict__ feats, const float* __restrict__ W,
                             const float* __restrict__ bias, float* __restrict__ out,
                             int M, int K) {
  int j = threadIdx.x;  // 128
  for (int row = blockIdx.x; row < M; row += gridDim.x) {
    const float* f = feats + (size_t)row * K;
    float acc = bias[j];
    for (int k = 0; k < K; ++k) acc += f[k] * W[k * L + j];
    out[(size_t)row * L + j] = acc;
  }
}

// packed out (nodes state)
__global__ void embed_pack_kernel(const float* __restrict__ feats, const float* __restrict__ W,
                                  const float* __restrict__ bias, unsigned* __restrict__ out,
                                  int M, int K) {
  int j = threadIdx.x;  // 128
  for (int row = blockIdx.x; row < M; row += gridDim.x) {
    const float* f = feats + (size_t)row * K;
    float acc = bias[j];
    for (int k = 0; k < K; ++k) acc += f[k] * W[k * L + j];
    out[(size_t)row * L + j] = packf(acc);
  }
}

__global__ void glob_embed_kernel(const float* __restrict__ gin, const float* __restrict__ W,
                                  const float* __restrict__ bias, float* __restrict__ glob) {
  int j = threadIdx.x;  // 128
  float acc = bias[j];
  for (int k = 0; k < 16; ++k) acc += gin[k] * W[k * L + j];
  glob[j] = acc;
}

__global__ void fold_glob_kernel(const float* __restrict__ Wg, const float* __restrict__ b0,
                                 const float* __restrict__ glob, float* __restrict__ b0eff) {
  int j = threadIdx.x;  // 128
  float a = b0[j];
  for (int k = 0; k < 128; ++k) a += glob[k] * Wg[k * L + j];
  b0eff[j] = a;
}

// ---------------- CSR build ----------------
__global__ void hist_kernel(const int* __restrict__ senders, const int* __restrict__ receivers,
                            int* __restrict__ cnt1, int* __restrict__ cnt2, int E) {
  int e = blockIdx.x * 256 + threadIdx.x;
  if (e >= E) return;
  atomicAdd(&cnt1[senders[e]], 1);
  atomicAdd(&cnt2[receivers[e]], 1);
}

__global__ void scan_sum_kernel(const int* __restrict__ cnt, int* __restrict__ part,
                                int n, int chunk) {
  __shared__ int red[256];
  int b = blockIdx.x, t = threadIdx.x;
  int lo = b * chunk, hi = min(lo + chunk, n);
  red[t] = (lo + t < hi) ? cnt[lo + t] : 0;
  __syncthreads();
  for (int o = 128; o > 0; o >>= 1) { if (t < o) red[t] += red[t + o]; __syncthreads(); }
  if (t == 0) part[b] = red[0];
}

__global__ void scan_part_kernel(int* __restrict__ part, int nb) {
  if (threadIdx.x == 0) {
    int run = 0;
    for (int i = 0; i < nb; ++i) { int v = part[i]; part[i] = run; run += v; }
  }
}

__global__ void scan_write_kernel(const int* __restrict__ cnt, const int* __restrict__ part,
                                  int* __restrict__ rp, int n, int chunk, int E) {
  __shared__ int buf[256];
  int b = blockIdx.x, t = threadIdx.x;
  int lo = b * chunk, hi = min(lo + chunk, n);
  buf[t] = (lo + t < hi) ? cnt[lo + t] : 0;
  __syncthreads();
  if (t == 0) {
    int run = part[b];
    for (int i = 0; i < hi - lo; ++i) { rp[lo + i] = run; run += buf[i]; }
  }
  if (b == gridDim.x - 1 && t == 0) rp[n] = E;
}

__global__ void fill_kernel(const int* __restrict__ senders, const int* __restrict__ receivers,
                            const int* __restrict__ rp1, const int* __restrict__ rp2,
                            int* __restrict__ cnt1, int* __restrict__ cnt2,
                            int* __restrict__ el1, int* __restrict__ el2, int E) {
  int e = blockIdx.x * 256 + threadIdx.x;
  if (e >= E) return;
  int s = senders[e];
  int p = atomicAdd(&cnt1[s], 1);
  el1[rp1[s] + p] = e;
  int r = receivers[e];
  int q = atomicAdd(&cnt2[r], 1);
  el2[rp2[r] + q] = e;
}

// sent_p/recv_p (packed) from bf16 e-buffer via CSR. 16 threads per node, 16B loads,
// both CSR sides interleaved for 2 loads in flight.
__global__ __launch_bounds__(256) void gather_kernel(
    const unsigned short* __restrict__ e16,
    const int* __restrict__ rp1, const int* __restrict__ el1,
    const int* __restrict__ rp2, const int* __restrict__ el2,
    unsigned* __restrict__ sent_p, unsigned* __restrict__ recv_p, int N) {
  int t = threadIdx.x;
  int v = blockIdx.x * 16 + (t >> 4);
  if (v >= N) return;
  int cols = (t & 15) * 8;
  float a1[8], a2[8];
#pragma unroll
  for (int i = 0; i < 8; ++i) { a1[i] = 0.f; a2[i] = 0.f; }
  int s1 = rp1[v], n1 = rp1[v + 1] - s1;
  int s2 = rp2[v], n2 = rp2[v + 1] - s2;
  int mx = max(n1, n2);
  for (int j = 0; j < mx; ++j) {
    if (j < n1) {
      uint4 u = *(const uint4*)(e16 + (size_t)el1[s1 + j] * L + cols);
      a1[0] += bflo(u.x); a1[1] += bfhi(u.x);
      a1[2] += bflo(u.y); a1[3] += bfhi(u.y);
      a1[4] += bflo(u.z); a1[5] += bfhi(u.z);
      a1[6] += bflo(u.w); a1[7] += bfhi(u.w);
    }
    if (j < n2) {
      uint4 u = *(const uint4*)(e16 + (size_t)el2[s2 + j] * L + cols);
      a2[0] += bflo(u.x); a2[1] += bfhi(u.x);
      a2[2] += bflo(u.y); a2[3] += bfhi(u.y);
      a2[4] += bflo(u.z); a2[5] += bfhi(u.z);
      a2[6] += bflo(u.w); a2[7] += bfhi(u.w);
    }
  }
  uint4 o0, o1;
  o0.x = packf(a1[0]); o0.y = packf(a1[1]); o0.z = packf(a1[2]); o0.w = packf(a1[3]);
  o1.x = packf(a1[4]); o1.y = packf(a1[5]); o1.z = packf(a1[6]); o1.w = packf(a1[7]);
  *(uint4*)(sent_p + (size_t)v * L + cols) = o0;
  *(uint4*)(sent_p + (size_t)v * L + cols + 4) = o1;
  o0.x = packf(a2[0]); o0.y = packf(a2[1]); o0.z = packf(a2[2]); o0.w = packf(a2[3]);
  o1.x = packf(a2[4]); o1.y = packf(a2[5]); o1.z = packf(a2[6]); o1.w = packf(a2[7]);
  *(uint4*)(recv_p + (size_t)v * L + cols) = o0;
  *(uint4*)(recv_p + (size_t)v * L + cols + 4) = o1;
}

// Fused per-step update. Block = ROWS threads = ROWS/64 waves; each wave owns 64 rows
// (4 x 16-row frags) x 128 cols. EDGE: seg0/residual from fp32 edges, seg1/2 gathered
// packed nodes_p; NODE: fully packed. Layer0 3-product split; layer1 2-product with
// bf16 hidden in LDS (XOR-swizzled). Glob folded into b0eff. e written as bf16-hi.
template<int ROWS, bool EDGE_MODE>
__global__ __launch_bounds__(ROWS, 2)
void block_step_kernel(const float* __restrict__ xf,          // EDGE: fp32 self state
                       const unsigned* __restrict__ xp,       // NODE: packed self state
                       const unsigned* __restrict__ g1p,      // nodes_p | sent_p
                       const unsigned* __restrict__ g2p,      // nodes_p | recv_p
                       const int* __restrict__ idx1, const int* __restrict__ idx2,
                       const unsigned short* __restrict__ W0h,
                       const unsigned short* __restrict__ W0l,
                       const float* __restrict__ b0eff,
                       const unsigned short* __restrict__ W1h,
                       const unsigned short* __restrict__ W1l,
                       const float* __restrict__ b1,
                       const float* __restrict__ ln_s, const float* __restrict__ ln_b,
                       float* __restrict__ agg,
                       unsigned short* __restrict__ e_out,    // EDGE: bf16 e_new
                       float* __restrict__ xf_out,            // fp32 LN out (or null)
                       unsigned* __restrict__ xp_out,         // packed LN out (or null)
                       int M) {
  constexpr int WAVES = ROWS / 64;
  __shared__ unsigned short Hbf[ROWS * 128];

  const int t = threadIdx.x;
  const int lane = t & 63;
  const int wg = t >> 6;
  const int c = lane & 15;
  const int g = lane >> 4;
  const int m0 = blockIdx.x * ROWS;
  const int valid = min(M - m0, ROWS);
  const int wbase = wg * 64;

  int rc4[4], j1[4], j2[4];
#pragma unroll
  for (int rf = 0; rf < 4; ++rf) {
    int rl = wbase + rf * 16 + c;
    int rc = min(rl, valid - 1);
    rc4[rf] = m0 + rc;
    if (EDGE_MODE) { j1[rf] = idx1[rc4[rf]]; j2[rf] = idx2[rc4[rf]]; }
    else           { j1[rf] = rc4[rf];       j2[rf] = rc4[rf]; }
  }

  const f32x4 z4 = {0.f, 0.f, 0.f, 0.f};
  f32x4 acc[4][8];
#pragma unroll
  for (int rf = 0; rf < 4; ++rf)
#pragma unroll
    for (int fn = 0; fn < 8; ++fn) acc[rf][fn] = z4;

  auto mfma_step = [&](int ks, const short8* ah, const short8* al) {
#pragma unroll
    for (int fn = 0; fn < 8; ++fn) {
      size_t wb = (size_t)(fn * 16 + c) * 384 + ks * 32 + g * 8;
      short8 bh = *(const short8*)(W0h + wb);
      short8 bl = *(const short8*)(W0l + wb);
#pragma unroll
      for (int rf = 0; rf < 4; ++rf) {
        acc[rf][fn] = __builtin_amdgcn_mfma_f32_16x16x32_bf16(ah[rf], bh, acc[rf][fn], 0, 0, 0);
        acc[rf][fn] = __builtin_amdgcn_mfma_f32_16x16x32_bf16(al[rf], bh, acc[rf][fn], 0, 0, 0);
        acc[rf][fn] = __builtin_amdgcn_mfma_f32_16x16x32_bf16(ah[rf], bl, acc[rf][fn], 0, 0, 0);
      }
    }
  };

  // ---- layer 0 seg0: self ----
#pragma unroll
  for (int kk = 0; kk < 4; ++kk) {
    short8 ah[4], al[4];
    if (EDGE_MODE) {
#pragma unroll
      for (int rf = 0; rf < 4; ++rf) {
        const float* bp = xf + (size_t)rc4[rf] * L + g * 8 + kk * 32;
        float4 v0 = *(const float4*)bp;
        float4 v1 = *(const float4*)(bp + 4);
        float xs[8] = {v0.x, v0.y, v0.z, v0.w, v1.x, v1.y, v1.z, v1.w};
#pragma unroll
        for (int j = 0; j < 8; ++j) {
          unsigned short h = f2bf(xs[j]);
          ah[rf][j] = (short)h;
          al[rf][j] = (short)f2bf_trunc(xs[j] - bf2f(h));
        }
      }
    } else {
#pragma unroll
      for (int rf = 0; rf < 4; ++rf)
        unpack8(xp + (size_t)rc4[rf] * L + g * 8 + kk * 32, ah[rf], al[rf]);
    }
    mfma_step(kk, ah, al);
  }
  // ---- layer 0 seg1: gather1 (packed) ----
#pragma unroll
  for (int kk = 0; kk < 4; ++kk) {
    short8 ah[4], al[4];
#pragma unroll
    for (int rf = 0; rf < 4; ++rf)
      unpack8(g1p + (size_t)j1[rf] * L + g * 8 + kk * 32, ah[rf], al[rf]);
    mfma_step(4 + kk, ah, al);
  }
  // ---- layer 0 seg2: gather2 (packed) ----
#pragma unroll
  for (int kk = 0; kk < 4; ++kk) {
    short8 ah[4], al[4];
#pragma unroll
    for (int rf = 0; rf < 4; ++rf)
      unpack8(g2p + (size_t)j2[rf] * L + g * 8 + kk * 32, ah[rf], al[rf]);
    mfma_step(8 + kk, ah, al);
  }

  // ---- hidden: relu(acc + b0eff) -> Hbf (bf16, swizzled; wave-private stripe) ----
#pragma unroll
  for (int fn = 0; fn < 8; ++fn) {
    int col = fn * 16 + c;
    float bb = b0eff[col];
    int unit = col >> 3;
#pragma unroll
    for (int rf = 0; rf < 4; ++rf) {
#pragma unroll
      for (int ri = 0; ri < 4; ++ri) {
        int rl = wbase + rf * 16 + g * 4 + ri;
        float x = fmaxf(acc[rf][fn][ri] + bb, 0.f);
        Hbf[rl * 128 + ((unit ^ (rl & 15)) << 3) + (col & 7)] = f2bf(x);
      }
    }
  }
  // no barrier: each wave reads only its own 64-row stripe

  // ---- layer 1: [ROWS x 128] @ [128 x 128], 2-product ----
  f32x4 acc2[4][8];
#pragma unroll
  for (int rf = 0; rf < 4; ++rf)
#pragma unroll
    for (int fn = 0; fn < 8; ++fn) acc2[rf][fn] = z4;
#pragma unroll
  for (int ks = 0; ks < 4; ++ks) {
    short8 ah[4];
#pragma unroll
    for (int rf = 0; rf < 4; ++rf) {
      int rl = wbase + rf * 16 + c;
      int unit = ks * 4 + g;
      ah[rf] = *(const short8*)&Hbf[rl * 128 + ((unit ^ (rl & 15)) << 3)];
    }
#pragma unroll
    for (int fn = 0; fn < 8; ++fn) {
      size_t wb = (size_t)(fn * 16 + c) * 128 + ks * 32 + g * 8;
      short8 bh = *(const short8*)(W1h + wb);
      short8 bl = *(const short8*)(W1l + wb);
#pragma unroll
      for (int rf = 0; rf < 4; ++rf) {
        acc2[rf][fn] = __builtin_amdgcn_mfma_f32_16x16x32_bf16(ah[rf], bh, acc2[rf][fn], 0, 0, 0);
        acc2[rf][fn] = __builtin_amdgcn_mfma_f32_16x16x32_bf16(ah[rf], bl, acc2[rf][fn], 0, 0, 0);
      }
    }
  }

  // ---- epilogue, per row-fragment ----
  float colagg[8];
#pragma unroll
  for (int fn = 0; fn < 8; ++fn) colagg[fn] = 0.f;

#pragma unroll
  for (int rf = 0; rf < 4; ++rf) {
    const int rb = wbase + rf * 16 + g * 4;
    float sum[4] = {0.f, 0.f, 0.f, 0.f}, sq[4] = {0.f, 0.f, 0.f, 0.f};
    float xv[8][4];
#pragma unroll
    for (int fn = 0; fn < 8; ++fn) {
      int col = fn * 16 + c;
      float bb = b1[col];
#pragma unroll
      for (int ri = 0; ri < 4; ++ri) {
        int row = rb + ri;
        float e = fmaxf(acc2[rf][fn][ri] + bb, 0.f);
        if (row < valid) {
          if (EDGE_MODE) e_out[(size_t)(m0 + row) * L + col] = f2bf(e);
          colagg[fn] += e;
          float xprev;
          if (EDGE_MODE) xprev = xf[(size_t)(m0 + row) * L + col];
          else           xprev = unpackf(xp[(size_t)(m0 + row) * L + col]);
          float x = e + xprev;
          xv[fn][ri] = x;
          sum[ri] += x;
          sq[ri] += x * x;
        } else {
          xv[fn][ri] = 0.f;
        }
      }
    }
#pragma unroll
    for (int mask = 1; mask <= 8; mask <<= 1) {
#pragma unroll
      for (int ri = 0; ri < 4; ++ri) {
        sum[ri] += __shfl_xor(sum[ri], mask);
        sq[ri] += __shfl_xor(sq[ri], mask);
      }
    }
    float mu[4], rs[4];
#pragma unroll
    for (int ri = 0; ri < 4; ++ri) {
      mu[ri] = sum[ri] * (1.f / 128.f);
      float var = sq[ri] * (1.f / 128.f) - mu[ri] * mu[ri];
      rs[ri] = rsqrtf(var + 1e-6f);
    }
#pragma unroll
    for (int fn = 0; fn < 8; ++fn) {
      int col = fn * 16 + c;
      float lns = ln_s[col], lnb = ln_b[col];
#pragma unroll
      for (int ri = 0; ri < 4; ++ri) {
        int row = rb + ri;
        if (row < valid) {
          float y = (xv[fn][ri] - mu[ri]) * rs[ri] * lns + lnb;
          if (xf_out) xf_out[(size_t)(m0 + row) * L + col] = y;
          if (xp_out) xp_out[(size_t)(m0 + row) * L + col] = packf(y);
        }
      }
    }
  }

  // column aggregate
#pragma unroll
  for (int mask = 16; mask <= 32; mask <<= 1)
#pragma unroll
    for (int fn = 0; fn < 8; ++fn) colagg[fn] += __shfl_xor(colagg[fn], mask);
  if (WAVES == 1) {
    if (lane < 16) {
#pragma unroll
      for (int fn = 0; fn < 8; ++fn) atomicAdd(agg + fn * 16 + lane, colagg[fn]);
    }
  } else {
    __syncthreads();               // all Hbf reads complete; reuse as float scratch
    float* F = (float*)Hbf;
    if (lane < 16) {
#pragma unroll
      for (int fn = 0; fn < 8; ++fn) F[wg * 128 + fn * 16 + lane] = colagg[fn];
    }
    __syncthreads();
    if (t < 128) {
      float s = 0.f;
#pragma unroll
      for (int w = 0; w < WAVES; ++w) s += F[w * 128 + t];
      atomicAdd(agg + t, s);
    }
  }
}

__global__ void glob_step_kernel(float* __restrict__ glob,
                                 const float* __restrict__ node_agg,
                                 const float* __restrict__ edge_agg,
                                 const float* __restrict__ W0, const float* __restrict__ b0,
                                 const float* __restrict__ W1, const float* __restrict__ b1,
                                 const float* __restrict__ ln_s, const float* __restrict__ ln_b) {
  __shared__ float gin[384];
  __shared__ float h[128];
  __shared__ float red4[4];
  int j = threadIdx.x;  // 128
  gin[j] = node_agg[j];
  gin[128 + j] = edge_agg[j];
  gin[256 + j] = glob[j];
  __syncthreads();
  float a = b0[j];
  for (int k = 0; k < 384; ++k) a += gin[k] * W0[k * L + j];
  h[j] = fmaxf(a, 0.f);
  __syncthreads();
  float o = b1[j];
  for (int k = 0; k < 128; ++k) o += h[k] * W1[k * L + j];
  o = fmaxf(o, 0.f);
  float x = o + glob[j];
  float sum = x, sq = x * x;
  for (int m = 1; m < 64; m <<= 1) { sum += __shfl_xor(sum, m); sq += __shfl_xor(sq, m); }
  if ((j & 63) == 0) { red4[(j >> 6) * 2] = sum; red4[(j >> 6) * 2 + 1] = sq; }
  __syncthreads();
  sum = red4[0] + red4[2]; sq = red4[1] + red4[3];
  float mu = sum * (1.f / 128.f);
  float var = sq * (1.f / 128.f) - mu * mu;
  float rsd = rsqrtf(var + 1e-6f);
  glob[j] = (x - mu) * rsd * ln_s[j] + ln_b[j];
}

__global__ void decode_kernel(const float* __restrict__ glob, const float* __restrict__ W,
                              const float* __restrict__ bias, float* __restrict__ out) {
  int j = threadIdx.x;  // 128
  float a = bias[j];
  for (int k = 0; k < 128; ++k) a += glob[k] * W[k * L + j];
  out[j] = a;
}

extern "C" void kernel_launch(void* const* d_in, const int* in_sizes, int n_in,
                              void* d_out, int out_size, void* d_ws, size_t ws_size,
                              hipStream_t stream) {
  const float* node_feats = (const float*)d_in[0];
  const float* edge_feats = (const float*)d_in[1];
  const float* globals_   = (const float*)d_in[2];
  const int*   senders    = (const int*)d_in[3];
  const int*   receivers  = (const int*)d_in[4];
  const float* emb_node_W = (const float*)d_in[5];
  const float* emb_node_b = (const float*)d_in[6];
  const float* emb_edge_W = (const float*)d_in[7];
  const float* emb_edge_b = (const float*)d_in[8];
  const float* emb_glob_W = (const float*)d_in[9];
  const float* emb_glob_b = (const float*)d_in[10];
  const float* edge_W0 = (const float*)d_in[11];
  const float* edge_b0 = (const float*)d_in[12];
  const float* edge_W1 = (const float*)d_in[13];
  const float* edge_b1 = (const float*)d_in[14];
  const float* node_W0 = (const float*)d_in[15];
  const float* node_b0 = (const float*)d_in[16];
  const float* node_W1 = (const float*)d_in[17];
  const float* node_b1 = (const float*)d_in[18];
  const float* glob_W0 = (const float*)d_in[19];
  const float* glob_b0 = (const float*)d_in[20];
  const float* glob_W1 = (const float*)d_in[21];
  const float* glob_b1 = (const float*)d_in[22];
  const float* ln_node_s = (const float*)d_in[23];
  const float* ln_node_b = (const float*)d_in[24];
  const float* ln_edge_s = (const float*)d_in[25];
  const float* ln_edge_b = (const float*)d_in[26];
  const float* ln_glob_s = (const float*)d_in[27];
  const float* ln_glob_b = (const float*)d_in[28];
  const float* dec_W = (const float*)d_in[29];
  const float* dec_b = (const float*)d_in[30];

  const int N = in_sizes[0] / 64;
  const int E = in_sizes[1] / 32;

  float* nodes = (float*)d_out;                   // [N][128]
  float* edges = nodes + (size_t)N * L;           // [E][128] (live fp32 edge state)
  float* gout  = edges + (size_t)E * L;           // [128]

  char* wp = (char*)d_ws;
  auto alloc = [&](size_t bytes) -> char* {
    char* p = wp;
    wp += (bytes + 255) & ~(size_t)255;
    return p;
  };
  float* glob = (float*)alloc(512);
  float* node_agg = (float*)alloc(512);
  float* edge_agg = (float*)alloc(512);
  float* b0e_eff = (float*)alloc(512);
  float* b0n_eff = (float*)alloc(512);
  unsigned short* eW0h = (unsigned short*)alloc((size_t)NSTEPS * 128 * 384 * 2);
  unsigned short* eW0l = (unsigned short*)alloc((size_t)NSTEPS * 128 * 384 * 2);
  unsigned short* eW1h = (unsigned short*)alloc((size_t)NSTEPS * 128 * 128 * 2);
  unsigned short* eW1l = (unsigned short*)alloc((size_t)NSTEPS * 128 * 128 * 2);
  unsigned short* nW0h = (unsigned short*)alloc((size_t)NSTEPS * 128 * 384 * 2);
  unsigned short* nW0l = (unsigned short*)alloc((size_t)NSTEPS * 128 * 384 * 2);
  unsigned short* nW1h = (unsigned short*)alloc((size_t)NSTEPS * 128 * 128 * 2);
  unsigned short* nW1l = (unsigned short*)alloc((size_t)NSTEPS * 128 * 128 * 2);
  unsigned* nodes_p = (unsigned*)alloc((size_t)N * L * 4);
  unsigned* sent_p  = (unsigned*)alloc((size_t)N * L * 4);
  unsigned* recv_p  = (unsigned*)alloc((size_t)N * L * 4);
  int* rp1 = (int*)alloc((size_t)(N + 1) * 4);
  int* rp2 = (int*)alloc((size_t)(N + 1) * 4);
  int* cnt1 = (int*)alloc((size_t)N * 4);
  int* cnt2 = (int*)alloc((size_t)N * 4);
  int* el1 = (int*)alloc((size_t)E * 4);
  int* el2 = (int*)alloc((size_t)E * 4);
  int* part = (int*)alloc(SCAN_B * 4);
  unsigned short* e16 = (unsigned short*)alloc((size_t)E * L * 2);
  (void)ws_size;

  // weight prep (bf16 hi/lo, transposed, first 384 rows of W0 only)
  conv_split_kernel<<<(NSTEPS * 128 * 384 + 255) / 256, 256, 0, stream>>>(edge_W0, eW0h, eW0l, 512, 384, NSTEPS);
  conv_split_kernel<<<(NSTEPS * 128 * 128 + 255) / 256, 256, 0, stream>>>(edge_W1, eW1h, eW1l, 128, 128, NSTEPS);
  conv_split_kernel<<<(NSTEPS * 128 * 384 + 255) / 256, 256, 0, stream>>>(node_W0, nW0h, nW0l, 512, 384, NSTEPS);
  conv_split_kernel<<<(NSTEPS * 128 * 128 + 255) / 256, 256, 0, stream>>>(node_W1, nW1h, nW1l, 128, 128, NSTEPS);

  // embeddings (exact fp32 math)
  embed_pack_kernel<<<2048, 128, 0, stream>>>(node_feats, emb_node_W, emb_node_b, nodes_p, N, 64);
  embed_kernel<<<4096, 128, 0, stream>>>(edge_feats, emb_edge_W, emb_edge_b, edges, E, 32);
  glob_embed_kernel<<<1, 128, 0, stream>>>(globals_, emb_glob_W, emb_glob_b, glob);

  // CSR build (once per launch)
  const int chunk = (N + SCAN_B - 1) / SCAN_B;
  hipMemsetAsync(cnt1, 0, (size_t)N * 4, stream);
  hipMemsetAsync(cnt2, 0, (size_t)N * 4, stream);
  hist_kernel<<<(E + 255) / 256, 256, 0, stream>>>(senders, receivers, cnt1, cnt2, E);
  scan_sum_kernel<<<SCAN_B, 256, 0, stream>>>(cnt1, part, N, chunk);
  scan_part_kernel<<<1, 64, 0, stream>>>(part, SCAN_B);
  scan_write_kernel<<<SCAN_B, 256, 0, stream>>>(cnt1, part, rp1, N, chunk, E);
  scan_sum_kernel<<<SCAN_B, 256, 0, stream>>>(cnt2, part, N, chunk);
  scan_part_kernel<<<1, 64, 0, stream>>>(part, SCAN_B);
  scan_write_kernel<<<SCAN_B, 256, 0, stream>>>(cnt2, part, rp2, N, chunk, E);
  hipMemsetAsync(cnt1, 0, (size_t)N * 4, stream);
  hipMemsetAsync(cnt2, 0, (size_t)N * 4, stream);
  fill_kernel<<<(E + 255) / 256, 256, 0, stream>>>(senders, receivers, rp1, rp2, cnt1, cnt2, el1, el2, E);

  const int egrid = (E + 127) / 128;
  const int ngrid = (N + 63) / 64;

  for (int s = 0; s < NSTEPS; ++s) {
    const bool last = (s == NSTEPS - 1);
    hipMemsetAsync(node_agg, 0, 512, stream);
    hipMemsetAsync(edge_agg, 0, 512, stream);

    fold_glob_kernel<<<1, 128, 0, stream>>>(edge_W0 + (size_t)s * 512 * L + 384 * L,
                                            edge_b0 + s * L, glob, b0e_eff);
    fold_glob_kernel<<<1, 128, 0, stream>>>(node_W0 + (size_t)s * 512 * L + 384 * L,
                                            node_b0 + s * L, glob, b0n_eff);

    block_step_kernel<128, true><<<egrid, 128, 0, stream>>>(
        edges, nullptr, nodes_p, nodes_p, senders, receivers,
        eW0h + (size_t)s * 128 * 384, eW0l + (size_t)s * 128 * 384, b0e_eff,
        eW1h + (size_t)s * 128 * 128, eW1l + (size_t)s * 128 * 128, edge_b1 + s * L,
        ln_edge_s + s * L, ln_edge_b + s * L,
        edge_agg, e16, edges, nullptr, E);

    gather_kernel<<<(N + 15) / 16, 256, 0, stream>>>(e16, rp1, el1, rp2, el2, sent_p, recv_p, N);

    block_step_kernel<64, false><<<ngrid, 64, 0, stream>>>(
        nullptr, nodes_p, sent_p, recv_p, nullptr, nullptr,
        nW0h + (size_t)s * 128 * 384, nW0l + (size_t)s * 128 * 384, b0n_eff,
        nW1h + (size_t)s * 128 * 128, nW1l + (size_t)s * 128 * 128, node_b1 + s * L,
        ln_node_s + s * L, ln_node_b + s * L,
        node_agg, nullptr, last ? nodes : nullptr, last ? nullptr : nodes_p, N);

    glob_step_kernel<<<1, 128, 0, stream>>>(
        glob, node_agg, edge_agg,
        glob_W0 + (size_t)s * 384 * L, glob_b0 + s * L,
        glob_W1 + (size_t)s * 128 * L, glob_b1 + s * L,
        ln_glob_s + s * L, ln_glob_b + s * L);
  }

  decode_kernel<<<1, 128, 0, stream>>>(glob, dec_W, dec_b, gout);
}

// Round 7
// 2493.521 us; speedup vs baseline: 2.0759x; 1.0293x over previous
//
#include <hip/hip_runtime.h>

#define L 128
#define NSTEPS 2
#define SCAN_B 250

typedef __attribute__((ext_vector_type(8))) short short8;
typedef __attribute__((ext_vector_type(4))) float f32x4;

static __device__ __forceinline__ unsigned short f2bf(float f) {
  unsigned int u = __float_as_uint(f);
  u += 0x7FFFu + ((u >> 16) & 1u);   // round-to-nearest-even
  return (unsigned short)(u >> 16);
}
static __device__ __forceinline__ unsigned short f2bf_trunc(float f) {
  return (unsigned short)(__float_as_uint(f) >> 16);
}
static __device__ __forceinline__ float bf2f(unsigned short h) {
  return __uint_as_float(((unsigned int)h) << 16);
}
static __device__ __forceinline__ float bfhi(unsigned u) {
  return __uint_as_float(u & 0xFFFF0000u);
}
static __device__ __forceinline__ float bflo(unsigned u) {
  return __uint_as_float(u << 16);
}
static __device__ __forceinline__ unsigned packf(float x) {
  unsigned short h = f2bf(x);
  unsigned short l = f2bf_trunc(x - bf2f(h));
  return ((unsigned)h << 16) | l;
}
static __device__ __forceinline__ float unpackf(unsigned p) {
  return bfhi(p) + bflo(p);
}

// hi16 of 8 packed u32 -> short8 (4 v_perm)
static __device__ __forceinline__ void unpack8_hi(const unsigned* __restrict__ p, short8& ah) {
  uint4 q0 = *(const uint4*)p;
  uint4 q1 = *(const uint4*)(p + 4);
  union U { unsigned u[4]; short8 s; } A;
  A.u[0] = __builtin_amdgcn_perm(q0.y, q0.x, 0x07060302u);
  A.u[1] = __builtin_amdgcn_perm(q0.w, q0.z, 0x07060302u);
  A.u[2] = __builtin_amdgcn_perm(q1.y, q1.x, 0x07060302u);
  A.u[3] = __builtin_amdgcn_perm(q1.w, q1.z, 0x07060302u);
  ah = A.s;
}

// hi[s][n][k] = bf16(in[s][k][n]) for k < Kkeep; lo = bf16(residual)
__global__ void conv_split_kernel(const float* __restrict__ in,
                                  unsigned short* __restrict__ hi,
                                  unsigned short* __restrict__ lo,
                                  int Ksrc, int Kkeep, int S) {
  int id = blockIdx.x * 256 + threadIdx.x;
  int nk = 128 * Kkeep;
  int total = S * nk;
  if (id >= total) return;
  int s = id / nk;
  int rem = id - s * nk;
  int n = rem / Kkeep;
  int k = rem - n * Kkeep;
  float x = in[(size_t)s * Ksrc * 128 + (size_t)k * 128 + n];
  unsigned short h = f2bf(x);
  hi[id] = h;
  lo[id] = f2bf(x - bf2f(h));
}

// fp32 out (edges: d_out array is the live state)
__global__ void embed_kernel(const float* __restrict__ feats, const float* __restrict__ W,
                             const float* __restrict__ bias, float* __restrict__ out,
                             int M, int K) {
  int j = threadIdx.x;  // 128
  for (int row = blockIdx.x; row < M; row += gridDim.x) {
    const float* f = feats + (size_t)row * K;
    float acc = bias[j];
    for (int k = 0; k < K; ++k) acc += f[k] * W[k * L + j];
    out[(size_t)row * L + j] = acc;
  }
}

// nodes: packed u32 (full precision state) + bf16-hi mirror (for edge gathers)
__global__ void embed_pack_kernel(const float* __restrict__ feats, const float* __restrict__ W,
                                  const float* __restrict__ bias,
                                  unsigned* __restrict__ outp,
                                  unsigned short* __restrict__ outh,
                                  int M, int K) {
  int j = threadIdx.x;  // 128
  for (int row = blockIdx.x; row < M; row += gridDim.x) {
    const float* f = feats + (size_t)row * K;
    float acc = bias[j];
    for (int k = 0; k < K; ++k) acc += f[k] * W[k * L + j];
    outp[(size_t)row * L + j] = packf(acc);
    outh[(size_t)row * L + j] = f2bf(acc);
  }
}

__global__ void glob_embed_kernel(const float* __restrict__ gin, const float* __restrict__ W,
                                  const float* __restrict__ bias, float* __restrict__ glob) {
  int j = threadIdx.x;  // 128
  float acc = bias[j];
  for (int k = 0; k < 16; ++k) acc += gin[k] * W[k * L + j];
  glob[j] = acc;
}

__global__ void fold_glob_kernel(const float* __restrict__ Wg, const float* __restrict__ b0,
                                 const float* __restrict__ glob, float* __restrict__ b0eff) {
  int j = threadIdx.x;  // 128
  float a = b0[j];
  for (int k = 0; k < 128; ++k) a += glob[k] * Wg[k * L + j];
  b0eff[j] = a;
}

// ---------------- CSR build ----------------
__global__ void hist_kernel(const int* __restrict__ senders, const int* __restrict__ receivers,
                            int* __restrict__ cnt1, int* __restrict__ cnt2, int E) {
  int e = blockIdx.x * 256 + threadIdx.x;
  if (e >= E) return;
  atomicAdd(&cnt1[senders[e]], 1);
  atomicAdd(&cnt2[receivers[e]], 1);
}

__global__ void scan_sum_kernel(const int* __restrict__ cnt, int* __restrict__ part,
                                int n, int chunk) {
  __shared__ int red[256];
  int b = blockIdx.x, t = threadIdx.x;
  int lo = b * chunk, hi = min(lo + chunk, n);
  red[t] = (lo + t < hi) ? cnt[lo + t] : 0;
  __syncthreads();
  for (int o = 128; o > 0; o >>= 1) { if (t < o) red[t] += red[t + o]; __syncthreads(); }
  if (t == 0) part[b] = red[0];
}

__global__ void scan_part_kernel(int* __restrict__ part, int nb) {
  if (threadIdx.x == 0) {
    int run = 0;
    for (int i = 0; i < nb; ++i) { int v = part[i]; part[i] = run; run += v; }
  }
}

__global__ void scan_write_kernel(const int* __restrict__ cnt, const int* __restrict__ part,
                                  int* __restrict__ rp, int n, int chunk, int E) {
  __shared__ int buf[256];
  int b = blockIdx.x, t = threadIdx.x;
  int lo = b * chunk, hi = min(lo + chunk, n);
  buf[t] = (lo + t < hi) ? cnt[lo + t] : 0;
  __syncthreads();
  if (t == 0) {
    int run = part[b];
    for (int i = 0; i < hi - lo; ++i) { rp[lo + i] = run; run += buf[i]; }
  }
  if (b == gridDim.x - 1 && t == 0) rp[n] = E;
}

__global__ void fill_kernel(const int* __restrict__ senders, const int* __restrict__ receivers,
                            const int* __restrict__ rp1, const int* __restrict__ rp2,
                            int* __restrict__ cnt1, int* __restrict__ cnt2,
                            int* __restrict__ el1, int* __restrict__ el2, int E) {
  int e = blockIdx.x * 256 + threadIdx.x;
  if (e >= E) return;
  int s = senders[e];
  int p = atomicAdd(&cnt1[s], 1);
  el1[rp1[s] + p] = e;
  int r = receivers[e];
  int q = atomicAdd(&cnt2[r], 1);
  el2[rp2[r] + q] = e;
}

// sent_h/recv_h (bf16-hi) from bf16 e-buffer via CSR. 16 threads per node.
__global__ __launch_bounds__(256) void gather_kernel(
    const unsigned short* __restrict__ e16,
    const int* __restrict__ rp1, const int* __restrict__ el1,
    const int* __restrict__ rp2, const int* __restrict__ el2,
    unsigned short* __restrict__ sent_h, unsigned short* __restrict__ recv_h, int N) {
  int t = threadIdx.x;
  int v = blockIdx.x * 16 + (t >> 4);
  if (v >= N) return;
  int cols = (t & 15) * 8;
  float a1[8], a2[8];
#pragma unroll
  for (int i = 0; i < 8; ++i) { a1[i] = 0.f; a2[i] = 0.f; }
  int s1 = rp1[v], n1 = rp1[v + 1] - s1;
  int s2 = rp2[v], n2 = rp2[v + 1] - s2;
  int mx = max(n1, n2);
  for (int j = 0; j < mx; ++j) {
    if (j < n1) {
      uint4 u = *(const uint4*)(e16 + (size_t)el1[s1 + j] * L + cols);
      a1[0] += bflo(u.x); a1[1] += bfhi(u.x);
      a1[2] += bflo(u.y); a1[3] += bfhi(u.y);
      a1[4] += bflo(u.z); a1[5] += bfhi(u.z);
      a1[6] += bflo(u.w); a1[7] += bfhi(u.w);
    }
    if (j < n2) {
      uint4 u = *(const uint4*)(e16 + (size_t)el2[s2 + j] * L + cols);
      a2[0] += bflo(u.x); a2[1] += bfhi(u.x);
      a2[2] += bflo(u.y); a2[3] += bfhi(u.y);
      a2[4] += bflo(u.z); a2[5] += bfhi(u.z);
      a2[6] += bflo(u.w); a2[7] += bfhi(u.w);
    }
  }
  short8 o1, o2;
#pragma unroll
  for (int i = 0; i < 8; ++i) { o1[i] = (short)f2bf(a1[i]); o2[i] = (short)f2bf(a2[i]); }
  *(short8*)(sent_h + (size_t)v * L + cols) = o1;
  *(short8*)(recv_h + (size_t)v * L + cols) = o2;
}

// Fused per-step update. Block = ROWS threads = ROWS/64 waves; each wave owns 64 rows
// (4 x 16-row frags) x 128 cols. ALL layer-0 A-operands are bf16-hi with 2-product
// MFMA (Ah*Bh + Ah*Bl) — weight precision kept via B hi/lo split. EDGE: seg0 from
// fp32 edges (convert), seg1/2 gathered from nodes_h (16B loads); NODE: seg0 hi-of-
// packed, seg1/2 from sent_h/recv_h. A-fragments software-pipelined 1 deep.
// Hidden bf16 in LDS (XOR-swizzled); layer1 2-product. Glob folded into b0eff.
template<int ROWS, bool EDGE_MODE>
__global__ __launch_bounds__(ROWS, 2)
void block_step_kernel(const float* __restrict__ xf,          // EDGE: fp32 self state
                       const unsigned* __restrict__ xp,       // NODE: packed self state
                       const unsigned short* __restrict__ g1h, // nodes_h | sent_h
                       const unsigned short* __restrict__ g2h, // nodes_h | recv_h
                       const int* __restrict__ idx1, const int* __restrict__ idx2,
                       const unsigned short* __restrict__ W0h,
                       const unsigned short* __restrict__ W0l,
                       const float* __restrict__ b0eff,
                       const unsigned short* __restrict__ W1h,
                       const unsigned short* __restrict__ W1l,
                       const float* __restrict__ b1,
                       const float* __restrict__ ln_s, const float* __restrict__ ln_b,
                       float* __restrict__ agg,
                       unsigned short* __restrict__ e_out,    // EDGE: bf16 e_new
                       float* __restrict__ xf_out,            // fp32 LN out (or null)
                       unsigned* __restrict__ xp_out,         // packed LN out (or null)
                       unsigned short* __restrict__ xh_out,   // bf16-hi LN out (or null)
                       int M) {
  constexpr int WAVES = ROWS / 64;
  __shared__ unsigned short Hbf[ROWS * 128];

  const int t = threadIdx.x;
  const int lane = t & 63;
  const int wg = t >> 6;
  const int c = lane & 15;
  const int g = lane >> 4;
  const int m0 = blockIdx.x * ROWS;
  const int valid = min(M - m0, ROWS);
  const int wbase = wg * 64;

  int rc4[4], j1[4], j2[4];
#pragma unroll
  for (int rf = 0; rf < 4; ++rf) {
    int rl = wbase + rf * 16 + c;
    int rc = min(rl, valid - 1);
    rc4[rf] = m0 + rc;
    if (EDGE_MODE) { j1[rf] = idx1[rc4[rf]]; j2[rf] = idx2[rc4[rf]]; }
    else           { j1[rf] = rc4[rf];       j2[rf] = rc4[rf]; }
  }

  const f32x4 z4 = {0.f, 0.f, 0.f, 0.f};
  f32x4 acc[4][8];
#pragma unroll
  for (int rf = 0; rf < 4; ++rf)
#pragma unroll
    for (int fn = 0; fn < 8; ++fn) acc[rf][fn] = z4;

  // load A-fragment (hi-only) for k-step ks (0..11)
  auto load_frag = [&](int ks, short8* a) {
    int seg = ks >> 2, kk = ks & 3;
    if (seg == 0) {
      if (EDGE_MODE) {
#pragma unroll
        for (int rf = 0; rf < 4; ++rf) {
          const float* bp = xf + (size_t)rc4[rf] * L + g * 8 + kk * 32;
          float4 v0 = *(const float4*)bp;
          float4 v1 = *(const float4*)(bp + 4);
          a[rf][0] = (short)f2bf(v0.x); a[rf][1] = (short)f2bf(v0.y);
          a[rf][2] = (short)f2bf(v0.z); a[rf][3] = (short)f2bf(v0.w);
          a[rf][4] = (short)f2bf(v1.x); a[rf][5] = (short)f2bf(v1.y);
          a[rf][6] = (short)f2bf(v1.z); a[rf][7] = (short)f2bf(v1.w);
        }
      } else {
#pragma unroll
        for (int rf = 0; rf < 4; ++rf)
          unpack8_hi(xp + (size_t)rc4[rf] * L + g * 8 + kk * 32, a[rf]);
      }
    } else {
      const unsigned short* src = (seg == 1) ? g1h : g2h;
      const int* rsel = (seg == 1) ? j1 : j2;
#pragma unroll
      for (int rf = 0; rf < 4; ++rf)
        a[rf] = *(const short8*)(src + (size_t)rsel[rf] * L + g * 8 + kk * 32);
    }
  };

  auto mfma_step = [&](int ks, const short8* a) {
#pragma unroll
    for (int fn = 0; fn < 8; ++fn) {
      size_t wb = (size_t)(fn * 16 + c) * 384 + ks * 32 + g * 8;
      short8 bh = *(const short8*)(W0h + wb);
      short8 bl = *(const short8*)(W0l + wb);
#pragma unroll
      for (int rf = 0; rf < 4; ++rf) {
        acc[rf][fn] = __builtin_amdgcn_mfma_f32_16x16x32_bf16(a[rf], bh, acc[rf][fn], 0, 0, 0);
        acc[rf][fn] = __builtin_amdgcn_mfma_f32_16x16x32_bf16(a[rf], bl, acc[rf][fn], 0, 0, 0);
      }
    }
  };

  // ---- layer 0: software-pipelined over 12 k-steps ----
  {
    short8 aA[4], aB[4];
    load_frag(0, aA);
#pragma unroll
    for (int ks = 0; ks < 12; ++ks) {
      if ((ks & 1) == 0) {
        if (ks < 11) load_frag(ks + 1, aB);
        mfma_step(ks, aA);
      } else {
        if (ks < 11) load_frag(ks + 1, aA);
        mfma_step(ks, aB);
      }
    }
  }

  // ---- hidden: relu(acc + b0eff) -> Hbf (bf16, swizzled; wave-private stripe) ----
#pragma unroll
  for (int fn = 0; fn < 8; ++fn) {
    int col = fn * 16 + c;
    float bb = b0eff[col];
    int unit = col >> 3;
#pragma unroll
    for (int rf = 0; rf < 4; ++rf) {
#pragma unroll
      for (int ri = 0; ri < 4; ++ri) {
        int rl = wbase + rf * 16 + g * 4 + ri;
        float x = fmaxf(acc[rf][fn][ri] + bb, 0.f);
        Hbf[rl * 128 + ((unit ^ (rl & 15)) << 3) + (col & 7)] = f2bf(x);
      }
    }
  }
  // no barrier: each wave reads only its own 64-row stripe

  // ---- layer 1: [ROWS x 128] @ [128 x 128], 2-product ----
  f32x4 acc2[4][8];
#pragma unroll
  for (int rf = 0; rf < 4; ++rf)
#pragma unroll
    for (int fn = 0; fn < 8; ++fn) acc2[rf][fn] = z4;
#pragma unroll
  for (int ks = 0; ks < 4; ++ks) {
    short8 ah[4];
#pragma unroll
    for (int rf = 0; rf < 4; ++rf) {
      int rl = wbase + rf * 16 + c;
      int unit = ks * 4 + g;
      ah[rf] = *(const short8*)&Hbf[rl * 128 + ((unit ^ (rl & 15)) << 3)];
    }
#pragma unroll
    for (int fn = 0; fn < 8; ++fn) {
      size_t wb = (size_t)(fn * 16 + c) * 128 + ks * 32 + g * 8;
      short8 bh = *(const short8*)(W1h + wb);
      short8 bl = *(const short8*)(W1l + wb);
#pragma unroll
      for (int rf = 0; rf < 4; ++rf) {
        acc2[rf][fn] = __builtin_amdgcn_mfma_f32_16x16x32_bf16(ah[rf], bh, acc2[rf][fn], 0, 0, 0);
        acc2[rf][fn] = __builtin_amdgcn_mfma_f32_16x16x32_bf16(ah[rf], bl, acc2[rf][fn], 0, 0, 0);
      }
    }
  }

  // ---- epilogue, per row-fragment ----
  float colagg[8];
#pragma unroll
  for (int fn = 0; fn < 8; ++fn) colagg[fn] = 0.f;

#pragma unroll
  for (int rf = 0; rf < 4; ++rf) {
    const int rb = wbase + rf * 16 + g * 4;
    float sum[4] = {0.f, 0.f, 0.f, 0.f}, sq[4] = {0.f, 0.f, 0.f, 0.f};
    float xv[8][4];
#pragma unroll
    for (int fn = 0; fn < 8; ++fn) {
      int col = fn * 16 + c;
      float bb = b1[col];
#pragma unroll
      for (int ri = 0; ri < 4; ++ri) {
        int row = rb + ri;
        float e = fmaxf(acc2[rf][fn][ri] + bb, 0.f);
        if (row < valid) {
          if (EDGE_MODE) e_out[(size_t)(m0 + row) * L + col] = f2bf(e);
          colagg[fn] += e;
          float xprev;
          if (EDGE_MODE) xprev = xf[(size_t)(m0 + row) * L + col];
          else           xprev = unpackf(xp[(size_t)(m0 + row) * L + col]);
          float x = e + xprev;
          xv[fn][ri] = x;
          sum[ri] += x;
          sq[ri] += x * x;
        } else {
          xv[fn][ri] = 0.f;
        }
      }
    }
#pragma unroll
    for (int mask = 1; mask <= 8; mask <<= 1) {
#pragma unroll
      for (int ri = 0; ri < 4; ++ri) {
        sum[ri] += __shfl_xor(sum[ri], mask);
        sq[ri] += __shfl_xor(sq[ri], mask);
      }
    }
    float mu[4], rs[4];
#pragma unroll
    for (int ri = 0; ri < 4; ++ri) {
      mu[ri] = sum[ri] * (1.f / 128.f);
      float var = sq[ri] * (1.f / 128.f) - mu[ri] * mu[ri];
      rs[ri] = rsqrtf(var + 1e-6f);
    }
#pragma unroll
    for (int fn = 0; fn < 8; ++fn) {
      int col = fn * 16 + c;
      float lns = ln_s[col], lnb = ln_b[col];
#pragma unroll
      for (int ri = 0; ri < 4; ++ri) {
        int row = rb + ri;
        if (row < valid) {
          float y = (xv[fn][ri] - mu[ri]) * rs[ri] * lns + lnb;
          if (xf_out) xf_out[(size_t)(m0 + row) * L + col] = y;
          if (xp_out) xp_out[(size_t)(m0 + row) * L + col] = packf(y);
          if (xh_out) xh_out[(size_t)(m0 + row) * L + col] = f2bf(y);
        }
      }
    }
  }

  // column aggregate
#pragma unroll
  for (int mask = 16; mask <= 32; mask <<= 1)
#pragma unroll
    for (int fn = 0; fn < 8; ++fn) colagg[fn] += __shfl_xor(colagg[fn], mask);
  if (WAVES == 1) {
    if (lane < 16) {
#pragma unroll
      for (int fn = 0; fn < 8; ++fn) atomicAdd(agg + fn * 16 + lane, colagg[fn]);
    }
  } else {
    __syncthreads();               // all Hbf reads complete; reuse as float scratch
    float* F = (float*)Hbf;
    if (lane < 16) {
#pragma unroll
      for (int fn = 0; fn < 8; ++fn) F[wg * 128 + fn * 16 + lane] = colagg[fn];
    }
    __syncthreads();
    if (t < 128) {
      float s = 0.f;
#pragma unroll
      for (int w = 0; w < WAVES; ++w) s += F[w * 128 + t];
      atomicAdd(agg + t, s);
    }
  }
}

__global__ void glob_step_kernel(float* __restrict__ glob,
                                 const float* __restrict__ node_agg,
                                 const float* __restrict__ edge_agg,
                                 const float* __restrict__ W0, const float* __restrict__ b0,
                                 const float* __restrict__ W1, const float* __restrict__ b1,
                                 const float* __restrict__ ln_s, const float* __restrict__ ln_b) {
  __shared__ float gin[384];
  __shared__ float h[128];
  __shared__ float red4[4];
  int j = threadIdx.x;  // 128
  gin[j] = node_agg[j];
  gin[128 + j] = edge_agg[j];
  gin[256 + j] = glob[j];
  __syncthreads();
  float a = b0[j];
  for (int k = 0; k < 384; ++k) a += gin[k] * W0[k * L + j];
  h[j] = fmaxf(a, 0.f);
  __syncthreads();
  float o = b1[j];
  for (int k = 0; k < 128; ++k) o += h[k] * W1[k * L + j];
  o = fmaxf(o, 0.f);
  float x = o + glob[j];
  float sum = x, sq = x * x;
  for (int m = 1; m < 64; m <<= 1) { sum += __shfl_xor(sum, m); sq += __shfl_xor(sq, m); }
  if ((j & 63) == 0) { red4[(j >> 6) * 2] = sum; red4[(j >> 6) * 2 + 1] = sq; }
  __syncthreads();
  sum = red4[0] + red4[2]; sq = red4[1] + red4[3];
  float mu = sum * (1.f / 128.f);
  float var = sq * (1.f / 128.f) - mu * mu;
  float rsd = rsqrtf(var + 1e-6f);
  glob[j] = (x - mu) * rsd * ln_s[j] + ln_b[j];
}

__global__ void decode_kernel(const float* __restrict__ glob, const float* __restrict__ W,
                              const float* __restrict__ bias, float* __restrict__ out) {
  int j = threadIdx.x;  // 128
  float a = bias[j];
  for (int k = 0; k < 128; ++k) a += glob[k] * W[k * L + j];
  out[j] = a;
}

extern "C" void kernel_launch(void* const* d_in, const int* in_sizes, int n_in,
                              void* d_out, int out_size, void* d_ws, size_t ws_size,
                              hipStream_t stream) {
  const float* node_feats = (const float*)d_in[0];
  const float* edge_feats = (const float*)d_in[1];
  const float* globals_   = (const float*)d_in[2];
  const int*   senders    = (const int*)d_in[3];
  const int*   receivers  = (const int*)d_in[4];
  const float* emb_node_W = (const float*)d_in[5];
  const float* emb_node_b = (const float*)d_in[6];
  const float* emb_edge_W = (const float*)d_in[7];
  const float* emb_edge_b = (const float*)d_in[8];
  const float* emb_glob_W = (const float*)d_in[9];
  const float* emb_glob_b = (const float*)d_in[10];
  const float* edge_W0 = (const float*)d_in[11];
  const float* edge_b0 = (const float*)d_in[12];
  const float* edge_W1 = (const float*)d_in[13];
  const float* edge_b1 = (const float*)d_in[14];
  const float* node_W0 = (const float*)d_in[15];
  const float* node_b0 = (const float*)d_in[16];
  const float* node_W1 = (const float*)d_in[17];
  const float* node_b1 = (const float*)d_in[18];
  const float* glob_W0 = (const float*)d_in[19];
  const float* glob_b0 = (const float*)d_in[20];
  const float* glob_W1 = (const float*)d_in[21];
  const float* glob_b1 = (const float*)d_in[22];
  const float* ln_node_s = (const float*)d_in[23];
  const float* ln_node_b = (const float*)d_in[24];
  const float* ln_edge_s = (const float*)d_in[25];
  const float* ln_edge_b = (const float*)d_in[26];
  const float* ln_glob_s = (const float*)d_in[27];
  const float* ln_glob_b = (const float*)d_in[28];
  const float* dec_W = (const float*)d_in[29];
  const float* dec_b = (const float*)d_in[30];

  const int N = in_sizes[0] / 64;
  const int E = in_sizes[1] / 32;

  float* nodes = (float*)d_out;                   // [N][128]
  float* edges = nodes + (size_t)N * L;           // [E][128] (live fp32 edge state)
  float* gout  = edges + (size_t)E * L;           // [128]

  char* wp = (char*)d_ws;
  auto alloc = [&](size_t bytes) -> char* {
    char* p = wp;
    wp += (bytes + 255) & ~(size_t)255;
    return p;
  };
  float* glob = (float*)alloc(512);
  float* node_agg = (float*)alloc(512);
  float* edge_agg = (float*)alloc(512);
  float* b0e_eff = (float*)alloc(512);
  float* b0n_eff = (float*)alloc(512);
  unsigned short* eW0h = (unsigned short*)alloc((size_t)NSTEPS * 128 * 384 * 2);
  unsigned short* eW0l = (unsigned short*)alloc((size_t)NSTEPS * 128 * 384 * 2);
  unsigned short* eW1h = (unsigned short*)alloc((size_t)NSTEPS * 128 * 128 * 2);
  unsigned short* eW1l = (unsigned short*)alloc((size_t)NSTEPS * 128 * 128 * 2);
  unsigned short* nW0h = (unsigned short*)alloc((size_t)NSTEPS * 128 * 384 * 2);
  unsigned short* nW0l = (unsigned short*)alloc((size_t)NSTEPS * 128 * 384 * 2);
  unsigned short* nW1h = (unsigned short*)alloc((size_t)NSTEPS * 128 * 128 * 2);
  unsigned short* nW1l = (unsigned short*)alloc((size_t)NSTEPS * 128 * 128 * 2);
  unsigned* nodes_p = (unsigned*)alloc((size_t)N * L * 4);
  unsigned short* nodes_h = (unsigned short*)alloc((size_t)N * L * 2);
  unsigned short* sent_h  = (unsigned short*)alloc((size_t)N * L * 2);
  unsigned short* recv_h  = (unsigned short*)alloc((size_t)N * L * 2);
  int* rp1 = (int*)alloc((size_t)(N + 1) * 4);
  int* rp2 = (int*)alloc((size_t)(N + 1) * 4);
  int* cnt1 = (int*)alloc((size_t)N * 4);
  int* cnt2 = (int*)alloc((size_t)N * 4);
  int* el1 = (int*)alloc((size_t)E * 4);
  int* el2 = (int*)alloc((size_t)E * 4);
  int* part = (int*)alloc(SCAN_B * 4);
  unsigned short* e16 = (unsigned short*)alloc((size_t)E * L * 2);
  (void)ws_size;

  // weight prep (bf16 hi/lo, transposed, first 384 rows of W0 only)
  conv_split_kernel<<<(NSTEPS * 128 * 384 + 255) / 256, 256, 0, stream>>>(edge_W0, eW0h, eW0l, 512, 384, NSTEPS);
  conv_split_kernel<<<(NSTEPS * 128 * 128 + 255) / 256, 256, 0, stream>>>(edge_W1, eW1h, eW1l, 128, 128, NSTEPS);
  conv_split_kernel<<<(NSTEPS * 128 * 384 + 255) / 256, 256, 0, stream>>>(node_W0, nW0h, nW0l, 512, 384, NSTEPS);
  conv_split_kernel<<<(NSTEPS * 128 * 128 + 255) / 256, 256, 0, stream>>>(node_W1, nW1h, nW1l, 128, 128, NSTEPS);

  // embeddings (exact fp32 math)
  embed_pack_kernel<<<2048, 128, 0, stream>>>(node_feats, emb_node_W, emb_node_b, nodes_p, nodes_h, N, 64);
  embed_kernel<<<4096, 128, 0, stream>>>(edge_feats, emb_edge_W, emb_edge_b, edges, E, 32);
  glob_embed_kernel<<<1, 128, 0, stream>>>(globals_, emb_glob_W, emb_glob_b, glob);

  // CSR build (once per launch)
  const int chunk = (N + SCAN_B - 1) / SCAN_B;
  hipMemsetAsync(cnt1, 0, (size_t)N * 4, stream);
  hipMemsetAsync(cnt2, 0, (size_t)N * 4, stream);
  hist_kernel<<<(E + 255) / 256, 256, 0, stream>>>(senders, receivers, cnt1, cnt2, E);
  scan_sum_kernel<<<SCAN_B, 256, 0, stream>>>(cnt1, part, N, chunk);
  scan_part_kernel<<<1, 64, 0, stream>>>(part, SCAN_B);
  scan_write_kernel<<<SCAN_B, 256, 0, stream>>>(cnt1, part, rp1, N, chunk, E);
  scan_sum_kernel<<<SCAN_B, 256, 0, stream>>>(cnt2, part, N, chunk);
  scan_part_kernel<<<1, 64, 0, stream>>>(part, SCAN_B);
  scan_write_kernel<<<SCAN_B, 256, 0, stream>>>(cnt2, part, rp2, N, chunk, E);
  hipMemsetAsync(cnt1, 0, (size_t)N * 4, stream);
  hipMemsetAsync(cnt2, 0, (size_t)N * 4, stream);
  fill_kernel<<<(E + 255) / 256, 256, 0, stream>>>(senders, receivers, rp1, rp2, cnt1, cnt2, el1, el2, E);

  const int egrid = (E + 127) / 128;
  const int ngrid = (N + 63) / 64;

  for (int s = 0; s < NSTEPS; ++s) {
    const bool last = (s == NSTEPS - 1);
    hipMemsetAsync(node_agg, 0, 512, stream);
    hipMemsetAsync(edge_agg, 0, 512, stream);

    fold_glob_kernel<<<1, 128, 0, stream>>>(edge_W0 + (size_t)s * 512 * L + 384 * L,
                                            edge_b0 + s * L, glob, b0e_eff);
    fold_glob_kernel<<<1, 128, 0, stream>>>(node_W0 + (size_t)s * 512 * L + 384 * L,
                                            node_b0 + s * L, glob, b0n_eff);

    block_step_kernel<128, true><<<egrid, 128, 0, stream>>>(
        edges, nullptr, nodes_h, nodes_h, senders, receivers,
        eW0h + (size_t)s * 128 * 384, eW0l + (size_t)s * 128 * 384, b0e_eff,
        eW1h + (size_t)s * 128 * 128, eW1l + (size_t)s * 128 * 128, edge_b1 + s * L,
        ln_edge_s + s * L, ln_edge_b + s * L,
        edge_agg, e16, edges, nullptr, nullptr, E);

    gather_kernel<<<(N + 15) / 16, 256, 0, stream>>>(e16, rp1, el1, rp2, el2, sent_h, recv_h, N);

    block_step_kernel<64, false><<<ngrid, 64, 0, stream>>>(
        nullptr, nodes_p, sent_h, recv_h, nullptr, nullptr,
        nW0h + (size_t)s * 128 * 384, nW0l + (size_t)s * 128 * 384, b0n_eff,
        nW1h + (size_t)s * 128 * 128, nW1l + (size_t)s * 128 * 128, node_b1 + s * L,
        ln_node_s + s * L, ln_node_b + s * L,
        node_agg, nullptr, last ? nodes : nullptr, last ? nullptr : nodes_p,
        last ? nullptr : nodes_h, N);

    glob_step_kernel<<<1, 128, 0, stream>>>(
        glob, node_agg, edge_agg,
        glob_W0 + (size_t)s * 384 * L, glob_b0 + s * L,
        glob_W1 + (size_t)s * 128 * L, glob_b1 + s * L,
        ln_glob_s + s * L, ln_glob_b + s * L);
  }

  decode_kernel<<<1, 128, 0, stream>>>(glob, dec_W, dec_b, gout);
}

// Round 8
// 2115.377 us; speedup vs baseline: 2.4470x; 1.1788x over previous
//
#include <hip/hip_runtime.h>

#define L 128
#define NSTEPS 2
#define SCAN_B 250

typedef __attribute__((ext_vector_type(8))) short short8;
typedef __attribute__((ext_vector_type(4))) float f32x4;

static __device__ __forceinline__ unsigned short f2bf(float f) {
  unsigned int u = __float_as_uint(f);
  u += 0x7FFFu + ((u >> 16) & 1u);   // round-to-nearest-even
  return (unsigned short)(u >> 16);
}
static __device__ __forceinline__ unsigned short f2bf_trunc(float f) {
  return (unsigned short)(__float_as_uint(f) >> 16);
}
static __device__ __forceinline__ float bf2f(unsigned short h) {
  return __uint_as_float(((unsigned int)h) << 16);
}
static __device__ __forceinline__ float bfhi(unsigned u) {
  return __uint_as_float(u & 0xFFFF0000u);
}
static __device__ __forceinline__ float bflo(unsigned u) {
  return __uint_as_float(u << 16);
}
static __device__ __forceinline__ unsigned packf(float x) {
  unsigned short h = f2bf(x);
  unsigned short l = f2bf_trunc(x - bf2f(h));
  return ((unsigned)h << 16) | l;
}
static __device__ __forceinline__ float unpackf(unsigned p) {
  return bfhi(p) + bflo(p);
}

// hi16 of 8 packed u32 -> short8 (4 v_perm)
static __device__ __forceinline__ void unpack8_hi(const unsigned* __restrict__ p, short8& ah) {
  uint4 q0 = *(const uint4*)p;
  uint4 q1 = *(const uint4*)(p + 4);
  union U { unsigned u[4]; short8 s; } A;
  A.u[0] = __builtin_amdgcn_perm(q0.y, q0.x, 0x07060302u);
  A.u[1] = __builtin_amdgcn_perm(q0.w, q0.z, 0x07060302u);
  A.u[2] = __builtin_amdgcn_perm(q1.y, q1.x, 0x07060302u);
  A.u[3] = __builtin_amdgcn_perm(q1.w, q1.z, 0x07060302u);
  ah = A.s;
}

// layer-0 weights in FRAGMENT ORDER: out[s][ks][hl][fn][c][g][8]
// k = ks*32 + g*8 + j (first 384 rows only), n = fn*16 + c; hl: 0=hi 1=lo
__global__ void conv_frag_kernel(const float* __restrict__ in, unsigned short* __restrict__ out,
                                 int S) {
  int id = blockIdx.x * 256 + threadIdx.x;
  int total = S * 12 * 8192;
  if (id >= total) return;
  int chunkid = id >> 13;          // s*12 + ks
  int within = id & 8191;
  int s = chunkid / 12, ks = chunkid % 12;
  int hl = within >> 12;
  int rem = within & 4095;
  int fn = rem >> 9;
  int rem2 = rem & 511;
  int c = rem2 >> 5;
  int rem3 = rem2 & 31;
  int g = rem3 >> 3;
  int j = rem3 & 7;
  int k = ks * 32 + g * 8 + j;
  int n = fn * 16 + c;
  float x = in[(size_t)s * 512 * 128 + (size_t)k * 128 + n];
  unsigned short h = f2bf(x);
  out[id] = hl ? f2bf_trunc(x - bf2f(h)) : h;
}

// hi[s][n][k] = bf16(in[s][k][n]) for k < Kkeep; lo = bf16(residual)  (layer-1 W)
__global__ void conv_split_kernel(const float* __restrict__ in,
                                  unsigned short* __restrict__ hi,
                                  unsigned short* __restrict__ lo,
                                  int Ksrc, int Kkeep, int S) {
  int id = blockIdx.x * 256 + threadIdx.x;
  int nk = 128 * Kkeep;
  int total = S * nk;
  if (id >= total) return;
  int s = id / nk;
  int rem = id - s * nk;
  int n = rem / Kkeep;
  int k = rem - n * Kkeep;
  float x = in[(size_t)s * Ksrc * 128 + (size_t)k * 128 + n];
  unsigned short h = f2bf(x);
  hi[id] = h;
  lo[id] = f2bf(x - bf2f(h));
}

// fp32 out (edges: d_out array is the live state)
__global__ void embed_kernel(const float* __restrict__ feats, const float* __restrict__ W,
                             const float* __restrict__ bias, float* __restrict__ out,
                             int M, int K) {
  int j = threadIdx.x;  // 128
  for (int row = blockIdx.x; row < M; row += gridDim.x) {
    const float* f = feats + (size_t)row * K;
    float acc = bias[j];
    for (int k = 0; k < K; ++k) acc += f[k] * W[k * L + j];
    out[(size_t)row * L + j] = acc;
  }
}

// nodes: packed u32 (full precision state) + bf16-hi mirror (for edge gathers)
__global__ void embed_pack_kernel(const float* __restrict__ feats, const float* __restrict__ W,
                                  const float* __restrict__ bias,
                                  unsigned* __restrict__ outp,
                                  unsigned short* __restrict__ outh,
                                  int M, int K) {
  int j = threadIdx.x;  // 128
  for (int row = blockIdx.x; row < M; row += gridDim.x) {
    const float* f = feats + (size_t)row * K;
    float acc = bias[j];
    for (int k = 0; k < K; ++k) acc += f[k] * W[k * L + j];
    outp[(size_t)row * L + j] = packf(acc);
    outh[(size_t)row * L + j] = f2bf(acc);
  }
}

__global__ void glob_embed_kernel(const float* __restrict__ gin, const float* __restrict__ W,
                                  const float* __restrict__ bias, float* __restrict__ glob) {
  int j = threadIdx.x;  // 128
  float acc = bias[j];
  for (int k = 0; k < 16; ++k) acc += gin[k] * W[k * L + j];
  glob[j] = acc;
}

__global__ void fold_glob_kernel(const float* __restrict__ Wg, const float* __restrict__ b0,
                                 const float* __restrict__ glob, float* __restrict__ b0eff) {
  int j = threadIdx.x;  // 128
  float a = b0[j];
  for (int k = 0; k < 128; ++k) a += glob[k] * Wg[k * L + j];
  b0eff[j] = a;
}

// ---------------- CSR build ----------------
__global__ void hist_kernel(const int* __restrict__ senders, const int* __restrict__ receivers,
                            int* __restrict__ cnt1, int* __restrict__ cnt2, int E) {
  int e = blockIdx.x * 256 + threadIdx.x;
  if (e >= E) return;
  atomicAdd(&cnt1[senders[e]], 1);
  atomicAdd(&cnt2[receivers[e]], 1);
}

__global__ void scan_sum_kernel(const int* __restrict__ cnt, int* __restrict__ part,
                                int n, int chunk) {
  __shared__ int red[256];
  int b = blockIdx.x, t = threadIdx.x;
  int lo = b * chunk, hi = min(lo + chunk, n);
  red[t] = (lo + t < hi) ? cnt[lo + t] : 0;
  __syncthreads();
  for (int o = 128; o > 0; o >>= 1) { if (t < o) red[t] += red[t + o]; __syncthreads(); }
  if (t == 0) part[b] = red[0];
}

__global__ void scan_part_kernel(int* __restrict__ part, int nb) {
  if (threadIdx.x == 0) {
    int run = 0;
    for (int i = 0; i < nb; ++i) { int v = part[i]; part[i] = run; run += v; }
  }
}

__global__ void scan_write_kernel(const int* __restrict__ cnt, const int* __restrict__ part,
                                  int* __restrict__ rp, int n, int chunk, int E) {
  __shared__ int buf[256];
  int b = blockIdx.x, t = threadIdx.x;
  int lo = b * chunk, hi = min(lo + chunk, n);
  buf[t] = (lo + t < hi) ? cnt[lo + t] : 0;
  __syncthreads();
  if (t == 0) {
    int run = part[b];
    for (int i = 0; i < hi - lo; ++i) { rp[lo + i] = run; run += buf[i]; }
  }
  if (b == gridDim.x - 1 && t == 0) rp[n] = E;
}

__global__ void fill_kernel(const int* __restrict__ senders, const int* __restrict__ receivers,
                            const int* __restrict__ rp1, const int* __restrict__ rp2,
                            int* __restrict__ cnt1, int* __restrict__ cnt2,
                            int* __restrict__ el1, int* __restrict__ el2, int E) {
  int e = blockIdx.x * 256 + threadIdx.x;
  if (e >= E) return;
  int s = senders[e];
  int p = atomicAdd(&cnt1[s], 1);
  el1[rp1[s] + p] = e;
  int r = receivers[e];
  int q = atomicAdd(&cnt2[r], 1);
  el2[rp2[r] + q] = e;
}

// sent_h/recv_h (bf16-hi) from bf16 e-buffer via CSR. 16 threads per node.
__global__ __launch_bounds__(256) void gather_kernel(
    const unsigned short* __restrict__ e16,
    const int* __restrict__ rp1, const int* __restrict__ el1,
    const int* __restrict__ rp2, const int* __restrict__ el2,
    unsigned short* __restrict__ sent_h, unsigned short* __restrict__ recv_h, int N) {
  int t = threadIdx.x;
  int v = blockIdx.x * 16 + (t >> 4);
  if (v >= N) return;
  int cols = (t & 15) * 8;
  float a1[8], a2[8];
#pragma unroll
  for (int i = 0; i < 8; ++i) { a1[i] = 0.f; a2[i] = 0.f; }
  int s1 = rp1[v], n1 = rp1[v + 1] - s1;
  int s2 = rp2[v], n2 = rp2[v + 1] - s2;
  int mx = max(n1, n2);
  for (int j = 0; j < mx; ++j) {
    if (j < n1) {
      uint4 u = *(const uint4*)(e16 + (size_t)el1[s1 + j] * L + cols);
      a1[0] += bflo(u.x); a1[1] += bfhi(u.x);
      a1[2] += bflo(u.y); a1[3] += bfhi(u.y);
      a1[4] += bflo(u.z); a1[5] += bfhi(u.z);
      a1[6] += bflo(u.w); a1[7] += bfhi(u.w);
    }
    if (j < n2) {
      uint4 u = *(const uint4*)(e16 + (size_t)el2[s2 + j] * L + cols);
      a2[0] += bflo(u.x); a2[1] += bfhi(u.x);
      a2[2] += bflo(u.y); a2[3] += bfhi(u.y);
      a2[4] += bflo(u.z); a2[5] += bfhi(u.z);
      a2[6] += bflo(u.w); a2[7] += bfhi(u.w);
    }
  }
  short8 o1, o2;
#pragma unroll
  for (int i = 0; i < 8; ++i) { o1[i] = (short)f2bf(a1[i]); o2[i] = (short)f2bf(a2[i]); }
  *(short8*)(sent_h + (size_t)v * L + cols) = o1;
  *(short8*)(recv_h + (size_t)v * L + cols) = o2;
}

// Fused per-step update. Block = 128 threads = 2 waves; each wave owns 64 rows
// (4 x 16-row frags) x 128 cols. Layer-0 weights stream through a double-buffered
// 2x16KB LDS region (fragment-ordered chunks, reg-staged, 1 barrier/k-step), shared
// by both waves. A-operands bf16-hi with 2-product MFMA (Ah*Bh + Ah*Bl). The hidden
// bf16 tile ALIASES the W double-buffer (W dead after layer 0). Layer-1 weights
// direct from L2. Glob segment folded into b0eff.
template<int ROWS, bool EDGE_MODE>
__global__ __launch_bounds__(ROWS, 2)
void block_step_kernel(const float* __restrict__ xf,          // EDGE: fp32 self state
                       const unsigned* __restrict__ xp,       // NODE: packed self state
                       const unsigned short* __restrict__ g1h, // nodes_h | sent_h
                       const unsigned short* __restrict__ g2h, // nodes_h | recv_h
                       const int* __restrict__ idx1, const int* __restrict__ idx2,
                       const unsigned short* __restrict__ W0c, // frag-ordered [12][2][8][16][4][8]
                       const float* __restrict__ b0eff,
                       const unsigned short* __restrict__ W1h,
                       const unsigned short* __restrict__ W1l,
                       const float* __restrict__ b1,
                       const float* __restrict__ ln_s, const float* __restrict__ ln_b,
                       float* __restrict__ agg,
                       unsigned short* __restrict__ e_out,    // EDGE: bf16 e_new
                       float* __restrict__ xf_out,            // fp32 LN out (or null)
                       unsigned* __restrict__ xp_out,         // packed LN out (or null)
                       unsigned short* __restrict__ xh_out,   // bf16-hi LN out (or null)
                       int M) {
  static_assert(ROWS == 128, "pipeline assumes 128 threads");
  constexpr int WAVES = ROWS / 64;
  __shared__ __align__(16) unsigned short SL[16384];   // 32 KB: W dbuf, later Hbf

  const int t = threadIdx.x;
  const int lane = t & 63;
  const int wg = t >> 6;
  const int c = lane & 15;
  const int g = lane >> 4;
  const int m0 = blockIdx.x * ROWS;
  const int valid = min(M - m0, ROWS);
  const int wbase = wg * 64;

  int rc4[4], j1[4], j2[4];
#pragma unroll
  for (int rf = 0; rf < 4; ++rf) {
    int rl = wbase + rf * 16 + c;
    int rc = min(rl, valid - 1);
    rc4[rf] = m0 + rc;
    if (EDGE_MODE) { j1[rf] = idx1[rc4[rf]]; j2[rf] = idx2[rc4[rf]]; }
    else           { j1[rf] = rc4[rf];       j2[rf] = rc4[rf]; }
  }

  const f32x4 z4 = {0.f, 0.f, 0.f, 0.f};
  f32x4 acc[4][8];
#pragma unroll
  for (int rf = 0; rf < 4; ++rf)
#pragma unroll
    for (int fn = 0; fn < 8; ++fn) acc[rf][fn] = z4;

  // ---- W staging: reg-staged double buffer ----
  short8 wreg[8];
  auto loadW = [&](int ks) {
    const unsigned short* src = W0c + (size_t)ks * 8192 + t * 8;
#pragma unroll
    for (int i = 0; i < 8; ++i) wreg[i] = *(const short8*)(src + i * 1024);
  };
  auto writeW = [&](int buf) {
    unsigned short* dst = &SL[buf * 8192 + t * 8];
#pragma unroll
    for (int i = 0; i < 8; ++i) *(short8*)(dst + i * 1024) = wreg[i];
  };

  // load A-fragment (hi-only) for k-step ks (0..11)
  auto load_frag = [&](int ks, short8* a) {
    int seg = ks >> 2, kk = ks & 3;
    if (seg == 0) {
      if (EDGE_MODE) {
#pragma unroll
        for (int rf = 0; rf < 4; ++rf) {
          const float* bp = xf + (size_t)rc4[rf] * L + g * 8 + kk * 32;
          float4 v0 = *(const float4*)bp;
          float4 v1 = *(const float4*)(bp + 4);
          a[rf][0] = (short)f2bf(v0.x); a[rf][1] = (short)f2bf(v0.y);
          a[rf][2] = (short)f2bf(v0.z); a[rf][3] = (short)f2bf(v0.w);
          a[rf][4] = (short)f2bf(v1.x); a[rf][5] = (short)f2bf(v1.y);
          a[rf][6] = (short)f2bf(v1.z); a[rf][7] = (short)f2bf(v1.w);
        }
      } else {
#pragma unroll
        for (int rf = 0; rf < 4; ++rf)
          unpack8_hi(xp + (size_t)rc4[rf] * L + g * 8 + kk * 32, a[rf]);
      }
    } else {
      const unsigned short* src = (seg == 1) ? g1h : g2h;
      const int* rsel = (seg == 1) ? j1 : j2;
#pragma unroll
      for (int rf = 0; rf < 4; ++rf)
        a[rf] = *(const short8*)(src + (size_t)rsel[rf] * L + g * 8 + kk * 32);
    }
  };

  auto mfma_phase = [&](int buf, const short8* a) {
#pragma unroll
    for (int fn = 0; fn < 8; ++fn) {
      int off = buf * 8192 + fn * 512 + c * 32 + g * 8;
      short8 bh = *(const short8*)&SL[off];
      short8 bl = *(const short8*)&SL[off + 4096];
#pragma unroll
      for (int rf = 0; rf < 4; ++rf) {
        acc[rf][fn] = __builtin_amdgcn_mfma_f32_16x16x32_bf16(a[rf], bh, acc[rf][fn], 0, 0, 0);
        acc[rf][fn] = __builtin_amdgcn_mfma_f32_16x16x32_bf16(a[rf], bl, acc[rf][fn], 0, 0, 0);
      }
    }
  };

  // ---- layer 0: 12 k-steps, W through LDS dbuf, A reg ping-pong ----
  {
    short8 aA[4], aB[4];
    loadW(0);
    load_frag(0, aA);
    writeW(0);
    loadW(1);
    __syncthreads();     // buf0 ready
#pragma unroll
    for (int ks = 0; ks < 12; ++ks) {
      short8* aCur = (ks & 1) ? aB : aA;
      short8* aNxt = (ks & 1) ? aA : aB;
      if (ks < 11) load_frag(ks + 1, aNxt);
      mfma_phase(ks & 1, aCur);
      if (ks < 11) {
        writeW((ks & 1) ^ 1);
        if (ks < 10) loadW(ks + 2);
      }
      __syncthreads();   // writes visible; buf[cur] reads done before next overwrite
    }
  }

  // ---- hidden: relu(acc + b0eff) -> Hbf (bf16, swizzled; wave-private stripe) ----
  unsigned short* Hbf = SL;   // aliases W dbuf (dead)
#pragma unroll
  for (int fn = 0; fn < 8; ++fn) {
    int col = fn * 16 + c;
    float bb = b0eff[col];
    int unit = col >> 3;
#pragma unroll
    for (int rf = 0; rf < 4; ++rf) {
#pragma unroll
      for (int ri = 0; ri < 4; ++ri) {
        int rl = wbase + rf * 16 + g * 4 + ri;
        float x = fmaxf(acc[rf][fn][ri] + bb, 0.f);
        Hbf[rl * 128 + ((unit ^ (rl & 15)) << 3) + (col & 7)] = f2bf(x);
      }
    }
  }
  // no barrier: each wave reads only its own 64-row stripe

  // ---- layer 1: [ROWS x 128] @ [128 x 128], 2-product, W1 direct L2 ----
  f32x4 acc2[4][8];
#pragma unroll
  for (int rf = 0; rf < 4; ++rf)
#pragma unroll
    for (int fn = 0; fn < 8; ++fn) acc2[rf][fn] = z4;
#pragma unroll
  for (int ks = 0; ks < 4; ++ks) {
    short8 ah[4];
#pragma unroll
    for (int rf = 0; rf < 4; ++rf) {
      int rl = wbase + rf * 16 + c;
      int unit = ks * 4 + g;
      ah[rf] = *(const short8*)&Hbf[rl * 128 + ((unit ^ (rl & 15)) << 3)];
    }
#pragma unroll
    for (int fn = 0; fn < 8; ++fn) {
      size_t wb = (size_t)(fn * 16 + c) * 128 + ks * 32 + g * 8;
      short8 bh = *(const short8*)(W1h + wb);
      short8 bl = *(const short8*)(W1l + wb);
#pragma unroll
      for (int rf = 0; rf < 4; ++rf) {
        acc2[rf][fn] = __builtin_amdgcn_mfma_f32_16x16x32_bf16(ah[rf], bh, acc2[rf][fn], 0, 0, 0);
        acc2[rf][fn] = __builtin_amdgcn_mfma_f32_16x16x32_bf16(ah[rf], bl, acc2[rf][fn], 0, 0, 0);
      }
    }
  }

  // ---- epilogue, per row-fragment ----
  float colagg[8];
#pragma unroll
  for (int fn = 0; fn < 8; ++fn) colagg[fn] = 0.f;

#pragma unroll
  for (int rf = 0; rf < 4; ++rf) {
    const int rb = wbase + rf * 16 + g * 4;
    float sum[4] = {0.f, 0.f, 0.f, 0.f}, sq[4] = {0.f, 0.f, 0.f, 0.f};
    float xv[8][4];
#pragma unroll
    for (int fn = 0; fn < 8; ++fn) {
      int col = fn * 16 + c;
      float bb = b1[col];
#pragma unroll
      for (int ri = 0; ri < 4; ++ri) {
        int row = rb + ri;
        float e = fmaxf(acc2[rf][fn][ri] + bb, 0.f);
        if (row < valid) {
          if (EDGE_MODE) e_out[(size_t)(m0 + row) * L + col] = f2bf(e);
          colagg[fn] += e;
          float xprev;
          if (EDGE_MODE) xprev = xf[(size_t)(m0 + row) * L + col];
          else           xprev = unpackf(xp[(size_t)(m0 + row) * L + col]);
          float x = e + xprev;
          xv[fn][ri] = x;
          sum[ri] += x;
          sq[ri] += x * x;
        } else {
          xv[fn][ri] = 0.f;
        }
      }
    }
#pragma unroll
    for (int mask = 1; mask <= 8; mask <<= 1) {
#pragma unroll
      for (int ri = 0; ri < 4; ++ri) {
        sum[ri] += __shfl_xor(sum[ri], mask);
        sq[ri] += __shfl_xor(sq[ri], mask);
      }
    }
    float mu[4], rs[4];
#pragma unroll
    for (int ri = 0; ri < 4; ++ri) {
      mu[ri] = sum[ri] * (1.f / 128.f);
      float var = sq[ri] * (1.f / 128.f) - mu[ri] * mu[ri];
      rs[ri] = rsqrtf(var + 1e-6f);
    }
#pragma unroll
    for (int fn = 0; fn < 8; ++fn) {
      int col = fn * 16 + c;
      float lns = ln_s[col], lnb = ln_b[col];
#pragma unroll
      for (int ri = 0; ri < 4; ++ri) {
        int row = rb + ri;
        if (row < valid) {
          float y = (xv[fn][ri] - mu[ri]) * rs[ri] * lns + lnb;
          if (xf_out) xf_out[(size_t)(m0 + row) * L + col] = y;
          if (xp_out) xp_out[(size_t)(m0 + row) * L + col] = packf(y);
          if (xh_out) xh_out[(size_t)(m0 + row) * L + col] = f2bf(y);
        }
      }
    }
  }

  // column aggregate
#pragma unroll
  for (int mask = 16; mask <= 32; mask <<= 1)
#pragma unroll
    for (int fn = 0; fn < 8; ++fn) colagg[fn] += __shfl_xor(colagg[fn], mask);
  __syncthreads();               // all Hbf reads complete; reuse as float scratch
  float* F = (float*)SL;
  if (lane < 16) {
#pragma unroll
    for (int fn = 0; fn < 8; ++fn) F[wg * 128 + fn * 16 + lane] = colagg[fn];
  }
  __syncthreads();
  if (t < 128) {
    float s = 0.f;
#pragma unroll
    for (int w = 0; w < WAVES; ++w) s += F[w * 128 + t];
    atomicAdd(agg + t, s);
  }
}

__global__ void glob_step_kernel(float* __restrict__ glob,
                                 const float* __restrict__ node_agg,
                                 const float* __restrict__ edge_agg,
                                 const float* __restrict__ W0, const float* __restrict__ b0,
                                 const float* __restrict__ W1, const float* __restrict__ b1,
                                 const float* __restrict__ ln_s, const float* __restrict__ ln_b) {
  __shared__ float gin[384];
  __shared__ float h[128];
  __shared__ float red4[4];
  int j = threadIdx.x;  // 128
  gin[j] = node_agg[j];
  gin[128 + j] = edge_agg[j];
  gin[256 + j] = glob[j];
  __syncthreads();
  float a = b0[j];
  for (int k = 0; k < 384; ++k) a += gin[k] * W0[k * L + j];
  h[j] = fmaxf(a, 0.f);
  __syncthreads();
  float o = b1[j];
  for (int k = 0; k < 128; ++k) o += h[k] * W1[k * L + j];
  o = fmaxf(o, 0.f);
  float x = o + glob[j];
  float sum = x, sq = x * x;
  for (int m = 1; m < 64; m <<= 1) { sum += __shfl_xor(sum, m); sq += __shfl_xor(sq, m); }
  if ((j & 63) == 0) { red4[(j >> 6) * 2] = sum; red4[(j >> 6) * 2 + 1] = sq; }
  __syncthreads();
  sum = red4[0] + red4[2]; sq = red4[1] + red4[3];
  float mu = sum * (1.f / 128.f);
  float var = sq * (1.f / 128.f) - mu * mu;
  float rsd = rsqrtf(var + 1e-6f);
  glob[j] = (x - mu) * rsd * ln_s[j] + ln_b[j];
}

__global__ void decode_kernel(const float* __restrict__ glob, const float* __restrict__ W,
                              const float* __restrict__ bias, float* __restrict__ out) {
  int j = threadIdx.x;  // 128
  float a = bias[j];
  for (int k = 0; k < 128; ++k) a += glob[k] * W[k * L + j];
  out[j] = a;
}

extern "C" void kernel_launch(void* const* d_in, const int* in_sizes, int n_in,
                              void* d_out, int out_size, void* d_ws, size_t ws_size,
                              hipStream_t stream) {
  const float* node_feats = (const float*)d_in[0];
  const float* edge_feats = (const float*)d_in[1];
  const float* globals_   = (const float*)d_in[2];
  const int*   senders    = (const int*)d_in[3];
  const int*   receivers  = (const int*)d_in[4];
  const float* emb_node_W = (const float*)d_in[5];
  const float* emb_node_b = (const float*)d_in[6];
  const float* emb_edge_W = (const float*)d_in[7];
  const float* emb_edge_b = (const float*)d_in[8];
  const float* emb_glob_W = (const float*)d_in[9];
  const float* emb_glob_b = (const float*)d_in[10];
  const float* edge_W0 = (const float*)d_in[11];
  const float* edge_b0 = (const float*)d_in[12];
  const float* edge_W1 = (const float*)d_in[13];
  const float* edge_b1 = (const float*)d_in[14];
  const float* node_W0 = (const float*)d_in[15];
  const float* node_b0 = (const float*)d_in[16];
  const float* node_W1 = (const float*)d_in[17];
  const float* node_b1 = (const float*)d_in[18];
  const float* glob_W0 = (const float*)d_in[19];
  const float* glob_b0 = (const float*)d_in[20];
  const float* glob_W1 = (const float*)d_in[21];
  const float* glob_b1 = (const float*)d_in[22];
  const float* ln_node_s = (const float*)d_in[23];
  const float* ln_node_b = (const float*)d_in[24];
  const float* ln_edge_s = (const float*)d_in[25];
  const float* ln_edge_b = (const float*)d_in[26];
  const float* ln_glob_s = (const float*)d_in[27];
  const float* ln_glob_b = (const float*)d_in[28];
  const float* dec_W = (const float*)d_in[29];
  const float* dec_b = (const float*)d_in[30];

  const int N = in_sizes[0] / 64;
  const int E = in_sizes[1] / 32;

  float* nodes = (float*)d_out;                   // [N][128]
  float* edges = nodes + (size_t)N * L;           // [E][128] (live fp32 edge state)
  float* gout  = edges + (size_t)E * L;           // [128]

  char* wp = (char*)d_ws;
  auto alloc = [&](size_t bytes) -> char* {
    char* p = wp;
    wp += (bytes + 255) & ~(size_t)255;
    return p;
  };
  float* glob = (float*)alloc(512);
  float* node_agg = (float*)alloc(512);
  float* edge_agg = (float*)alloc(512);
  float* b0e_eff = (float*)alloc(512);
  float* b0n_eff = (float*)alloc(512);
  unsigned short* eW0c = (unsigned short*)alloc((size_t)NSTEPS * 12 * 8192 * 2);
  unsigned short* nW0c = (unsigned short*)alloc((size_t)NSTEPS * 12 * 8192 * 2);
  unsigned short* eW1h = (unsigned short*)alloc((size_t)NSTEPS * 128 * 128 * 2);
  unsigned short* eW1l = (unsigned short*)alloc((size_t)NSTEPS * 128 * 128 * 2);
  unsigned short* nW1h = (unsigned short*)alloc((size_t)NSTEPS * 128 * 128 * 2);
  unsigned short* nW1l = (unsigned short*)alloc((size_t)NSTEPS * 128 * 128 * 2);
  unsigned* nodes_p = (unsigned*)alloc((size_t)N * L * 4);
  unsigned short* nodes_h = (unsigned short*)alloc((size_t)N * L * 2);
  unsigned short* sent_h  = (unsigned short*)alloc((size_t)N * L * 2);
  unsigned short* recv_h  = (unsigned short*)alloc((size_t)N * L * 2);
  int* rp1 = (int*)alloc((size_t)(N + 1) * 4);
  int* rp2 = (int*)alloc((size_t)(N + 1) * 4);
  int* cnt1 = (int*)alloc((size_t)N * 4);
  int* cnt2 = (int*)alloc((size_t)N * 4);
  int* el1 = (int*)alloc((size_t)E * 4);
  int* el2 = (int*)alloc((size_t)E * 4);
  int* part = (int*)alloc(SCAN_B * 4);
  unsigned short* e16 = (unsigned short*)alloc((size_t)E * L * 2);
  (void)ws_size;

  // weight prep: layer0 fragment-ordered, layer1 transposed hi/lo
  conv_frag_kernel<<<(NSTEPS * 12 * 8192 + 255) / 256, 256, 0, stream>>>(edge_W0, eW0c, NSTEPS);
  conv_frag_kernel<<<(NSTEPS * 12 * 8192 + 255) / 256, 256, 0, stream>>>(node_W0, nW0c, NSTEPS);
  conv_split_kernel<<<(NSTEPS * 128 * 128 + 255) / 256, 256, 0, stream>>>(edge_W1, eW1h, eW1l, 128, 128, NSTEPS);
  conv_split_kernel<<<(NSTEPS * 128 * 128 + 255) / 256, 256, 0, stream>>>(node_W1, nW1h, nW1l, 128, 128, NSTEPS);

  // embeddings (exact fp32 math)
  embed_pack_kernel<<<2048, 128, 0, stream>>>(node_feats, emb_node_W, emb_node_b, nodes_p, nodes_h, N, 64);
  embed_kernel<<<4096, 128, 0, stream>>>(edge_feats, emb_edge_W, emb_edge_b, edges, E, 32);
  glob_embed_kernel<<<1, 128, 0, stream>>>(globals_, emb_glob_W, emb_glob_b, glob);

  // CSR build (once per launch)
  const int chunk = (N + SCAN_B - 1) / SCAN_B;
  hipMemsetAsync(cnt1, 0, (size_t)N * 4, stream);
  hipMemsetAsync(cnt2, 0, (size_t)N * 4, stream);
  hist_kernel<<<(E + 255) / 256, 256, 0, stream>>>(senders, receivers, cnt1, cnt2, E);
  scan_sum_kernel<<<SCAN_B, 256, 0, stream>>>(cnt1, part, N, chunk);
  scan_part_kernel<<<1, 64, 0, stream>>>(part, SCAN_B);
  scan_write_kernel<<<SCAN_B, 256, 0, stream>>>(cnt1, part, rp1, N, chunk, E);
  scan_sum_kernel<<<SCAN_B, 256, 0, stream>>>(cnt2, part, N, chunk);
  scan_part_kernel<<<1, 64, 0, stream>>>(part, SCAN_B);
  scan_write_kernel<<<SCAN_B, 256, 0, stream>>>(cnt2, part, rp2, N, chunk, E);
  hipMemsetAsync(cnt1, 0, (size_t)N * 4, stream);
  hipMemsetAsync(cnt2, 0, (size_t)N * 4, stream);
  fill_kernel<<<(E + 255) / 256, 256, 0, stream>>>(senders, receivers, rp1, rp2, cnt1, cnt2, el1, el2, E);

  const int egrid = (E + 127) / 128;
  const int ngrid = (N + 127) / 128;

  for (int s = 0; s < NSTEPS; ++s) {
    const bool last = (s == NSTEPS - 1);
    hipMemsetAsync(node_agg, 0, 512, stream);
    hipMemsetAsync(edge_agg, 0, 512, stream);

    fold_glob_kernel<<<1, 128, 0, stream>>>(edge_W0 + (size_t)s * 512 * L + 384 * L,
                                            edge_b0 + s * L, glob, b0e_eff);
    fold_glob_kernel<<<1, 128, 0, stream>>>(node_W0 + (size_t)s * 512 * L + 384 * L,
                                            node_b0 + s * L, glob, b0n_eff);

    block_step_kernel<128, true><<<egrid, 128, 0, stream>>>(
        edges, nullptr, nodes_h, nodes_h, senders, receivers,
        eW0c + (size_t)s * 12 * 8192, b0e_eff,
        eW1h + (size_t)s * 128 * 128, eW1l + (size_t)s * 128 * 128, edge_b1 + s * L,
        ln_edge_s + s * L, ln_edge_b + s * L,
        edge_agg, e16, edges, nullptr, nullptr, E);

    gather_kernel<<<(N + 15) / 16, 256, 0, stream>>>(e16, rp1, el1, rp2, el2, sent_h, recv_h, N);

    block_step_kernel<128, false><<<ngrid, 128, 0, stream>>>(
        nullptr, nodes_p, sent_h, recv_h, nullptr, nullptr,
        nW0c + (size_t)s * 12 * 8192, b0n_eff,
        nW1h + (size_t)s * 128 * 128, nW1l + (size_t)s * 128 * 128, node_b1 + s * L,
        ln_node_s + s * L, ln_node_b + s * L,
        node_agg, nullptr, last ? nodes : nullptr, last ? nullptr : nodes_p,
        last ? nullptr : nodes_h, N);

    glob_step_kernel<<<1, 128, 0, stream>>>(
        glob, node_agg, edge_agg,
        glob_W0 + (size_t)s * 384 * L, glob_b0 + s * L,
        glob_W1 + (size_t)s * 128 * L, glob_b1 + s * L,
        ln_glob_s + s * L, ln_glob_b + s * L);
  }

  decode_kernel<<<1, 128, 0, stream>>>(glob, dec_W, dec_b, gout);
}

// Round 9
// 1672.893 us; speedup vs baseline: 3.0942x; 1.2645x over previous
//
#include <hip/hip_runtime.h>

#define L 128
#define NSTEPS 2
#define SCAN_B 250

typedef __attribute__((ext_vector_type(8))) short short8;
typedef __attribute__((ext_vector_type(4))) float f32x4;

static __device__ __forceinline__ unsigned short f2bf(float f) {
  unsigned int u = __float_as_uint(f);
  u += 0x7FFFu + ((u >> 16) & 1u);   // round-to-nearest-even
  return (unsigned short)(u >> 16);
}
static __device__ __forceinline__ unsigned short f2bf_trunc(float f) {
  return (unsigned short)(__float_as_uint(f) >> 16);
}
static __device__ __forceinline__ float bf2f(unsigned short h) {
  return __uint_as_float(((unsigned int)h) << 16);
}
static __device__ __forceinline__ float bfhi(unsigned u) {
  return __uint_as_float(u & 0xFFFF0000u);
}
static __device__ __forceinline__ float bflo(unsigned u) {
  return __uint_as_float(u << 16);
}
static __device__ __forceinline__ unsigned packf(float x) {
  unsigned short h = f2bf(x);
  unsigned short l = f2bf_trunc(x - bf2f(h));
  return ((unsigned)h << 16) | l;
}
static __device__ __forceinline__ float unpackf(unsigned p) {
  return bfhi(p) + bflo(p);
}

// hi16 of 8 packed u32 -> short8 (4 v_perm)
static __device__ __forceinline__ void unpack8_hi(const unsigned* __restrict__ p, short8& ah) {
  uint4 q0 = *(const uint4*)p;
  uint4 q1 = *(const uint4*)(p + 4);
  union U { unsigned u[4]; short8 s; } A;
  A.u[0] = __builtin_amdgcn_perm(q0.y, q0.x, 0x07060302u);
  A.u[1] = __builtin_amdgcn_perm(q0.w, q0.z, 0x07060302u);
  A.u[2] = __builtin_amdgcn_perm(q1.y, q1.x, 0x07060302u);
  A.u[3] = __builtin_amdgcn_perm(q1.w, q1.z, 0x07060302u);
  ah = A.s;
}

// layer-0 weights in FRAGMENT ORDER: out[s][ks][hl][fn][c][g][8]
// k = ks*32 + g*8 + j (first 384 rows only), n = fn*16 + c; hl: 0=hi 1=lo
__global__ void conv_frag_kernel(const float* __restrict__ in, unsigned short* __restrict__ out,
                                 int S) {
  int id = blockIdx.x * 256 + threadIdx.x;
  int total = S * 12 * 8192;
  if (id >= total) return;
  int chunkid = id >> 13;          // s*12 + ks
  int within = id & 8191;
  int s = chunkid / 12, ks = chunkid % 12;
  int hl = within >> 12;
  int rem = within & 4095;
  int fn = rem >> 9;
  int rem2 = rem & 511;
  int c = rem2 >> 5;
  int rem3 = rem2 & 31;
  int g = rem3 >> 3;
  int j = rem3 & 7;
  int k = ks * 32 + g * 8 + j;
  int n = fn * 16 + c;
  float x = in[(size_t)s * 512 * 128 + (size_t)k * 128 + n];
  unsigned short h = f2bf(x);
  out[id] = hl ? f2bf_trunc(x - bf2f(h)) : h;
}

// hi[s][n][k] = bf16(in[s][k][n]) for k < Kkeep; lo = bf16(residual)  (layer-1 W)
__global__ void conv_split_kernel(const float* __restrict__ in,
                                  unsigned short* __restrict__ hi,
                                  unsigned short* __restrict__ lo,
                                  int Ksrc, int Kkeep, int S) {
  int id = blockIdx.x * 256 + threadIdx.x;
  int nk = 128 * Kkeep;
  int total = S * nk;
  if (id >= total) return;
  int s = id / nk;
  int rem = id - s * nk;
  int n = rem / Kkeep;
  int k = rem - n * Kkeep;
  float x = in[(size_t)s * Ksrc * 128 + (size_t)k * 128 + n];
  unsigned short h = f2bf(x);
  hi[id] = h;
  lo[id] = f2bf(x - bf2f(h));
}

// W-in-register embed: thread j holds W column j (K regs); 4 rows in flight.
// Outputs any of: fp32, packed u32, bf16-hi.
template<int K>
__global__ __launch_bounds__(128, 4)
void embed_reg_kernel(const float* __restrict__ feats, const float* __restrict__ W,
                      const float* __restrict__ bias,
                      float* __restrict__ outf, unsigned* __restrict__ outp,
                      unsigned short* __restrict__ outh, int M) {
  int j = threadIdx.x;  // 128
  float w[K];
#pragma unroll
  for (int k = 0; k < K; ++k) w[k] = W[k * L + j];
  float bb = bias[j];
  int ng = (M + 3) >> 2;
  for (int gi = blockIdx.x; gi < ng; gi += gridDim.x) {
    int r0 = gi * 4;
    int r[4];
#pragma unroll
    for (int ri = 0; ri < 4; ++ri) r[ri] = min(r0 + ri, M - 1);
    float acc[4] = {bb, bb, bb, bb};
#pragma unroll
    for (int k4 = 0; k4 < K; k4 += 4) {
#pragma unroll
      for (int ri = 0; ri < 4; ++ri) {
        float4 f = *(const float4*)(feats + (size_t)r[ri] * K + k4);
        acc[ri] = fmaf(f.x, w[k4], acc[ri]);
        acc[ri] = fmaf(f.y, w[k4 + 1], acc[ri]);
        acc[ri] = fmaf(f.z, w[k4 + 2], acc[ri]);
        acc[ri] = fmaf(f.w, w[k4 + 3], acc[ri]);
      }
    }
#pragma unroll
    for (int ri = 0; ri < 4; ++ri) {
      size_t o = (size_t)r[ri] * L + j;
      if (outf) outf[o] = acc[ri];
      if (outp) outp[o] = packf(acc[ri]);
      if (outh) outh[o] = f2bf(acc[ri]);
    }
  }
}

// glob embed + step-0 bias folds + agg reset (single block, 128 threads)
__global__ void glob_embed_fold_kernel(const float* __restrict__ gin,
                                       const float* __restrict__ W, const float* __restrict__ bias,
                                       float* __restrict__ glob,
                                       const float* __restrict__ eWg, const float* __restrict__ eb0,
                                       float* __restrict__ b0e,
                                       const float* __restrict__ nWg, const float* __restrict__ nb0,
                                       float* __restrict__ b0n,
                                       float* __restrict__ node_agg, float* __restrict__ edge_agg) {
  __shared__ float gl[128];
  int j = threadIdx.x;  // 128
  float acc = bias[j];
  for (int k = 0; k < 16; ++k) acc += gin[k] * W[k * L + j];
  glob[j] = acc;
  gl[j] = acc;
  node_agg[j] = 0.f;
  edge_agg[j] = 0.f;
  __syncthreads();
  float ae = eb0[j], an = nb0[j];
  for (int k = 0; k < 128; ++k) {
    float g = gl[k];
    ae = fmaf(g, eWg[k * L + j], ae);
    an = fmaf(g, nWg[k * L + j], an);
  }
  b0e[j] = ae;
  b0n[j] = an;
}

// ---------------- CSR build ----------------
__global__ void hist_kernel(const int* __restrict__ senders, const int* __restrict__ receivers,
                            int* __restrict__ cnt1, int* __restrict__ cnt2, int E) {
  int e = blockIdx.x * 256 + threadIdx.x;
  if (e >= E) return;
  atomicAdd(&cnt1[senders[e]], 1);
  atomicAdd(&cnt2[receivers[e]], 1);
}

__global__ void scan_sum_kernel(const int* __restrict__ cnt, int* __restrict__ part,
                                int n, int chunk) {
  __shared__ int red[256];
  int b = blockIdx.x, t = threadIdx.x;
  int lo = b * chunk, hi = min(lo + chunk, n);
  red[t] = (lo + t < hi) ? cnt[lo + t] : 0;
  __syncthreads();
  for (int o = 128; o > 0; o >>= 1) { if (t < o) red[t] += red[t + o]; __syncthreads(); }
  if (t == 0) part[b] = red[0];
}

__global__ void scan_part_kernel(int* __restrict__ part, int nb) {
  if (threadIdx.x == 0) {
    int run = 0;
    for (int i = 0; i < nb; ++i) { int v = part[i]; part[i] = run; run += v; }
  }
}

__global__ void scan_write_kernel(const int* __restrict__ cnt, const int* __restrict__ part,
                                  int* __restrict__ rp, int n, int chunk, int E) {
  __shared__ int buf[256];
  int b = blockIdx.x, t = threadIdx.x;
  int lo = b * chunk, hi = min(lo + chunk, n);
  buf[t] = (lo + t < hi) ? cnt[lo + t] : 0;
  __syncthreads();
  if (t == 0) {
    int run = part[b];
    for (int i = 0; i < hi - lo; ++i) { rp[lo + i] = run; run += buf[i]; }
  }
  if (b == gridDim.x - 1 && t == 0) rp[n] = E;
}

__global__ void fill_kernel(const int* __restrict__ senders, const int* __restrict__ receivers,
                            const int* __restrict__ rp1, const int* __restrict__ rp2,
                            int* __restrict__ cnt1, int* __restrict__ cnt2,
                            int* __restrict__ el1, int* __restrict__ el2, int E) {
  int e = blockIdx.x * 256 + threadIdx.x;
  if (e >= E) return;
  int s = senders[e];
  int p = atomicAdd(&cnt1[s], 1);
  el1[rp1[s] + p] = e;
  int r = receivers[e];
  int q = atomicAdd(&cnt2[r], 1);
  el2[rp2[r] + q] = e;
}

// sent_h/recv_h (bf16-hi) from bf16 e-buffer via CSR. 16 threads per node.
__global__ __launch_bounds__(256) void gather_kernel(
    const unsigned short* __restrict__ e16,
    const int* __restrict__ rp1, const int* __restrict__ el1,
    const int* __restrict__ rp2, const int* __restrict__ el2,
    unsigned short* __restrict__ sent_h, unsigned short* __restrict__ recv_h, int N) {
  int t = threadIdx.x;
  int v = blockIdx.x * 16 + (t >> 4);
  if (v >= N) return;
  int cols = (t & 15) * 8;
  float a1[8], a2[8];
#pragma unroll
  for (int i = 0; i < 8; ++i) { a1[i] = 0.f; a2[i] = 0.f; }
  int s1 = rp1[v], n1 = rp1[v + 1] - s1;
  int s2 = rp2[v], n2 = rp2[v + 1] - s2;
  int mx = max(n1, n2);
  for (int j = 0; j < mx; ++j) {
    if (j < n1) {
      uint4 u = *(const uint4*)(e16 + (size_t)el1[s1 + j] * L + cols);
      a1[0] += bflo(u.x); a1[1] += bfhi(u.x);
      a1[2] += bflo(u.y); a1[3] += bfhi(u.y);
      a1[4] += bflo(u.z); a1[5] += bfhi(u.z);
      a1[6] += bflo(u.w); a1[7] += bfhi(u.w);
    }
    if (j < n2) {
      uint4 u = *(const uint4*)(e16 + (size_t)el2[s2 + j] * L + cols);
      a2[0] += bflo(u.x); a2[1] += bfhi(u.x);
      a2[2] += bflo(u.y); a2[3] += bfhi(u.y);
      a2[4] += bflo(u.z); a2[5] += bfhi(u.z);
      a2[6] += bflo(u.w); a2[7] += bfhi(u.w);
    }
  }
  short8 o1, o2;
#pragma unroll
  for (int i = 0; i < 8; ++i) { o1[i] = (short)f2bf(a1[i]); o2[i] = (short)f2bf(a2[i]); }
  *(short8*)(sent_h + (size_t)v * L + cols) = o1;
  *(short8*)(recv_h + (size_t)v * L + cols) = o2;
}

// Fused per-step update. Block = 128 threads = 2 waves; each wave owns 64 rows
// (4 x 16-row frags) x 128 cols. Layer-0 weights stream through a double-buffered
// 2x16KB LDS region (fragment-ordered chunks, reg-staged, 1 barrier/k-step), shared
// by both waves. A-operands bf16-hi with 2-product MFMA (Ah*Bh + Ah*Bl). The hidden
// bf16 tile ALIASES the W double-buffer (W dead after layer 0). Layer-1 weights
// direct from L2. Glob segment folded into b0eff.
template<int ROWS, bool EDGE_MODE>
__global__ __launch_bounds__(ROWS, 2)
void block_step_kernel(const float* __restrict__ xf,          // EDGE: fp32 self state
                       const unsigned* __restrict__ xp,       // NODE: packed self state
                       const unsigned short* __restrict__ g1h, // nodes_h | sent_h
                       const unsigned short* __restrict__ g2h, // nodes_h | recv_h
                       const int* __restrict__ idx1, const int* __restrict__ idx2,
                       const unsigned short* __restrict__ W0c, // frag-ordered [12][2][8][16][4][8]
                       const float* __restrict__ b0eff,
                       const unsigned short* __restrict__ W1h,
                       const unsigned short* __restrict__ W1l,
                       const float* __restrict__ b1,
                       const float* __restrict__ ln_s, const float* __restrict__ ln_b,
                       float* __restrict__ agg,
                       unsigned short* __restrict__ e_out,    // EDGE: bf16 e_new
                       float* __restrict__ xf_out,            // fp32 LN out (or null)
                       unsigned* __restrict__ xp_out,         // packed LN out (or null)
                       unsigned short* __restrict__ xh_out,   // bf16-hi LN out (or null)
                       int M) {
  static_assert(ROWS == 128, "pipeline assumes 128 threads");
  constexpr int WAVES = ROWS / 64;
  __shared__ __align__(16) unsigned short SL[16384];   // 32 KB: W dbuf, later Hbf

  const int t = threadIdx.x;
  const int lane = t & 63;
  const int wg = t >> 6;
  const int c = lane & 15;
  const int g = lane >> 4;
  const int m0 = blockIdx.x * ROWS;
  const int valid = min(M - m0, ROWS);
  const int wbase = wg * 64;

  int rc4[4], j1[4], j2[4];
#pragma unroll
  for (int rf = 0; rf < 4; ++rf) {
    int rl = wbase + rf * 16 + c;
    int rc = min(rl, valid - 1);
    rc4[rf] = m0 + rc;
    if (EDGE_MODE) { j1[rf] = idx1[rc4[rf]]; j2[rf] = idx2[rc4[rf]]; }
    else           { j1[rf] = rc4[rf];       j2[rf] = rc4[rf]; }
  }

  const f32x4 z4 = {0.f, 0.f, 0.f, 0.f};
  f32x4 acc[4][8];
#pragma unroll
  for (int rf = 0; rf < 4; ++rf)
#pragma unroll
    for (int fn = 0; fn < 8; ++fn) acc[rf][fn] = z4;

  // ---- W staging: reg-staged double buffer ----
  short8 wreg[8];
  auto loadW = [&](int ks) {
    const unsigned short* src = W0c + (size_t)ks * 8192 + t * 8;
#pragma unroll
    for (int i = 0; i < 8; ++i) wreg[i] = *(const short8*)(src + i * 1024);
  };
  auto writeW = [&](int buf) {
    unsigned short* dst = &SL[buf * 8192 + t * 8];
#pragma unroll
    for (int i = 0; i < 8; ++i) *(short8*)(dst + i * 1024) = wreg[i];
  };

  // load A-fragment (hi-only) for k-step ks (0..11)
  auto load_frag = [&](int ks, short8* a) {
    int seg = ks >> 2, kk = ks & 3;
    if (seg == 0) {
      if (EDGE_MODE) {
#pragma unroll
        for (int rf = 0; rf < 4; ++rf) {
          const float* bp = xf + (size_t)rc4[rf] * L + g * 8 + kk * 32;
          float4 v0 = *(const float4*)bp;
          float4 v1 = *(const float4*)(bp + 4);
          a[rf][0] = (short)f2bf(v0.x); a[rf][1] = (short)f2bf(v0.y);
          a[rf][2] = (short)f2bf(v0.z); a[rf][3] = (short)f2bf(v0.w);
          a[rf][4] = (short)f2bf(v1.x); a[rf][5] = (short)f2bf(v1.y);
          a[rf][6] = (short)f2bf(v1.z); a[rf][7] = (short)f2bf(v1.w);
        }
      } else {
#pragma unroll
        for (int rf = 0; rf < 4; ++rf)
          unpack8_hi(xp + (size_t)rc4[rf] * L + g * 8 + kk * 32, a[rf]);
      }
    } else {
      const unsigned short* src = (seg == 1) ? g1h : g2h;
      const int* rsel = (seg == 1) ? j1 : j2;
#pragma unroll
      for (int rf = 0; rf < 4; ++rf)
        a[rf] = *(const short8*)(src + (size_t)rsel[rf] * L + g * 8 + kk * 32);
    }
  };

  auto mfma_phase = [&](int buf, const short8* a) {
#pragma unroll
    for (int fn = 0; fn < 8; ++fn) {
      int off = buf * 8192 + fn * 512 + c * 32 + g * 8;
      short8 bh = *(const short8*)&SL[off];
      short8 bl = *(const short8*)&SL[off + 4096];
#pragma unroll
      for (int rf = 0; rf < 4; ++rf) {
        acc[rf][fn] = __builtin_amdgcn_mfma_f32_16x16x32_bf16(a[rf], bh, acc[rf][fn], 0, 0, 0);
        acc[rf][fn] = __builtin_amdgcn_mfma_f32_16x16x32_bf16(a[rf], bl, acc[rf][fn], 0, 0, 0);
      }
    }
  };

  // ---- layer 0: 12 k-steps, W through LDS dbuf, A reg ping-pong ----
  {
    short8 aA[4], aB[4];
    loadW(0);
    load_frag(0, aA);
    writeW(0);
    loadW(1);
    __syncthreads();     // buf0 ready
#pragma unroll
    for (int ks = 0; ks < 12; ++ks) {
      short8* aCur = (ks & 1) ? aB : aA;
      short8* aNxt = (ks & 1) ? aA : aB;
      if (ks < 11) load_frag(ks + 1, aNxt);
      mfma_phase(ks & 1, aCur);
      if (ks < 11) {
        writeW((ks & 1) ^ 1);
        if (ks < 10) loadW(ks + 2);
      }
      __syncthreads();   // writes visible; buf[cur] reads done before next overwrite
    }
  }

  // ---- hidden: relu(acc + b0eff) -> Hbf (bf16, swizzled; wave-private stripe) ----
  unsigned short* Hbf = SL;   // aliases W dbuf (dead)
#pragma unroll
  for (int fn = 0; fn < 8; ++fn) {
    int col = fn * 16 + c;
    float bb = b0eff[col];
    int unit = col >> 3;
#pragma unroll
    for (int rf = 0; rf < 4; ++rf) {
#pragma unroll
      for (int ri = 0; ri < 4; ++ri) {
        int rl = wbase + rf * 16 + g * 4 + ri;
        float x = fmaxf(acc[rf][fn][ri] + bb, 0.f);
        Hbf[rl * 128 + ((unit ^ (rl & 15)) << 3) + (col & 7)] = f2bf(x);
      }
    }
  }
  // no barrier: each wave reads only its own 64-row stripe

  // ---- layer 1: [ROWS x 128] @ [128 x 128], 2-product, W1 direct L2 ----
  f32x4 acc2[4][8];
#pragma unroll
  for (int rf = 0; rf < 4; ++rf)
#pragma unroll
    for (int fn = 0; fn < 8; ++fn) acc2[rf][fn] = z4;
#pragma unroll
  for (int ks = 0; ks < 4; ++ks) {
    short8 ah[4];
#pragma unroll
    for (int rf = 0; rf < 4; ++rf) {
      int rl = wbase + rf * 16 + c;
      int unit = ks * 4 + g;
      ah[rf] = *(const short8*)&Hbf[rl * 128 + ((unit ^ (rl & 15)) << 3)];
    }
#pragma unroll
    for (int fn = 0; fn < 8; ++fn) {
      size_t wb = (size_t)(fn * 16 + c) * 128 + ks * 32 + g * 8;
      short8 bh = *(const short8*)(W1h + wb);
      short8 bl = *(const short8*)(W1l + wb);
#pragma unroll
      for (int rf = 0; rf < 4; ++rf) {
        acc2[rf][fn] = __builtin_amdgcn_mfma_f32_16x16x32_bf16(ah[rf], bh, acc2[rf][fn], 0, 0, 0);
        acc2[rf][fn] = __builtin_amdgcn_mfma_f32_16x16x32_bf16(ah[rf], bl, acc2[rf][fn], 0, 0, 0);
      }
    }
  }

  // ---- epilogue, per row-fragment ----
  float colagg[8];
#pragma unroll
  for (int fn = 0; fn < 8; ++fn) colagg[fn] = 0.f;

#pragma unroll
  for (int rf = 0; rf < 4; ++rf) {
    const int rb = wbase + rf * 16 + g * 4;
    float sum[4] = {0.f, 0.f, 0.f, 0.f}, sq[4] = {0.f, 0.f, 0.f, 0.f};
    float xv[8][4];
#pragma unroll
    for (int fn = 0; fn < 8; ++fn) {
      int col = fn * 16 + c;
      float bb = b1[col];
#pragma unroll
      for (int ri = 0; ri < 4; ++ri) {
        int row = rb + ri;
        float e = fmaxf(acc2[rf][fn][ri] + bb, 0.f);
        if (row < valid) {
          if (EDGE_MODE) e_out[(size_t)(m0 + row) * L + col] = f2bf(e);
          colagg[fn] += e;
          float xprev;
          if (EDGE_MODE) xprev = xf[(size_t)(m0 + row) * L + col];
          else           xprev = unpackf(xp[(size_t)(m0 + row) * L + col]);
          float x = e + xprev;
          xv[fn][ri] = x;
          sum[ri] += x;
          sq[ri] += x * x;
        } else {
          xv[fn][ri] = 0.f;
        }
      }
    }
#pragma unroll
    for (int mask = 1; mask <= 8; mask <<= 1) {
#pragma unroll
      for (int ri = 0; ri < 4; ++ri) {
        sum[ri] += __shfl_xor(sum[ri], mask);
        sq[ri] += __shfl_xor(sq[ri], mask);
      }
    }
    float mu[4], rs[4];
#pragma unroll
    for (int ri = 0; ri < 4; ++ri) {
      mu[ri] = sum[ri] * (1.f / 128.f);
      float var = sq[ri] * (1.f / 128.f) - mu[ri] * mu[ri];
      rs[ri] = rsqrtf(var + 1e-6f);
    }
#pragma unroll
    for (int fn = 0; fn < 8; ++fn) {
      int col = fn * 16 + c;
      float lns = ln_s[col], lnb = ln_b[col];
#pragma unroll
      for (int ri = 0; ri < 4; ++ri) {
        int row = rb + ri;
        if (row < valid) {
          float y = (xv[fn][ri] - mu[ri]) * rs[ri] * lns + lnb;
          if (xf_out) xf_out[(size_t)(m0 + row) * L + col] = y;
          if (xp_out) xp_out[(size_t)(m0 + row) * L + col] = packf(y);
          if (xh_out) xh_out[(size_t)(m0 + row) * L + col] = f2bf(y);
        }
      }
    }
  }

  // column aggregate
#pragma unroll
  for (int mask = 16; mask <= 32; mask <<= 1)
#pragma unroll
    for (int fn = 0; fn < 8; ++fn) colagg[fn] += __shfl_xor(colagg[fn], mask);
  __syncthreads();               // all Hbf reads complete; reuse as float scratch
  float* F = (float*)SL;
  if (lane < 16) {
#pragma unroll
    for (int fn = 0; fn < 8; ++fn) F[wg * 128 + fn * 16 + lane] = colagg[fn];
  }
  __syncthreads();
  if (t < 128) {
    float s = 0.f;
#pragma unroll
    for (int w = 0; w < WAVES; ++w) s += F[w * 128 + t];
    atomicAdd(agg + t, s);
  }
}

// global update + LN + (optionally) next step's bias folds + agg reset
__global__ void glob_step_kernel(float* __restrict__ glob,
                                 float* __restrict__ node_agg, float* __restrict__ edge_agg,
                                 const float* __restrict__ W0, const float* __restrict__ b0,
                                 const float* __restrict__ W1, const float* __restrict__ b1,
                                 const float* __restrict__ ln_s, const float* __restrict__ ln_b,
                                 const float* __restrict__ eWg, const float* __restrict__ eb0,
                                 float* __restrict__ b0e,
                                 const float* __restrict__ nWg, const float* __restrict__ nb0,
                                 float* __restrict__ b0n) {
  __shared__ float gin[384];
  __shared__ float h[128];
  __shared__ float red4[4];
  __shared__ float gl[128];
  int j = threadIdx.x;  // 128
  gin[j] = node_agg[j];
  gin[128 + j] = edge_agg[j];
  gin[256 + j] = glob[j];
  __syncthreads();
  node_agg[j] = 0.f;     // reset for next step (after consumption)
  edge_agg[j] = 0.f;
  float a = b0[j];
  for (int k = 0; k < 384; ++k) a += gin[k] * W0[k * L + j];
  h[j] = fmaxf(a, 0.f);
  __syncthreads();
  float o = b1[j];
  for (int k = 0; k < 128; ++k) o += h[k] * W1[k * L + j];
  o = fmaxf(o, 0.f);
  float x = o + gin[256 + j];
  float sum = x, sq = x * x;
  for (int m = 1; m < 64; m <<= 1) { sum += __shfl_xor(sum, m); sq += __shfl_xor(sq, m); }
  if ((j & 63) == 0) { red4[(j >> 6) * 2] = sum; red4[(j >> 6) * 2 + 1] = sq; }
  __syncthreads();
  sum = red4[0] + red4[2]; sq = red4[1] + red4[3];
  float mu = sum * (1.f / 128.f);
  float var = sq * (1.f / 128.f) - mu * mu;
  float rsd = rsqrtf(var + 1e-6f);
  float gnew = (x - mu) * rsd * ln_s[j] + ln_b[j];
  glob[j] = gnew;
  gl[j] = gnew;
  __syncthreads();
  if (eWg) {
    float ae = eb0[j], an = nb0[j];
    for (int k = 0; k < 128; ++k) {
      float g = gl[k];
      ae = fmaf(g, eWg[k * L + j], ae);
      an = fmaf(g, nWg[k * L + j], an);
    }
    b0e[j] = ae;
    b0n[j] = an;
  }
}

__global__ void decode_kernel(const float* __restrict__ glob, const float* __restrict__ W,
                              const float* __restrict__ bias, float* __restrict__ out) {
  int j = threadIdx.x;  // 128
  float a = bias[j];
  for (int k = 0; k < 128; ++k) a += glob[k] * W[k * L + j];
  out[j] = a;
}

extern "C" void kernel_launch(void* const* d_in, const int* in_sizes, int n_in,
                              void* d_out, int out_size, void* d_ws, size_t ws_size,
                              hipStream_t stream) {
  const float* node_feats = (const float*)d_in[0];
  const float* edge_feats = (const float*)d_in[1];
  const float* globals_   = (const float*)d_in[2];
  const int*   senders    = (const int*)d_in[3];
  const int*   receivers  = (const int*)d_in[4];
  const float* emb_node_W = (const float*)d_in[5];
  const float* emb_node_b = (const float*)d_in[6];
  const float* emb_edge_W = (const float*)d_in[7];
  const float* emb_edge_b = (const float*)d_in[8];
  const float* emb_glob_W = (const float*)d_in[9];
  const float* emb_glob_b = (const float*)d_in[10];
  const float* edge_W0 = (const float*)d_in[11];
  const float* edge_b0 = (const float*)d_in[12];
  const float* edge_W1 = (const float*)d_in[13];
  const float* edge_b1 = (const float*)d_in[14];
  const float* node_W0 = (const float*)d_in[15];
  const float* node_b0 = (const float*)d_in[16];
  const float* node_W1 = (const float*)d_in[17];
  const float* node_b1 = (const float*)d_in[18];
  const float* glob_W0 = (const float*)d_in[19];
  const float* glob_b0 = (const float*)d_in[20];
  const float* glob_W1 = (const float*)d_in[21];
  const float* glob_b1 = (const float*)d_in[22];
  const float* ln_node_s = (const float*)d_in[23];
  const float* ln_node_b = (const float*)d_in[24];
  const float* ln_edge_s = (const float*)d_in[25];
  const float* ln_edge_b = (const float*)d_in[26];
  const float* ln_glob_s = (const float*)d_in[27];
  const float* ln_glob_b = (const float*)d_in[28];
  const float* dec_W = (const float*)d_in[29];
  const float* dec_b = (const float*)d_in[30];

  const int N = in_sizes[0] / 64;
  const int E = in_sizes[1] / 32;

  float* nodes = (float*)d_out;                   // [N][128]
  float* edges = nodes + (size_t)N * L;           // [E][128] (live fp32 edge state)
  float* gout  = edges + (size_t)E * L;           // [128]

  char* wp = (char*)d_ws;
  auto alloc = [&](size_t bytes) -> char* {
    char* p = wp;
    wp += (bytes + 255) & ~(size_t)255;
    return p;
  };
  float* glob = (float*)alloc(512);
  float* node_agg = (float*)alloc(512);
  float* edge_agg = (float*)alloc(512);
  float* b0e_eff = (float*)alloc(512);
  float* b0n_eff = (float*)alloc(512);
  unsigned short* eW0c = (unsigned short*)alloc((size_t)NSTEPS * 12 * 8192 * 2);
  unsigned short* nW0c = (unsigned short*)alloc((size_t)NSTEPS * 12 * 8192 * 2);
  unsigned short* eW1h = (unsigned short*)alloc((size_t)NSTEPS * 128 * 128 * 2);
  unsigned short* eW1l = (unsigned short*)alloc((size_t)NSTEPS * 128 * 128 * 2);
  unsigned short* nW1h = (unsigned short*)alloc((size_t)NSTEPS * 128 * 128 * 2);
  unsigned short* nW1l = (unsigned short*)alloc((size_t)NSTEPS * 128 * 128 * 2);
  unsigned* nodes_p = (unsigned*)alloc((size_t)N * L * 4);
  unsigned short* nodes_h = (unsigned short*)alloc((size_t)N * L * 2);
  unsigned short* sent_h  = (unsigned short*)alloc((size_t)N * L * 2);
  unsigned short* recv_h  = (unsigned short*)alloc((size_t)N * L * 2);
  int* rp1 = (int*)alloc((size_t)(N + 1) * 4);
  int* rp2 = (int*)alloc((size_t)(N + 1) * 4);
  int* cnt1 = (int*)alloc((size_t)N * 4);
  int* cnt2 = (int*)alloc((size_t)N * 4);
  int* el1 = (int*)alloc((size_t)E * 4);
  int* el2 = (int*)alloc((size_t)E * 4);
  int* part = (int*)alloc(SCAN_B * 4);
  unsigned short* e16 = (unsigned short*)alloc((size_t)E * L * 2);
  (void)ws_size;

  // weight prep: layer0 fragment-ordered, layer1 transposed hi/lo
  conv_frag_kernel<<<(NSTEPS * 12 * 8192 + 255) / 256, 256, 0, stream>>>(edge_W0, eW0c, NSTEPS);
  conv_frag_kernel<<<(NSTEPS * 12 * 8192 + 255) / 256, 256, 0, stream>>>(node_W0, nW0c, NSTEPS);
  conv_split_kernel<<<(NSTEPS * 128 * 128 + 255) / 256, 256, 0, stream>>>(edge_W1, eW1h, eW1l, 128, 128, NSTEPS);
  conv_split_kernel<<<(NSTEPS * 128 * 128 + 255) / 256, 256, 0, stream>>>(node_W1, nW1h, nW1l, 128, 128, NSTEPS);

  // embeddings (exact fp32 math, W-in-register)
  embed_reg_kernel<64><<<2048, 128, 0, stream>>>(node_feats, emb_node_W, emb_node_b,
                                                 nullptr, nodes_p, nodes_h, N);
  embed_reg_kernel<32><<<4096, 128, 0, stream>>>(edge_feats, emb_edge_W, emb_edge_b,
                                                 edges, nullptr, nullptr, E);
  glob_embed_fold_kernel<<<1, 128, 0, stream>>>(globals_, emb_glob_W, emb_glob_b, glob,
                                                edge_W0 + 384 * L, edge_b0, b0e_eff,
                                                node_W0 + 384 * L, node_b0, b0n_eff,
                                                node_agg, edge_agg);

  // CSR build (once per launch)
  const int chunk = (N + SCAN_B - 1) / SCAN_B;
  hipMemsetAsync(cnt1, 0, (size_t)N * 4, stream);
  hipMemsetAsync(cnt2, 0, (size_t)N * 4, stream);
  hist_kernel<<<(E + 255) / 256, 256, 0, stream>>>(senders, receivers, cnt1, cnt2, E);
  scan_sum_kernel<<<SCAN_B, 256, 0, stream>>>(cnt1, part, N, chunk);
  scan_part_kernel<<<1, 64, 0, stream>>>(part, SCAN_B);
  scan_write_kernel<<<SCAN_B, 256, 0, stream>>>(cnt1, part, rp1, N, chunk, E);
  scan_sum_kernel<<<SCAN_B, 256, 0, stream>>>(cnt2, part, N, chunk);
  scan_part_kernel<<<1, 64, 0, stream>>>(part, SCAN_B);
  scan_write_kernel<<<SCAN_B, 256, 0, stream>>>(cnt2, part, rp2, N, chunk, E);
  hipMemsetAsync(cnt1, 0, (size_t)N * 4, stream);
  hipMemsetAsync(cnt2, 0, (size_t)N * 4, stream);
  fill_kernel<<<(E + 255) / 256, 256, 0, stream>>>(senders, receivers, rp1, rp2, cnt1, cnt2, el1, el2, E);

  const int egrid = (E + 127) / 128;
  const int ngrid = (N + 127) / 128;

  for (int s = 0; s < NSTEPS; ++s) {
    const bool last = (s == NSTEPS - 1);

    block_step_kernel<128, true><<<egrid, 128, 0, stream>>>(
        edges, nullptr, nodes_h, nodes_h, senders, receivers,
        eW0c + (size_t)s * 12 * 8192, b0e_eff,
        eW1h + (size_t)s * 128 * 128, eW1l + (size_t)s * 128 * 128, edge_b1 + s * L,
        ln_edge_s + s * L, ln_edge_b + s * L,
        edge_agg, e16, edges, nullptr, nullptr, E);

    gather_kernel<<<(N + 15) / 16, 256, 0, stream>>>(e16, rp1, el1, rp2, el2, sent_h, recv_h, N);

    block_step_kernel<128, false><<<ngrid, 128, 0, stream>>>(
        nullptr, nodes_p, sent_h, recv_h, nullptr, nullptr,
        nW0c + (size_t)s * 12 * 8192, b0n_eff,
        nW1h + (size_t)s * 128 * 128, nW1l + (size_t)s * 128 * 128, node_b1 + s * L,
        ln_node_s + s * L, ln_node_b + s * L,
        node_agg, nullptr, last ? nodes : nullptr, last ? nullptr : nodes_p,
        last ? nullptr : nodes_h, N);

    glob_step_kernel<<<1, 128, 0, stream>>>(
        glob, node_agg, edge_agg,
        glob_W0 + (size_t)s * 384 * L, glob_b0 + s * L,
        glob_W1 + (size_t)s * 128 * L, glob_b1 + s * L,
        ln_glob_s + s * L, ln_glob_b + s * L,
        last ? nullptr : (edge_W0 + (size_t)1 * 512 * L + 384 * L),
        last ? nullptr : (edge_b0 + 1 * L), b0e_eff,
        last ? nullptr : (node_W0 + (size_t)1 * 512 * L + 384 * L),
        last ? nullptr : (node_b0 + 1 * L), b0n_eff);
  }

  decode_kernel<<<1, 128, 0, stream>>>(glob, dec_W, dec_b, gout);
}